// Round 1
// baseline (18998.868 us; speedup 1.0000x reference)
//
#include <hip/hip_runtime.h>
#include <hip/hip_bf16.h>
#include <math.h>

// Problem constants (from setup_inputs)
#define BB 2
#define NSEQ 1024
#define DIM 1024
#define NH 16
#define DH 64
#define DEPTH 4
#define VOCAB 32000
#define XLM 256
#define MDB 4096
#define TOPK 32
#define KNN_LAYER 2
#define BNROWS (BB * NSEQ)   // 2048

// ---------------------------------------------------------------------------
// Embedding lookup: x[r, :] = emb[tokens[r], :]
__global__ __launch_bounds__(256) void embed_kernel(const int* __restrict__ tok,
                                                    const float* __restrict__ emb,
                                                    float* __restrict__ x) {
    int r = blockIdx.x, t = threadIdx.x;
    int id = tok[r];
    const float* er = emb + (size_t)id * DIM;
    float* xr = x + (size_t)r * DIM;
#pragma unroll
    for (int i = 0; i < 4; i++) xr[t + 256 * i] = er[t + 256 * i];
}

// ---------------------------------------------------------------------------
// Row LayerNorm over DIM=1024, one block (256 thr) per row
__global__ __launch_bounds__(256) void ln_kernel(const float* __restrict__ x,
                                                 const float* __restrict__ w,
                                                 const float* __restrict__ b,
                                                 float* __restrict__ y) {
    __shared__ float red[256];
    int r = blockIdx.x, t = threadIdx.x;
    const float* xr = x + (size_t)r * DIM;
    float v[4];
#pragma unroll
    for (int i = 0; i < 4; i++) v[i] = xr[t + 256 * i];
    float s = v[0] + v[1] + v[2] + v[3];
    red[t] = s; __syncthreads();
    for (int st = 128; st; st >>= 1) { if (t < st) red[t] += red[t + st]; __syncthreads(); }
    float mean = red[0] * (1.0f / DIM);
    __syncthreads();
    float s2 = 0.f;
#pragma unroll
    for (int i = 0; i < 4; i++) { float d = v[i] - mean; s2 += d * d; }
    red[t] = s2; __syncthreads();
    for (int st = 128; st; st >>= 1) { if (t < st) red[t] += red[t + st]; __syncthreads(); }
    float rs = rsqrtf(red[0] * (1.0f / DIM) + 1e-5f);
    float* yr = y + (size_t)r * DIM;
#pragma unroll
    for (int i = 0; i < 4; i++) {
        int c = t + 256 * i;
        yr[c] = (v[i] - mean) * rs * w[c] + b[c];
    }
}

// ---------------------------------------------------------------------------
// L2-normalize rows of length 64 (stride between rows configurable), in-place
__global__ void l2norm_kernel(float* __restrict__ p, int stride) {
    int r = blockIdx.x, t = threadIdx.x; // 64 threads
    float* pr = p + (size_t)r * stride;
    float v = pr[t];
    float s = v * v;
#pragma unroll
    for (int off = 32; off; off >>= 1) s += __shfl_xor(s, off, 64);
    float n = fmaxf(sqrtf(s), 1e-12f);
    pr[t] = v / n;
}

// Normalize db keys: dbkn[r,:] = l2n(db_kv[r, 0, :])   r in [0, B*M)
__global__ void dbnorm_kernel(const float* __restrict__ db, float* __restrict__ dbkn) {
    int r = blockIdx.x, t = threadIdx.x; // 64 threads
    float v = db[((size_t)r * 2 + 0) * DH + t];
    float s = v * v;
#pragma unroll
    for (int off = 32; off; off >>= 1) s += __shfl_xor(s, off, 64);
    float n = fmaxf(sqrtf(s), 1e-12f);
    dbkn[(size_t)r * DH + t] = v / n;
}

// ---------------------------------------------------------------------------
// Tiled fp32 GEMM: C = A(MxK) @ B(KxN) [+bias] [gelu] [+res]; all dims % tile == 0
#define GBM 64
#define GBN 64
#define GBK 16
__global__ __launch_bounds__(256) void gemm_f32(const float* __restrict__ A,
                                                const float* __restrict__ B,
                                                float* __restrict__ C,
                                                int M, int N, int K,
                                                const float* __restrict__ bias,
                                                const float* __restrict__ res,
                                                int act /*1=exact gelu*/) {
    __shared__ float sA[GBK][GBM + 1];
    __shared__ float sB[GBK][GBN];
    int bn = blockIdx.x * GBN;
    int bm = blockIdx.y * GBM;
    int tid = threadIdx.x;
    int tx = tid & 15, ty = tid >> 4;
    float acc[4][4] = {};
    for (int k0 = 0; k0 < K; k0 += GBK) {
#pragma unroll
        for (int i = 0; i < 4; i++) {
            int e = tid + 256 * i;
            int m = e >> 4, kk = e & 15;
            sA[kk][m] = A[(size_t)(bm + m) * K + k0 + kk];
        }
#pragma unroll
        for (int i = 0; i < 4; i++) {
            int e = tid + 256 * i;
            int kk = e >> 6, n = e & 63;
            sB[kk][n] = B[(size_t)(k0 + kk) * N + bn + n];
        }
        __syncthreads();
#pragma unroll
        for (int kk = 0; kk < GBK; kk++) {
            float a[4], bv[4];
#pragma unroll
            for (int j = 0; j < 4; j++) { a[j] = sA[kk][ty * 4 + j]; bv[j] = sB[kk][tx * 4 + j]; }
#pragma unroll
            for (int i = 0; i < 4; i++)
#pragma unroll
                for (int j = 0; j < 4; j++) acc[i][j] += a[i] * bv[j];
        }
        __syncthreads();
    }
#pragma unroll
    for (int i = 0; i < 4; i++) {
#pragma unroll
        for (int j = 0; j < 4; j++) {
            int r = bm + ty * 4 + i, c = bn + tx * 4 + j;
            float v = acc[i][j];
            if (bias) v += bias[c];
            if (act == 1) v = 0.5f * v * (1.0f + erff(v * 0.70710678118654752f));
            if (res) v += res[(size_t)r * N + c];
            C[(size_t)r * N + c] = v;
        }
    }
}

// ---------------------------------------------------------------------------
// Row-wise attention. One block (256 thr) per (b, h, i).
// q: (B*N, H*DH) (normalized already at KNN layer), kv: (B*N, 128) k|v
// xlm: layer-offset xl_mems (B, XL, 2, DH); dbkn: (B*M, DH) normalized keys
// dbfull: db_kv base (B, M, 2, DH); out: (B*N, H*DH)
template <int KNN>
__global__ __launch_bounds__(256) void attn_kernel(const float* __restrict__ q,
                                                   const float* __restrict__ kv,
                                                   const float* __restrict__ xlm,
                                                   const float* __restrict__ knn_scale,
                                                   const float* __restrict__ dbkn,
                                                   const float* __restrict__ dbfull,
                                                   float* __restrict__ out) {
    __shared__ float s_q[DH];
    __shared__ float s_sim[XLM + NSEQ];
    __shared__ float s_db[KNN ? MDB : 1];
    __shared__ float s_topv[TOPK];
    __shared__ int s_topi[TOPK];
    __shared__ float r_val[256];
    __shared__ int r_idx[256];
    __shared__ float s_part[4][DH];

    int bid = blockIdx.x;
    int i = bid & (NSEQ - 1);
    int h = (bid >> 10) & (NH - 1);
    int b = bid >> 14;
    int t = threadIdx.x;

    if (t < DH) s_q[t] = q[(size_t)(b * NSEQ + i) * (NH * DH) + h * DH + t];
    __syncthreads();

    float scale = KNN ? expf(knn_scale[h]) : 0.125f;
    int nloc = XLM + i + 1;

    // local sims (XL memories + causal local keys)
    float pmax = -INFINITY;
    for (int j = t; j < nloc; j += 256) {
        const float* kp = (j < XLM) ? &xlm[(((size_t)b * XLM + j) * 2 + 0) * DH]
                                    : &kv[(size_t)(b * NSEQ + (j - XLM)) * 128];
        float s = 0.f;
#pragma unroll
        for (int d = 0; d < DH; d++) s += s_q[d] * kp[d];
        s *= scale;
        s_sim[j] = s;
        pmax = fmaxf(pmax, s);
    }

    if (KNN) {
        // db sims (raw dot; q and dbkn both normalized)
        for (int ii = 0; ii < MDB / 256; ii++) {
            int m = t + 256 * ii;
            const float* kp = &dbkn[(size_t)(b * MDB + m) * DH];
            float s = 0.f;
#pragma unroll
            for (int d = 0; d < DH; d++) s += s_q[d] * kp[d];
            s_db[m] = s;
        }
        __syncthreads();
        // iterative top-32 via block argmax
        for (int it = 0; it < TOPK; it++) {
            float bv = -INFINITY; int bi = 0;
            for (int ii = 0; ii < MDB / 256; ii++) {
                int m = t + 256 * ii;
                float v = s_db[m];
                if (v > bv) { bv = v; bi = m; }
            }
            r_val[t] = bv; r_idx[t] = bi;
            __syncthreads();
            for (int st = 128; st; st >>= 1) {
                if (t < st && r_val[t + st] > r_val[t]) { r_val[t] = r_val[t + st]; r_idx[t] = r_idx[t + st]; }
                __syncthreads();
            }
            if (t == 0) { s_topv[it] = r_val[0]; s_topi[it] = r_idx[0]; s_db[r_idx[0]] = -INFINITY; }
            __syncthreads();
        }
        if (t < TOPK) pmax = fmaxf(pmax, s_topv[t] * scale);
    }

    // block max
    r_val[t] = pmax; __syncthreads();
    for (int st = 128; st; st >>= 1) { if (t < st) r_val[t] = fmaxf(r_val[t], r_val[t + st]); __syncthreads(); }
    float gmax = r_val[0];
    __syncthreads();

    // exp & sum
    float psum = 0.f;
    for (int j = t; j < nloc; j += 256) {
        float e = expf(s_sim[j] - gmax);
        s_sim[j] = e;
        psum += e;
    }
    if (KNN && t < TOPK) {
        float e = expf(s_topv[t] * scale - gmax);
        s_topv[t] = e;
        psum += e;
    }
    r_val[t] = psum; __syncthreads();
    for (int st = 128; st; st >>= 1) { if (t < st) r_val[t] += r_val[t + st]; __syncthreads(); }
    float gsum = r_val[0];
    __syncthreads();

    // weighted V accumulation, 4 groups of 64 threads
    int g = t >> 6, d = t & 63;
    float accd = 0.f;
    for (int j = g; j < nloc; j += 4) {
        const float* vp = (j < XLM) ? &xlm[(((size_t)b * XLM + j) * 2 + 1) * DH]
                                    : &kv[(size_t)(b * NSEQ + (j - XLM)) * 128 + DH];
        accd += s_sim[j] * vp[d];
    }
    if (KNN) {
        for (int j = g; j < TOPK; j += 4) {
            int m = s_topi[j];
            accd += s_topv[j] * dbfull[(((size_t)b * MDB + m) * 2 + 1) * DH + d];
        }
    }
    s_part[g][d] = accd;
    __syncthreads();
    if (t < DH) {
        float o = (s_part[0][t] + s_part[1][t] + s_part[2][t] + s_part[3][t]) / gsum;
        out[(size_t)(b * NSEQ + i) * (NH * DH) + h * DH + t] = o;
    }
}

// ---------------------------------------------------------------------------
extern "C" void kernel_launch(void* const* d_in, const int* in_sizes, int n_in,
                              void* d_out, int out_size, void* d_ws, size_t ws_size,
                              hipStream_t stream) {
    const int* tokens = (const int*)d_in[0];
    const float* emb = (const float*)d_in[1];
    const float* ln1_w = (const float*)d_in[2];
    const float* ln1_b = (const float*)d_in[3];
    const float* wq = (const float*)d_in[4];
    const float* wkv = (const float*)d_in[5];
    const float* wo = (const float*)d_in[6];
    const float* wo_b = (const float*)d_in[7];
    const float* knn_scale = (const float*)d_in[8];
    const float* ln2_w = (const float*)d_in[9];
    const float* ln2_b = (const float*)d_in[10];
    const float* ff_w1 = (const float*)d_in[11];
    const float* ff_b1 = (const float*)d_in[12];
    const float* ff_w2 = (const float*)d_in[13];
    const float* ff_b2 = (const float*)d_in[14];
    const float* lnf_w = (const float*)d_in[15];
    const float* lnf_b = (const float*)d_in[16];
    const float* w_logits = (const float*)d_in[17];
    const float* b_logits = (const float*)d_in[18];
    const float* xl_mems = (const float*)d_in[19];
    const float* db_kv = (const float*)d_in[20];
    // d_in[21] = knn_layer (=2), d_in[22] = topk (=32): fixed by setup_inputs, hardcoded.

    float* ws = (float*)d_ws;
    // workspace layout (floats)
    float* x    = ws;                              // 2048*1024
    float* h    = x + (size_t)BNROWS * DIM;        // 2048*1024 (also attn_out)
    float* kvb  = h + (size_t)BNROWS * DIM;        // 2048*128
    float* dbkn = kvb + (size_t)BNROWS * 128;      // 2*4096*64
    float* big  = dbkn + (size_t)BB * MDB * DH;    // 2048*4096 (q and ff-mid overlap)
    float* q = big;
    float* mid = big;
    float* logits = (float*)d_out;

    // embed
    embed_kernel<<<BNROWS, 256, 0, stream>>>(tokens, emb, x);
    // normalized db keys (used only at layer 2, cheap to always compute)
    dbnorm_kernel<<<BB * MDB, 64, 0, stream>>>(db_kv, dbkn);

    for (int l = 0; l < DEPTH; l++) {
        const float* wq_l = wq + (size_t)l * DIM * (NH * DH);
        const float* wkv_l = wkv + (size_t)l * DIM * (2 * DH);
        const float* wo_l = wo + (size_t)l * (NH * DH) * DIM;
        const float* xlm_l = xl_mems + (size_t)l * BB * XLM * 2 * DH;

        // h = LN1(x)
        ln_kernel<<<BNROWS, 256, 0, stream>>>(x, ln1_w + (size_t)l * DIM, ln1_b + (size_t)l * DIM, h);
        // q = h @ wq_l   (2048 x 1024 x 1024)
        gemm_f32<<<dim3((NH * DH) / GBN, BNROWS / GBM), 256, 0, stream>>>(
            h, wq_l, q, BNROWS, NH * DH, DIM, nullptr, nullptr, 0);
        // kv = h @ wkv_l (2048 x 128 x 1024)
        gemm_f32<<<dim3(128 / GBN, BNROWS / GBM), 256, 0, stream>>>(
            h, wkv_l, kvb, BNROWS, 128, DIM, nullptr, nullptr, 0);

        if (l == KNN_LAYER) {
            // l2-normalize q rows (per b,n,h) and fresh-k rows (per b,n)
            l2norm_kernel<<<BNROWS * NH, 64, 0, stream>>>(q, DH);
            l2norm_kernel<<<BNROWS, 64, 0, stream>>>(kvb, 128);
            attn_kernel<1><<<BB * NH * NSEQ, 256, 0, stream>>>(q, kvb, xlm_l, knn_scale, dbkn, db_kv, h);
        } else {
            attn_kernel<0><<<BB * NH * NSEQ, 256, 0, stream>>>(q, kvb, xlm_l, knn_scale, dbkn, db_kv, h);
        }

        // x = attn_out @ wo_l + wo_b + x  (in-place residual)
        gemm_f32<<<dim3(DIM / GBN, BNROWS / GBM), 256, 0, stream>>>(
            h, wo_l, x, BNROWS, DIM, NH * DH, wo_b + (size_t)l * DIM, x, 0);

        // h = LN2(x)
        ln_kernel<<<BNROWS, 256, 0, stream>>>(x, ln2_w + (size_t)l * DIM, ln2_b + (size_t)l * DIM, h);
        // mid = gelu(h @ ff_w1 + b1)  (2048 x 4096 x 1024)
        gemm_f32<<<dim3((4 * DIM) / GBN, BNROWS / GBM), 256, 0, stream>>>(
            h, ff_w1 + (size_t)l * DIM * 4 * DIM, mid, BNROWS, 4 * DIM, DIM,
            ff_b1 + (size_t)l * 4 * DIM, nullptr, 1);
        // x = mid @ ff_w2 + b2 + x    (2048 x 1024 x 4096)
        gemm_f32<<<dim3(DIM / GBN, BNROWS / GBM), 256, 0, stream>>>(
            mid, ff_w2 + (size_t)l * 4 * DIM * DIM, x, BNROWS, DIM, 4 * DIM,
            ff_b2 + (size_t)l * DIM, x, 0);
    }

    // final LN + logits
    ln_kernel<<<BNROWS, 256, 0, stream>>>(x, lnf_w, lnf_b, h);
    gemm_f32<<<dim3(VOCAB / GBN, BNROWS / GBM), 256, 0, stream>>>(
        h, w_logits, logits, BNROWS, VOCAB, DIM, b_logits, nullptr, 0);
}

// Round 2
// 11483.727 us; speedup vs baseline: 1.6544x; 1.6544x over previous
//
#include <hip/hip_runtime.h>
#include <hip/hip_bf16.h>
#include <math.h>

// Problem constants (from setup_inputs)
#define BB 2
#define NSEQ 1024
#define DIM 1024
#define NH 16
#define DH 64
#define DEPTH 4
#define VOCAB 32000
#define XLM 256
#define MDB 4096
#define TOPK 32
#define KNN_LAYER 2
#define BNROWS (BB * NSEQ)   // 2048

// ---------------------------------------------------------------------------
__global__ __launch_bounds__(256) void embed_kernel(const int* __restrict__ tok,
                                                    const float* __restrict__ emb,
                                                    float* __restrict__ x) {
    int r = blockIdx.x, t = threadIdx.x;
    int id = tok[r];
    const float* er = emb + (size_t)id * DIM;
    float* xr = x + (size_t)r * DIM;
#pragma unroll
    for (int i = 0; i < 4; i++) xr[t + 256 * i] = er[t + 256 * i];
}

// ---------------------------------------------------------------------------
__global__ __launch_bounds__(256) void ln_kernel(const float* __restrict__ x,
                                                 const float* __restrict__ w,
                                                 const float* __restrict__ b,
                                                 float* __restrict__ y) {
    __shared__ float red[256];
    int r = blockIdx.x, t = threadIdx.x;
    const float* xr = x + (size_t)r * DIM;
    float v[4];
#pragma unroll
    for (int i = 0; i < 4; i++) v[i] = xr[t + 256 * i];
    float s = v[0] + v[1] + v[2] + v[3];
    red[t] = s; __syncthreads();
    for (int st = 128; st; st >>= 1) { if (t < st) red[t] += red[t + st]; __syncthreads(); }
    float mean = red[0] * (1.0f / DIM);
    __syncthreads();
    float s2 = 0.f;
#pragma unroll
    for (int i = 0; i < 4; i++) { float d = v[i] - mean; s2 += d * d; }
    red[t] = s2; __syncthreads();
    for (int st = 128; st; st >>= 1) { if (t < st) red[t] += red[t + st]; __syncthreads(); }
    float rs = rsqrtf(red[0] * (1.0f / DIM) + 1e-5f);
    float* yr = y + (size_t)r * DIM;
#pragma unroll
    for (int i = 0; i < 4; i++) {
        int c = t + 256 * i;
        yr[c] = (v[i] - mean) * rs * w[c] + b[c];
    }
}

// ---------------------------------------------------------------------------
__global__ void l2norm_kernel(float* __restrict__ p, int stride) {
    int r = blockIdx.x, t = threadIdx.x; // 64 threads
    float* pr = p + (size_t)r * stride;
    float v = pr[t];
    float s = v * v;
#pragma unroll
    for (int off = 32; off; off >>= 1) s += __shfl_xor(s, off, 64);
    float n = fmaxf(sqrtf(s), 1e-12f);
    pr[t] = v / n;
}

__global__ void dbnorm_kernel(const float* __restrict__ db, float* __restrict__ dbkn) {
    int r = blockIdx.x, t = threadIdx.x; // 64 threads
    float v = db[((size_t)r * 2 + 0) * DH + t];
    float s = v * v;
#pragma unroll
    for (int off = 32; off; off >>= 1) s += __shfl_xor(s, off, 64);
    float n = fmaxf(sqrtf(s), 1e-12f);
    dbkn[(size_t)r * DH + t] = v / n;
}

// ---------------------------------------------------------------------------
// Tiled fp32 GEMM: C = A(MxK) @ B(KxN) [+bias] [gelu] [+res]
#define GBM 64
#define GBN 64
#define GBK 16
__global__ __launch_bounds__(256) void gemm_f32(const float* __restrict__ A,
                                                const float* __restrict__ B,
                                                float* __restrict__ C,
                                                int M, int N, int K,
                                                const float* __restrict__ bias,
                                                const float* __restrict__ res,
                                                int act) {
    __shared__ float sA[GBK][GBM + 1];
    __shared__ float sB[GBK][GBN];
    int bn = blockIdx.x * GBN;
    int bm = blockIdx.y * GBM;
    int tid = threadIdx.x;
    int tx = tid & 15, ty = tid >> 4;
    float acc[4][4] = {};
    for (int k0 = 0; k0 < K; k0 += GBK) {
#pragma unroll
        for (int i = 0; i < 4; i++) {
            int e = tid + 256 * i;
            int m = e >> 4, kk = e & 15;
            sA[kk][m] = A[(size_t)(bm + m) * K + k0 + kk];
        }
#pragma unroll
        for (int i = 0; i < 4; i++) {
            int e = tid + 256 * i;
            int kk = e >> 6, n = e & 63;
            sB[kk][n] = B[(size_t)(k0 + kk) * N + bn + n];
        }
        __syncthreads();
#pragma unroll
        for (int kk = 0; kk < GBK; kk++) {
            float a[4], bv[4];
#pragma unroll
            for (int j = 0; j < 4; j++) { a[j] = sA[kk][ty * 4 + j]; bv[j] = sB[kk][tx * 4 + j]; }
#pragma unroll
            for (int i = 0; i < 4; i++)
#pragma unroll
                for (int j = 0; j < 4; j++) acc[i][j] += a[i] * bv[j];
        }
        __syncthreads();
    }
#pragma unroll
    for (int i = 0; i < 4; i++) {
#pragma unroll
        for (int j = 0; j < 4; j++) {
            int r = bm + ty * 4 + i, c = bn + tx * 4 + j;
            float v = acc[i][j];
            if (bias) v += bias[c];
            if (act == 1) v = 0.5f * v * (1.0f + erff(v * 0.70710678118654752f));
            if (res) v += res[(size_t)r * N + c];
            C[(size_t)r * N + c] = v;
        }
    }
}

// ---------------------------------------------------------------------------
// Flash attention over XL + causal local keys.
// Block = 256 thr, one (b, h, 64-row q tile). thread t: qr = t>>2, cg = t&3.
// Each thread: 16 score cols (cg*16..) and 16 output dims (cg*16..) of its row.
// KNNL: scale = exp(knn_scale[h]); writes (m, l) stats for later mem-combine.
template <int KNNL>
__global__ __launch_bounds__(256) void flash_kernel(const float* __restrict__ q,
                                                    const float* __restrict__ kv,
                                                    const float* __restrict__ xlm,
                                                    const float* __restrict__ knn_scale,
                                                    float* __restrict__ out,
                                                    float* __restrict__ stats) {
    __shared__ float sQ[64][65];
    __shared__ float sK[64][65];
    __shared__ float sV[64][65];

    int qt = blockIdx.x, h = blockIdx.y, b = blockIdx.z;
    int q0 = qt * 64;
    int t = threadIdx.x;
    int lane = t & 63;
    int qr = t >> 2, cg = t & 3;

    // load Q tile (coalesced float4)
    {
        int r = t >> 4, d4 = (t & 15) * 4;
#pragma unroll
        for (int rr = 0; rr < 4; rr++) {
            int row = rr * 16 + r;
            float4 v = *(const float4*)&q[(size_t)(b * NSEQ + q0 + row) * DIM + h * DH + d4];
            sQ[row][d4] = v.x; sQ[row][d4 + 1] = v.y; sQ[row][d4 + 2] = v.z; sQ[row][d4 + 3] = v.w;
        }
    }
    float scale = KNNL ? __expf(knn_scale[h]) : 0.125f;
    float m = -1e30f, l = 0.f;
    float o[16];
#pragma unroll
    for (int j = 0; j < 16; j++) o[j] = 0.f;

    int ntiles = 5 + qt;
    int lim = XLM + q0 + qr;          // max allowed key index for this row

    for (int T = 0; T < ntiles; T++) {
        __syncthreads();   // previous tile's PV reads done before restage
        {
            int r = t >> 4, d4 = (t & 15) * 4;
#pragma unroll
            for (int rr = 0; rr < 4; rr++) {
                int row = rr * 16 + r;
                int kg = T * 64 + row;
                const float *kp, *vp;
                if (kg < XLM) {
                    kp = &xlm[(((size_t)b * XLM + kg) * 2 + 0) * DH + d4];
                    vp = &xlm[(((size_t)b * XLM + kg) * 2 + 1) * DH + d4];
                } else {
                    kp = &kv[(size_t)(b * NSEQ + kg - XLM) * 128 + d4];
                    vp = kp + DH;
                }
                float4 kk = *(const float4*)kp;
                sK[row][d4] = kk.x; sK[row][d4 + 1] = kk.y; sK[row][d4 + 2] = kk.z; sK[row][d4 + 3] = kk.w;
                float4 vv = *(const float4*)vp;
                sV[row][d4] = vv.x; sV[row][d4 + 1] = vv.y; sV[row][d4 + 2] = vv.z; sV[row][d4 + 3] = vv.w;
            }
        }
        __syncthreads();

        // scores: s[j] = q[qr] . k[cg*16+j]
        float s[16];
#pragma unroll
        for (int j = 0; j < 16; j++) s[j] = 0.f;
        const float* qrow = &sQ[qr][0];
        const float* kbase = &sK[cg * 16][0];
        for (int d = 0; d < 64; d++) {
            float qv = qrow[d];
#pragma unroll
            for (int j = 0; j < 16; j++) s[j] += qv * kbase[j * 65 + d];
        }
        int kb = T * 64 + cg * 16;
#pragma unroll
        for (int j = 0; j < 16; j++) s[j] = (kb + j <= lim) ? s[j] * scale : -1e30f;

        // online softmax (4-lane row group)
        float tm = s[0];
#pragma unroll
        for (int j = 1; j < 16; j++) tm = fmaxf(tm, s[j]);
        tm = fmaxf(tm, __shfl_xor(tm, 1, 64));
        tm = fmaxf(tm, __shfl_xor(tm, 2, 64));
        float mnew = fmaxf(m, tm);
        float alpha = __expf(m - mnew);
        float ps = 0.f;
#pragma unroll
        for (int j = 0; j < 16; j++) { s[j] = __expf(s[j] - mnew); ps += s[j]; }
        ps += __shfl_xor(ps, 1, 64);
        ps += __shfl_xor(ps, 2, 64);
        l = l * alpha + ps;
        m = mnew;
#pragma unroll
        for (int j = 0; j < 16; j++) o[j] *= alpha;

        // PV: exchange p across the 4-lane row group via shfl, accumulate
        int src0 = lane & ~3;
#pragma unroll
        for (int g = 0; g < 4; g++) {
            float pj[16];
#pragma unroll
            for (int j = 0; j < 16; j++) pj[j] = __shfl(s[j], src0 + g, 64);
            const float* vbase = &sV[g * 16][cg * 16];
#pragma unroll
            for (int j = 0; j < 16; j++) {
                float p = pj[j];
#pragma unroll
                for (int dd = 0; dd < 16; dd++) o[dd] += p * vbase[j * 65 + dd];
            }
        }
    }

    float inv = 1.0f / l;
    float* op = &out[(size_t)(b * NSEQ + q0 + qr) * DIM + h * DH + cg * 16];
#pragma unroll
    for (int dd = 0; dd < 16; dd++) op[dd] = o[dd] * inv;
    if (KNNL && cg == 0) {
        size_t srow = (((size_t)b * NH + h) * NSEQ + q0 + qr) * 2;
        stats[srow] = m;
        stats[srow + 1] = l;
    }
}

// ---------------------------------------------------------------------------
// simdb = q_bh (1024x64, l2-normalized) @ dbkn_b^T (64x4096), batched over bh.
// grid: (M/64, N/64, nbh), block 256. Output chunk-local: (z, N, M).
__global__ __launch_bounds__(256) void simdb_gemm(const float* __restrict__ q,
                                                  const float* __restrict__ dbkn,
                                                  float* __restrict__ simdb,
                                                  int bh0) {
    __shared__ float sQ[64][65];
    __shared__ float sK[64][65];
    int bh = bh0 + blockIdx.z;
    int b = bh >> 4, h = bh & 15;
    int m0 = blockIdx.x * 64, i0 = blockIdx.y * 64;
    int t = threadIdx.x;
    {
        int r = t >> 4, d4 = (t & 15) * 4;
#pragma unroll
        for (int rr = 0; rr < 4; rr++) {
            int row = rr * 16 + r;
            float4 qv = *(const float4*)&q[(size_t)(b * NSEQ + i0 + row) * DIM + h * DH + d4];
            sQ[row][d4] = qv.x; sQ[row][d4 + 1] = qv.y; sQ[row][d4 + 2] = qv.z; sQ[row][d4 + 3] = qv.w;
            float4 kk = *(const float4*)&dbkn[(size_t)(b * MDB + m0 + row) * DH + d4];
            sK[row][d4] = kk.x; sK[row][d4 + 1] = kk.y; sK[row][d4 + 2] = kk.z; sK[row][d4 + 3] = kk.w;
        }
    }
    __syncthreads();
    int ti = t >> 4, tm = t & 15;
    float acc[4][4] = {};
    for (int d = 0; d < 64; d++) {
        float a[4], bv[4];
#pragma unroll
        for (int j = 0; j < 4; j++) { a[j] = sQ[ti * 4 + j][d]; bv[j] = sK[tm * 4 + j][d]; }
#pragma unroll
        for (int i = 0; i < 4; i++)
#pragma unroll
            for (int j = 0; j < 4; j++) acc[i][j] += a[i] * bv[j];
    }
#pragma unroll
    for (int i = 0; i < 4; i++)
#pragma unroll
        for (int j = 0; j < 4; j++)
            simdb[((size_t)blockIdx.z * NSEQ + i0 + ti * 4 + i) * MDB + m0 + tm * 4 + j] = acc[i][j];
}

// ---------------------------------------------------------------------------
// Per-row top-32 over simdb + mem softmax + combine with local flash stats.
// 1 wave per row. Element m lives at sv[(m>>6)*65 + (m&63)]; lane owns m&63==lane.
__global__ void knn_select(const float* __restrict__ simdb,
                           const float* __restrict__ db,
                           const float* __restrict__ knn_scale,
                           const float* __restrict__ stats,
                           float* __restrict__ out,
                           int bh0) {
    __shared__ float sv[64 * 65];
    int bh = bh0 + blockIdx.y;
    int b = bh >> 4, h = bh & 15;
    int i = blockIdx.x;
    int lane = threadIdx.x;

    const float* srow = &simdb[((size_t)blockIdx.y * NSEQ + i) * MDB];
    float lmax = -1e30f; int lidx = 0;
    for (int ii = 0; ii < 64; ii++) {
        float v = srow[ii * 64 + lane];
        sv[ii * 65 + lane] = v;
        if (v > lmax) { lmax = v; lidx = ii * 64 + lane; }
    }
    __syncthreads();

    float tv = 0.f; int ti = 0;
    for (int it = 0; it < TOPK; it++) {
        float v = lmax; int idx = lidx;
#pragma unroll
        for (int off = 32; off; off >>= 1) {
            float v2 = __shfl_xor(v, off, 64);
            int i2 = __shfl_xor(idx, off, 64);
            if (v2 > v || (v2 == v && i2 < idx)) { v = v2; idx = i2; }
        }
        if (lane == it) { tv = v; ti = idx; }
        int col = idx & 63;
        if (lane == (idx >> 6)) sv[(idx >> 6) * 65 + col] = -1e30f;
        __syncthreads();
        float rv = sv[lane * 65 + col];
        int ridx = lane * 64 + col;
#pragma unroll
        for (int off = 32; off; off >>= 1) {
            float v2 = __shfl_xor(rv, off, 64);
            int i2 = __shfl_xor(ridx, off, 64);
            if (v2 > rv || (v2 == rv && i2 < ridx)) { rv = v2; ridx = i2; }
        }
        if (lane == col) { lmax = rv; lidx = ridx; }
        __syncthreads();
    }

    float scl = __expf(knn_scale[h]);
    size_t srow_idx = (((size_t)b * NH + h) * NSEQ + i) * 2;
    float m_loc = stats[srow_idx], l_loc = stats[srow_idx + 1];
    float m_mem = __shfl(tv, 0, 64) * scl;
    float M = fmaxf(m_loc, m_mem);
    float e = (lane < TOPK) ? __expf(tv * scl - M) : 0.f;
    float esum = e;
#pragma unroll
    for (int off = 32; off; off >>= 1) esum += __shfl_xor(esum, off, 64);
    float co = __expf(m_loc - M);
    float denom = l_loc * co + esum;

    float acc = 0.f;
    for (int j = 0; j < TOPK; j++) {
        int idxj = __shfl(ti, j, 64);
        float ej = __shfl(e, j, 64);
        acc += ej * db[(((size_t)b * MDB + idxj) * 2 + 1) * DH + lane];
    }
    size_t op = (size_t)(b * NSEQ + i) * DIM + h * DH + lane;
    float o_loc = out[op];
    out[op] = (o_loc * l_loc * co + acc) / denom;
}

// ---------------------------------------------------------------------------
extern "C" void kernel_launch(void* const* d_in, const int* in_sizes, int n_in,
                              void* d_out, int out_size, void* d_ws, size_t ws_size,
                              hipStream_t stream) {
    const int* tokens = (const int*)d_in[0];
    const float* emb = (const float*)d_in[1];
    const float* ln1_w = (const float*)d_in[2];
    const float* ln1_b = (const float*)d_in[3];
    const float* wq = (const float*)d_in[4];
    const float* wkv = (const float*)d_in[5];
    const float* wo = (const float*)d_in[6];
    const float* wo_b = (const float*)d_in[7];
    const float* knn_scale = (const float*)d_in[8];
    const float* ln2_w = (const float*)d_in[9];
    const float* ln2_b = (const float*)d_in[10];
    const float* ff_w1 = (const float*)d_in[11];
    const float* ff_b1 = (const float*)d_in[12];
    const float* ff_w2 = (const float*)d_in[13];
    const float* ff_b2 = (const float*)d_in[14];
    const float* lnf_w = (const float*)d_in[15];
    const float* lnf_b = (const float*)d_in[16];
    const float* w_logits = (const float*)d_in[17];
    const float* b_logits = (const float*)d_in[18];
    const float* xl_mems = (const float*)d_in[19];
    const float* db_kv = (const float*)d_in[20];

    float* ws = (float*)d_ws;
    float* x     = ws;                               // 2048*1024
    float* h     = x + (size_t)BNROWS * DIM;         // 2048*1024 (attn out too)
    float* kvb   = h + (size_t)BNROWS * DIM;         // 2048*128
    float* dbkn  = kvb + (size_t)BNROWS * 128;       // 2*4096*64
    float* stats = dbkn + (size_t)BB * MDB * DH;     // 2*16*1024*2
    float* big   = stats + (size_t)BB * NH * NSEQ * 2; // 2048*4096 (q / ff-mid)
    float* q = big;
    float* mid = big;
    float* logits = (float*)d_out;
    // d_out doubles as simdb scratch during the KNN layer (fully rewritten by
    // the final logits GEMM). Capacity in bh-slices of N*M floats:
    int nbh_cap = (int)((size_t)out_size / ((size_t)NSEQ * MDB));
    if (nbh_cap > BB * NH) nbh_cap = BB * NH;
    if (nbh_cap < 1) nbh_cap = 1;

    embed_kernel<<<BNROWS, 256, 0, stream>>>(tokens, emb, x);
    dbnorm_kernel<<<BB * MDB, 64, 0, stream>>>(db_kv, dbkn);

    for (int l = 0; l < DEPTH; l++) {
        const float* wq_l = wq + (size_t)l * DIM * (NH * DH);
        const float* wkv_l = wkv + (size_t)l * DIM * (2 * DH);
        const float* wo_l = wo + (size_t)l * (NH * DH) * DIM;
        const float* xlm_l = xl_mems + (size_t)l * BB * XLM * 2 * DH;

        ln_kernel<<<BNROWS, 256, 0, stream>>>(x, ln1_w + (size_t)l * DIM, ln1_b + (size_t)l * DIM, h);
        gemm_f32<<<dim3((NH * DH) / GBN, BNROWS / GBM), 256, 0, stream>>>(
            h, wq_l, q, BNROWS, NH * DH, DIM, nullptr, nullptr, 0);
        gemm_f32<<<dim3(128 / GBN, BNROWS / GBM), 256, 0, stream>>>(
            h, wkv_l, kvb, BNROWS, 128, DIM, nullptr, nullptr, 0);

        if (l == KNN_LAYER) {
            l2norm_kernel<<<BNROWS * NH, 64, 0, stream>>>(q, DH);
            l2norm_kernel<<<BNROWS, 64, 0, stream>>>(kvb, 128);
            flash_kernel<1><<<dim3(NSEQ / 64, NH, BB), 256, 0, stream>>>(
                q, kvb, xlm_l, knn_scale, h, stats);
            for (int bh0 = 0; bh0 < BB * NH; bh0 += nbh_cap) {
                int nb = BB * NH - bh0; if (nb > nbh_cap) nb = nbh_cap;
                simdb_gemm<<<dim3(MDB / 64, NSEQ / 64, nb), 256, 0, stream>>>(
                    q, dbkn, (float*)d_out, bh0);
                knn_select<<<dim3(NSEQ, nb), 64, 0, stream>>>(
                    (float*)d_out, db_kv, knn_scale, stats, h, bh0);
            }
        } else {
            flash_kernel<0><<<dim3(NSEQ / 64, NH, BB), 256, 0, stream>>>(
                q, kvb, xlm_l, knn_scale, h, stats);
        }

        gemm_f32<<<dim3(DIM / GBN, BNROWS / GBM), 256, 0, stream>>>(
            h, wo_l, x, BNROWS, DIM, NH * DH, wo_b + (size_t)l * DIM, x, 0);

        ln_kernel<<<BNROWS, 256, 0, stream>>>(x, ln2_w + (size_t)l * DIM, ln2_b + (size_t)l * DIM, h);
        gemm_f32<<<dim3((4 * DIM) / GBN, BNROWS / GBM), 256, 0, stream>>>(
            h, ff_w1 + (size_t)l * DIM * 4 * DIM, mid, BNROWS, 4 * DIM, DIM,
            ff_b1 + (size_t)l * 4 * DIM, nullptr, 1);
        gemm_f32<<<dim3(DIM / GBN, BNROWS / GBM), 256, 0, stream>>>(
            mid, ff_w2 + (size_t)l * 4 * DIM * DIM, x, BNROWS, DIM, 4 * DIM,
            ff_b2 + (size_t)l * DIM, x, 0);
    }

    ln_kernel<<<BNROWS, 256, 0, stream>>>(x, lnf_w, lnf_b, h);
    gemm_f32<<<dim3(VOCAB / GBN, BNROWS / GBM), 256, 0, stream>>>(
        h, w_logits, logits, BNROWS, VOCAB, DIM, b_logits, nullptr, 0);
}

// Round 5
// 6782.072 us; speedup vs baseline: 2.8013x; 1.6932x over previous
//
#include <hip/hip_runtime.h>
#include <hip/hip_bf16.h>
#include <math.h>

// Problem constants (from setup_inputs)
#define BB 2
#define NSEQ 1024
#define DIM 1024
#define NH 16
#define DH 64
#define DEPTH 4
#define VOCAB 32000
#define XLM 256
#define MDB 4096
#define TOPK 32
#define KNN_LAYER 2
#define BNROWS (BB * NSEQ)   // 2048
#define LOGITS_CHUNK 3200    // 32000 = 10 * 3200; 3200 % 128 == 0

typedef __bf16 bf16x8v __attribute__((ext_vector_type(8)));
typedef float f32x4v __attribute__((ext_vector_type(4)));

__device__ __forceinline__ float bfbits2f(unsigned short u) {
    union { float f; unsigned int i; } v; v.i = ((unsigned int)u) << 16; return v.f;
}
__device__ __forceinline__ float bf2f(__hip_bfloat16 h) { return __bfloat162float(h); }
__device__ __forceinline__ __hip_bfloat16 f2bf(float f) { return __float2bfloat16(f); }

__device__ __forceinline__ void gload16(const void* gp, void* lp) {
    __builtin_amdgcn_global_load_lds(
        (const __attribute__((address_space(1))) unsigned int*)gp,
        (__attribute__((address_space(3))) unsigned int*)lp, 16, 0, 0);
}

// ---------------------------------------------------------------------------
__global__ __launch_bounds__(256) void embed_kernel(const int* __restrict__ tok,
                                                    const float* __restrict__ emb,
                                                    float* __restrict__ x) {
    int r = blockIdx.x, t = threadIdx.x;
    int id = tok[r];
    const float* er = emb + (size_t)id * DIM;
    float* xr = x + (size_t)r * DIM;
#pragma unroll
    for (int i = 0; i < 4; i++) xr[t + 256 * i] = er[t + 256 * i];
}

// ---------------------------------------------------------------------------
// Row LayerNorm over DIM=1024, fp32 in, split-bf16 (hi/lo planes) out
__global__ __launch_bounds__(256) void ln_kernel(const float* __restrict__ x,
                                                 const float* __restrict__ w,
                                                 const float* __restrict__ b,
                                                 __hip_bfloat16* __restrict__ y,
                                                 size_t ypS) {
    __shared__ float red[256];
    int r = blockIdx.x, t = threadIdx.x;
    const float* xr = x + (size_t)r * DIM;
    float v[4];
#pragma unroll
    for (int i = 0; i < 4; i++) v[i] = xr[t + 256 * i];
    float s = v[0] + v[1] + v[2] + v[3];
    red[t] = s; __syncthreads();
    for (int st = 128; st; st >>= 1) { if (t < st) red[t] += red[t + st]; __syncthreads(); }
    float mean = red[0] * (1.0f / DIM);
    __syncthreads();
    float s2 = 0.f;
#pragma unroll
    for (int i = 0; i < 4; i++) { float d = v[i] - mean; s2 += d * d; }
    red[t] = s2; __syncthreads();
    for (int st = 128; st; st >>= 1) { if (t < st) red[t] += red[t + st]; __syncthreads(); }
    float rs = rsqrtf(red[0] * (1.0f / DIM) + 1e-5f);
    __hip_bfloat16* yr = y + (size_t)r * DIM;
#pragma unroll
    for (int i = 0; i < 4; i++) {
        int c = t + 256 * i;
        float val = (v[i] - mean) * rs * w[c] + b[c];
        __hip_bfloat16 hv = f2bf(val);
        yr[c] = hv;
        yr[c + ypS] = f2bf(val - bf2f(hv));
    }
}

// ---------------------------------------------------------------------------
// L2-normalize fp32 rows of length 64 (row stride configurable), in-place
__global__ void l2norm_kernel(float* __restrict__ p, int stride) {
    int r = blockIdx.x, t = threadIdx.x; // 64 threads
    float* pr = p + (size_t)r * stride;
    float v = pr[t];
    float s = v * v;
#pragma unroll
    for (int off = 32; off; off >>= 1) s += __shfl_xor(s, off, 64);
    float n = fmaxf(sqrtf(s), 1e-12f);
    pr[t] = v / n;
}

__global__ void dbnorm_kernel(const float* __restrict__ db, float* __restrict__ dbkn) {
    int r = blockIdx.x, t = threadIdx.x; // 64 threads
    float v = db[((size_t)r * 2 + 0) * DH + t];
    float s = v * v;
#pragma unroll
    for (int off = 32; off; off >>= 1) s += __shfl_xor(s, off, 64);
    float n = fmaxf(sqrtf(s), 1e-12f);
    dbkn[(size_t)r * DH + t] = v / n;
}

// ---------------------------------------------------------------------------
// Weight convert + transpose: W (K x N fp32, row stride ldw) ->
// WT (N x K split-bf16, hi plane + lo plane at +wpS)
__global__ __launch_bounds__(256) void wconv(const float* __restrict__ W,
                                             __hip_bfloat16* __restrict__ WT,
                                             size_t wpS, int K, int N, int ldw) {
    __shared__ float tile[64][65];
    int k0 = blockIdx.x * 64, n0 = blockIdx.y * 64;
    int t = threadIdx.x;
    int r = t >> 4, c4 = (t & 15) * 4;
#pragma unroll
    for (int rr = 0; rr < 4; rr++) {
        int row = rr * 16 + r;
        float4 v = *(const float4*)&W[(size_t)(k0 + row) * ldw + n0 + c4];
        tile[row][c4] = v.x; tile[row][c4 + 1] = v.y; tile[row][c4 + 2] = v.z; tile[row][c4 + 3] = v.w;
    }
    __syncthreads();
#pragma unroll
    for (int rr = 0; rr < 4; rr++) {
        int nrow = rr * 16 + r;
        size_t base = (size_t)(n0 + nrow) * K + k0 + c4;
#pragma unroll
        for (int j = 0; j < 4; j++) {
            float val = tile[c4 + j][nrow];
            __hip_bfloat16 hv = f2bf(val);
            WT[base + j] = hv;
            WT[base + j + wpS] = f2bf(val - bf2f(hv));
        }
    }
}

// ---------------------------------------------------------------------------
// Split-bf16 MFMA GEMM: C(MxN) = A(MxK) @ BT(NxK)^T with A,B as hi/lo planes.
// 128x128 tile, BK=32, 4 waves (2x2), each wave 64x64 = 4x4 x mfma 16x16x32.
// 3 MFMAs per fragment pair (hi*hi + lo*hi + hi*lo) ~ fp32 accuracy.
// OT=float: plain fp32 out. OT=__hip_bfloat16: split output (hi, lo at +cpS).
template <typename OT, int ACT>
__global__ __launch_bounds__(256) void gemm_split(const __hip_bfloat16* __restrict__ A, int lda, size_t apS,
                                                  const __hip_bfloat16* __restrict__ BT, int ldb, size_t bpS,
                                                  OT* __restrict__ C, int ldc, size_t cpS, int K,
                                                  const float* __restrict__ bias,
                                                  const float* __restrict__ res) {
    __shared__ __align__(16) __hip_bfloat16 sAh[128 * 32];
    __shared__ __align__(16) __hip_bfloat16 sAl[128 * 32];
    __shared__ __align__(16) __hip_bfloat16 sBh[128 * 32];
    __shared__ __align__(16) __hip_bfloat16 sBl[128 * 32];
    int bn = blockIdx.x * 128;
    int bm = blockIdx.y * 128;
    int t = threadIdx.x;
    int lane = t & 63, wid = t >> 6;
    int wr = wid >> 1, wc = wid & 1;
    int lr = lane & 15, kc = lane >> 4;

    f32x4v acc[4][4];
#pragma unroll
    for (int m = 0; m < 4; m++)
#pragma unroll
        for (int n = 0; n < 4; n++) acc[m][n] = (f32x4v){0.f, 0.f, 0.f, 0.f};

    for (int k0 = 0; k0 < K; k0 += 32) {
        __syncthreads();
        // stage 4 planes: chunk e -> row e>>2, lds slot e&3 holds logical
        // k-chunk (e&3)^((row>>1)&3)  (inverse-swizzled source, linear dest)
#pragma unroll
        for (int it = 0; it < 2; it++) {
            int e = wid * 128 + it * 64 + lane;
            int r = e >> 2;
            int cl = (e & 3) ^ ((r >> 1) & 3);
            size_t aoff = (size_t)(bm + r) * lda + k0 + cl * 8;
            size_t boff = (size_t)(bn + r) * ldb + k0 + cl * 8;
            int dst = (wid * 128 + it * 64) * 8;
            gload16(&A[aoff], &sAh[dst]);
            gload16(&A[aoff + apS], &sAl[dst]);
            gload16(&BT[boff], &sBh[dst]);
            gload16(&BT[boff + bpS], &sBl[dst]);
        }
        __syncthreads();

        bf16x8v ah[4], al[4], bh[4], bl[4];
#pragma unroll
        for (int m = 0; m < 4; m++) {
            int row = wr * 64 + m * 16 + lr;
            int off = row * 32 + ((kc ^ ((row >> 1) & 3)) << 3);
            ah[m] = *(const bf16x8v*)&sAh[off];
            al[m] = *(const bf16x8v*)&sAl[off];
        }
#pragma unroll
        for (int n = 0; n < 4; n++) {
            int row = wc * 64 + n * 16 + lr;
            int off = row * 32 + ((kc ^ ((row >> 1) & 3)) << 3);
            bh[n] = *(const bf16x8v*)&sBh[off];
            bl[n] = *(const bf16x8v*)&sBl[off];
        }
#pragma unroll
        for (int m = 0; m < 4; m++)
#pragma unroll
            for (int n = 0; n < 4; n++) {
                acc[m][n] = __builtin_amdgcn_mfma_f32_16x16x32_bf16(ah[m], bh[n], acc[m][n], 0, 0, 0);
                acc[m][n] = __builtin_amdgcn_mfma_f32_16x16x32_bf16(al[m], bh[n], acc[m][n], 0, 0, 0);
                acc[m][n] = __builtin_amdgcn_mfma_f32_16x16x32_bf16(ah[m], bl[n], acc[m][n], 0, 0, 0);
            }
    }

    // epilogue: C/D layout col = lane&15, row = (lane>>4)*4 + j
#pragma unroll
    for (int m = 0; m < 4; m++) {
#pragma unroll
        for (int n = 0; n < 4; n++) {
            int gcol = bn + wc * 64 + n * 16 + lr;
            float bv = bias ? bias[gcol] : 0.f;
#pragma unroll
            for (int j = 0; j < 4; j++) {
                int grow = bm + wr * 64 + m * 16 + kc * 4 + j;
                float v = acc[m][n][j] + bv;
                if (ACT == 1) v = 0.5f * v * (1.0f + erff(v * 0.70710678118654752f));
                if (res) v += res[(size_t)grow * ldc + gcol];
                size_t idx = (size_t)grow * ldc + gcol;
                if constexpr (__is_same(OT, float)) {
                    C[idx] = v;
                } else {
                    __hip_bfloat16 hv = f2bf(v);
                    C[idx] = hv;
                    C[idx + cpS] = f2bf(v - bf2f(hv));
                }
            }
        }
    }
}

// ---------------------------------------------------------------------------
// Flash attention over XL + causal local keys (all fp32 in; split-bf16 out).
template <int KNNL>
__global__ __launch_bounds__(256) void flash_kernel(const float* __restrict__ q,
                                                    const float* __restrict__ kv,
                                                    const float* __restrict__ xlm,
                                                    const float* __restrict__ knn_scale,
                                                    __hip_bfloat16* __restrict__ out,
                                                    size_t opS,
                                                    float* __restrict__ stats) {
    __shared__ float sQ[64][65];
    __shared__ float sK[64][65];
    __shared__ float sV[64][65];

    int qt = blockIdx.x, h = blockIdx.y, b = blockIdx.z;
    int q0 = qt * 64;
    int t = threadIdx.x;
    int lane = t & 63;
    int qr = t >> 2, cg = t & 3;

    {
        int r = t >> 4, d4 = (t & 15) * 4;
#pragma unroll
        for (int rr = 0; rr < 4; rr++) {
            int row = rr * 16 + r;
            float4 v = *(const float4*)&q[(size_t)(b * NSEQ + q0 + row) * DIM + h * DH + d4];
            sQ[row][d4] = v.x; sQ[row][d4 + 1] = v.y; sQ[row][d4 + 2] = v.z; sQ[row][d4 + 3] = v.w;
        }
    }
    float scale = KNNL ? __expf(knn_scale[h]) : 0.125f;
    float m = -1e30f, l = 0.f;
    float o[16];
#pragma unroll
    for (int j = 0; j < 16; j++) o[j] = 0.f;

    int ntiles = 5 + qt;
    int lim = XLM + q0 + qr;

    for (int T = 0; T < ntiles; T++) {
        __syncthreads();
        {
            int r = t >> 4, d4 = (t & 15) * 4;
#pragma unroll
            for (int rr = 0; rr < 4; rr++) {
                int row = rr * 16 + r;
                int kg = T * 64 + row;
                const float *kp, *vp;
                if (kg < XLM) {
                    kp = &xlm[(((size_t)b * XLM + kg) * 2 + 0) * DH + d4];
                    vp = &xlm[(((size_t)b * XLM + kg) * 2 + 1) * DH + d4];
                } else {
                    kp = &kv[(size_t)(b * NSEQ + kg - XLM) * 128 + d4];
                    vp = kp + DH;
                }
                float4 kk = *(const float4*)kp;
                sK[row][d4] = kk.x; sK[row][d4 + 1] = kk.y; sK[row][d4 + 2] = kk.z; sK[row][d4 + 3] = kk.w;
                float4 vv = *(const float4*)vp;
                sV[row][d4] = vv.x; sV[row][d4 + 1] = vv.y; sV[row][d4 + 2] = vv.z; sV[row][d4 + 3] = vv.w;
            }
        }
        __syncthreads();

        float s[16];
#pragma unroll
        for (int j = 0; j < 16; j++) s[j] = 0.f;
        const float* qrow = &sQ[qr][0];
        const float* kbase = &sK[cg * 16][0];
        for (int d = 0; d < 64; d++) {
            float qv = qrow[d];
#pragma unroll
            for (int j = 0; j < 16; j++) s[j] += qv * kbase[j * 65 + d];
        }
        int kb = T * 64 + cg * 16;
#pragma unroll
        for (int j = 0; j < 16; j++) s[j] = (kb + j <= lim) ? s[j] * scale : -1e30f;

        float tm = s[0];
#pragma unroll
        for (int j = 1; j < 16; j++) tm = fmaxf(tm, s[j]);
        tm = fmaxf(tm, __shfl_xor(tm, 1, 64));
        tm = fmaxf(tm, __shfl_xor(tm, 2, 64));
        float mnew = fmaxf(m, tm);
        float alpha = __expf(m - mnew);
        float ps = 0.f;
#pragma unroll
        for (int j = 0; j < 16; j++) { s[j] = __expf(s[j] - mnew); ps += s[j]; }
        ps += __shfl_xor(ps, 1, 64);
        ps += __shfl_xor(ps, 2, 64);
        l = l * alpha + ps;
        m = mnew;
#pragma unroll
        for (int j = 0; j < 16; j++) o[j] *= alpha;

        int src0 = lane & ~3;
#pragma unroll
        for (int g = 0; g < 4; g++) {
            float pj[16];
#pragma unroll
            for (int j = 0; j < 16; j++) pj[j] = __shfl(s[j], src0 + g, 64);
            const float* vbase = &sV[g * 16][cg * 16];
#pragma unroll
            for (int j = 0; j < 16; j++) {
                float p = pj[j];
#pragma unroll
                for (int dd = 0; dd < 16; dd++) o[dd] += p * vbase[j * 65 + dd];
            }
        }
    }

    float inv = 1.0f / l;
    __hip_bfloat16* oph = &out[(size_t)(b * NSEQ + q0 + qr) * DIM + h * DH + cg * 16];
#pragma unroll
    for (int dd = 0; dd < 16; dd++) {
        float v = o[dd] * inv;
        __hip_bfloat16 hv = f2bf(v);
        oph[dd] = hv;
        oph[dd + opS] = f2bf(v - bf2f(hv));
    }
    if (KNNL && cg == 0) {
        size_t srow = (((size_t)b * NH + h) * NSEQ + q0 + qr) * 2;
        stats[srow] = m;
        stats[srow + 1] = l;
    }
}

// ---------------------------------------------------------------------------
// simdb = q_bh (1024x64 fp32, normalized) @ dbkn_b^T (64x4096), batched.
__global__ __launch_bounds__(256) void simdb_gemm(const float* __restrict__ q,
                                                  const float* __restrict__ dbkn,
                                                  float* __restrict__ simdb,
                                                  int bh0) {
    __shared__ float sQ[64][65];
    __shared__ float sK[64][65];
    int bh = bh0 + blockIdx.z;
    int b = bh >> 4, h = bh & 15;
    int m0 = blockIdx.x * 64, i0 = blockIdx.y * 64;
    int t = threadIdx.x;
    {
        int r = t >> 4, c4 = (t & 15) * 4;
#pragma unroll
        for (int rr = 0; rr < 4; rr++) {
            int row = rr * 16 + r;
            float4 qv = *(const float4*)&q[(size_t)(b * NSEQ + i0 + row) * DIM + h * DH + c4];
            sQ[row][c4] = qv.x; sQ[row][c4 + 1] = qv.y; sQ[row][c4 + 2] = qv.z; sQ[row][c4 + 3] = qv.w;
            float4 kk = *(const float4*)&dbkn[(size_t)(b * MDB + m0 + row) * DH + c4];
            sK[row][c4] = kk.x; sK[row][c4 + 1] = kk.y; sK[row][c4 + 2] = kk.z; sK[row][c4 + 3] = kk.w;
        }
    }
    __syncthreads();
    int ti = t >> 4, tm = t & 15;
    float acc[4][4] = {};
    for (int d = 0; d < 64; d++) {
        float a[4], bv[4];
#pragma unroll
        for (int j = 0; j < 4; j++) { a[j] = sQ[ti * 4 + j][d]; bv[j] = sK[tm * 4 + j][d]; }
#pragma unroll
        for (int i = 0; i < 4; i++)
#pragma unroll
            for (int j = 0; j < 4; j++) acc[i][j] += a[i] * bv[j];
    }
#pragma unroll
    for (int i = 0; i < 4; i++)
#pragma unroll
        for (int j = 0; j < 4; j++)
            simdb[((size_t)blockIdx.z * NSEQ + i0 + ti * 4 + i) * MDB + m0 + tm * 4 + j] = acc[i][j];
}

// ---------------------------------------------------------------------------
// Per-row top-32 over simdb + mem softmax + combine with local flash stats.
// Updates split-bf16 attn output (hi/lo planes).
__global__ void knn_select(const float* __restrict__ simdb,
                           const float* __restrict__ db,
                           const float* __restrict__ knn_scale,
                           const float* __restrict__ stats,
                           __hip_bfloat16* __restrict__ out,
                           size_t opS,
                           int bh0) {
    __shared__ float sv[64 * 65];
    int bh = bh0 + blockIdx.y;
    int b = bh >> 4, h = bh & 15;
    int i = blockIdx.x;
    int lane = threadIdx.x;

    const float* srow = &simdb[((size_t)blockIdx.y * NSEQ + i) * MDB];
    float lmax = -1e30f; int lidx = 0;
    for (int ii = 0; ii < 64; ii++) {
        float v = srow[ii * 64 + lane];
        sv[ii * 65 + lane] = v;
        if (v > lmax) { lmax = v; lidx = ii * 64 + lane; }
    }
    __syncthreads();

    float tv = 0.f; int ti = 0;
    for (int it = 0; it < TOPK; it++) {
        float v = lmax; int idx = lidx;
#pragma unroll
        for (int off = 32; off; off >>= 1) {
            float v2 = __shfl_xor(v, off, 64);
            int i2 = __shfl_xor(idx, off, 64);
            if (v2 > v || (v2 == v && i2 < idx)) { v = v2; idx = i2; }
        }
        if (lane == it) { tv = v; ti = idx; }
        int col = idx & 63;
        if (lane == (idx >> 6)) sv[(idx >> 6) * 65 + col] = -1e30f;
        __syncthreads();
        float rv = sv[lane * 65 + col];
        int ridx = lane * 64 + col;
#pragma unroll
        for (int off = 32; off; off >>= 1) {
            float v2 = __shfl_xor(rv, off, 64);
            int i2 = __shfl_xor(ridx, off, 64);
            if (v2 > rv || (v2 == rv && i2 < ridx)) { rv = v2; ridx = i2; }
        }
        if (lane == col) { lmax = rv; lidx = ridx; }
        __syncthreads();
    }

    float scl = __expf(knn_scale[h]);
    size_t srow_idx = (((size_t)b * NH + h) * NSEQ + i) * 2;
    float m_loc = stats[srow_idx], l_loc = stats[srow_idx + 1];
    float m_mem = __shfl(tv, 0, 64) * scl;
    float M = fmaxf(m_loc, m_mem);
    float e = (lane < TOPK) ? __expf(tv * scl - M) : 0.f;
    float esum = e;
#pragma unroll
    for (int off = 32; off; off >>= 1) esum += __shfl_xor(esum, off, 64);
    float co = __expf(m_loc - M);
    float denom = l_loc * co + esum;

    float acc = 0.f;
    for (int j = 0; j < TOPK; j++) {
        int idxj = __shfl(ti, j, 64);
        float ej = __shfl(e, j, 64);
        acc += ej * db[(((size_t)b * MDB + idxj) * 2 + 1) * DH + lane];
    }
    size_t op = (size_t)(b * NSEQ + i) * DIM + h * DH + lane;
    float o_loc = bf2f(out[op]) + bf2f(out[op + opS]);
    float nv = (o_loc * l_loc * co + acc) / denom;
    __hip_bfloat16 hv = f2bf(nv);
    out[op] = hv;
    out[op + opS] = f2bf(nv - bf2f(hv));
}

// ---------------------------------------------------------------------------
extern "C" void kernel_launch(void* const* d_in, const int* in_sizes, int n_in,
                              void* d_out, int out_size, void* d_ws, size_t ws_size,
                              hipStream_t stream) {
    const int* tokens = (const int*)d_in[0];
    const float* emb = (const float*)d_in[1];
    const float* ln1_w = (const float*)d_in[2];
    const float* ln1_b = (const float*)d_in[3];
    const float* wq = (const float*)d_in[4];
    const float* wkv = (const float*)d_in[5];
    const float* wo = (const float*)d_in[6];
    const float* wo_b = (const float*)d_in[7];
    const float* knn_scale = (const float*)d_in[8];
    const float* ln2_w = (const float*)d_in[9];
    const float* ln2_b = (const float*)d_in[10];
    const float* ff_w1 = (const float*)d_in[11];
    const float* ff_b1 = (const float*)d_in[12];
    const float* ff_w2 = (const float*)d_in[13];
    const float* ff_b2 = (const float*)d_in[14];
    const float* lnf_w = (const float*)d_in[15];
    const float* lnf_b = (const float*)d_in[16];
    const float* w_logits = (const float*)d_in[17];
    const float* b_logits = (const float*)d_in[18];
    const float* xl_mems = (const float*)d_in[19];
    const float* db_kv = (const float*)d_in[20];

    // ---- workspace layout ----
    const size_t PS_H = (size_t)BNROWS * DIM;        // plane stride for h / attn-out
    char* p = (char*)d_ws;
    float* x = (float*)p;                p += PS_H * 4;                        // 8 MB
    __hip_bfloat16* hb = (__hip_bfloat16*)p;  p += PS_H * 2 * 2;               // 8 MB (2 planes)
    float* qf = (float*)p;               p += PS_H * 4;                        // 8 MB
    float* kvf = (float*)p;              p += (size_t)BNROWS * 128 * 4;        // 1 MB
    float* dbkn = (float*)p;             p += (size_t)BB * MDB * DH * 4;       // 2 MB
    float* stats = (float*)p;            p += (size_t)BB * NH * NSEQ * 2 * 4;  // 0.25 MB
    __hip_bfloat16* wT = (__hip_bfloat16*)p; p += (size_t)4096 * DIM * 2 * 2;  // 16 MB (2 planes, max N=4096)

    // mid (split planes) + simdb live in d_out (temporally disjoint; logits
    // GEMM fully rewrites d_out at the end)
    const size_t PS_MID = (size_t)BNROWS * 4 * DIM;  // 8M elems per plane
    __hip_bfloat16* midb = (__hip_bfloat16*)d_out;   // 32 MB of the 262 MB out buf
    float* logits = (float*)d_out;
    int nbh_cap = (int)((size_t)out_size / ((size_t)NSEQ * MDB));
    if (nbh_cap > BB * NH) nbh_cap = BB * NH;
    if (nbh_cap < 1) nbh_cap = 1;

    embed_kernel<<<BNROWS, 256, 0, stream>>>(tokens, emb, x);
    dbnorm_kernel<<<BB * MDB, 64, 0, stream>>>(db_kv, dbkn);

    for (int l = 0; l < DEPTH; l++) {
        const float* wq_l = wq + (size_t)l * DIM * DIM;
        const float* wkv_l = wkv + (size_t)l * DIM * 128;
        const float* wo_l = wo + (size_t)l * DIM * DIM;
        const float* xlm_l = xl_mems + (size_t)l * BB * XLM * 2 * DH;

        // h = LN1(x) -> split bf16
        ln_kernel<<<BNROWS, 256, 0, stream>>>(x, ln1_w + (size_t)l * DIM, ln1_b + (size_t)l * DIM, hb, PS_H);

        // q = h @ wq  (fp32 out)
        wconv<<<dim3(16, 16), 256, 0, stream>>>(wq_l, wT, (size_t)DIM * DIM, DIM, DIM, DIM);
        gemm_split<float, 0><<<dim3(DIM / 128, BNROWS / 128), 256, 0, stream>>>(
            hb, DIM, PS_H, wT, DIM, (size_t)DIM * DIM, qf, DIM, 0, DIM, nullptr, nullptr);
        // kv = h @ wkv (fp32 out)
        wconv<<<dim3(16, 2), 256, 0, stream>>>(wkv_l, wT, (size_t)128 * DIM, DIM, 128, 128);
        gemm_split<float, 0><<<dim3(1, BNROWS / 128), 256, 0, stream>>>(
            hb, DIM, PS_H, wT, DIM, (size_t)128 * DIM, kvf, 128, 0, DIM, nullptr, nullptr);

        if (l == KNN_LAYER) {
            l2norm_kernel<<<BNROWS * NH, 64, 0, stream>>>(qf, DH);
            l2norm_kernel<<<BNROWS, 64, 0, stream>>>(kvf, 128);
            flash_kernel<1><<<dim3(NSEQ / 64, NH, BB), 256, 0, stream>>>(
                qf, kvf, xlm_l, knn_scale, hb, PS_H, stats);
            for (int bh0 = 0; bh0 < BB * NH; bh0 += nbh_cap) {
                int nb = BB * NH - bh0; if (nb > nbh_cap) nb = nbh_cap;
                simdb_gemm<<<dim3(MDB / 64, NSEQ / 64, nb), 256, 0, stream>>>(
                    qf, dbkn, (float*)d_out, bh0);
                knn_select<<<dim3(NSEQ, nb), 64, 0, stream>>>(
                    (float*)d_out, db_kv, knn_scale, stats, hb, PS_H, bh0);
            }
        } else {
            flash_kernel<0><<<dim3(NSEQ / 64, NH, BB), 256, 0, stream>>>(
                qf, kvf, xlm_l, knn_scale, hb, PS_H, stats);
        }

        // x = attn @ wo + wo_b + x
        wconv<<<dim3(16, 16), 256, 0, stream>>>(wo_l, wT, (size_t)DIM * DIM, DIM, DIM, DIM);
        gemm_split<float, 0><<<dim3(DIM / 128, BNROWS / 128), 256, 0, stream>>>(
            hb, DIM, PS_H, wT, DIM, (size_t)DIM * DIM, x, DIM, 0, DIM,
            wo_b + (size_t)l * DIM, x);

        // h = LN2(x)
        ln_kernel<<<BNROWS, 256, 0, stream>>>(x, ln2_w + (size_t)l * DIM, ln2_b + (size_t)l * DIM, hb, PS_H);
        // mid = gelu(h @ ff_w1 + b1) -> split bf16 (in d_out)
        wconv<<<dim3(16, 64), 256, 0, stream>>>(ff_w1 + (size_t)l * DIM * 4 * DIM, wT, (size_t)4096 * DIM, DIM, 4 * DIM, 4 * DIM);
        gemm_split<__hip_bfloat16, 1><<<dim3(4 * DIM / 128, BNROWS / 128), 256, 0, stream>>>(
            hb, DIM, PS_H, wT, DIM, (size_t)4096 * DIM, midb, 4 * DIM, PS_MID, DIM,
            ff_b1 + (size_t)l * 4 * DIM, nullptr);
        // x = mid @ ff_w2 + b2 + x
        wconv<<<dim3(64, 16), 256, 0, stream>>>(ff_w2 + (size_t)l * 4 * DIM * DIM, wT, (size_t)DIM * 4096, 4 * DIM, DIM, DIM);
        gemm_split<float, 0><<<dim3(DIM / 128, BNROWS / 128), 256, 0, stream>>>(
            midb, 4 * DIM, PS_MID, wT, 4 * DIM, (size_t)DIM * 4096, x, DIM, 0, 4 * DIM,
            ff_b2 + (size_t)l * DIM, x);
    }

    // final LN + logits (10 column chunks of 3200)
    ln_kernel<<<BNROWS, 256, 0, stream>>>(x, lnf_w, lnf_b, hb, PS_H);
    for (int c0 = 0; c0 < VOCAB; c0 += LOGITS_CHUNK) {
        wconv<<<dim3(16, LOGITS_CHUNK / 64), 256, 0, stream>>>(
            w_logits + c0, wT, (size_t)LOGITS_CHUNK * DIM, DIM, LOGITS_CHUNK, VOCAB);
        gemm_split<float, 0><<<dim3(LOGITS_CHUNK / 128, BNROWS / 128), 256, 0, stream>>>(
            hb, DIM, PS_H, wT, DIM, (size_t)LOGITS_CHUNK * DIM, logits + c0, VOCAB, 0, DIM,
            b_logits + c0, nullptr);
    }
}

// Round 6
// 3626.876 us; speedup vs baseline: 5.2384x; 1.8699x over previous
//
#include <hip/hip_runtime.h>
#include <hip/hip_bf16.h>
#include <math.h>

// Problem constants (from setup_inputs)
#define BB 2
#define NSEQ 1024
#define DIM 1024
#define NH 16
#define DH 64
#define DEPTH 4
#define VOCAB 32000
#define XLM 256
#define MDB 4096
#define TOPK 32
#define KNN_LAYER 2
#define BNROWS (BB * NSEQ)   // 2048
#define LOGITS_CHUNK 3200    // 32000 = 10 * 3200; 3200 % 128 == 0

typedef __bf16 bf16x8v __attribute__((ext_vector_type(8)));
typedef float f32x4v __attribute__((ext_vector_type(4)));
typedef unsigned short u16x8v __attribute__((ext_vector_type(8)));

__device__ __forceinline__ float bfbits2f(unsigned short u) {
    union { float f; unsigned int i; } v; v.i = ((unsigned int)u) << 16; return v.f;
}
__device__ __forceinline__ unsigned short f2bfbits(float f) {
    union { __hip_bfloat16 b; unsigned short u; } v;
    v.b = __float2bfloat16(f);
    return v.u;
}
__device__ __forceinline__ float bf2f(__hip_bfloat16 h) { return __bfloat162float(h); }
__device__ __forceinline__ __hip_bfloat16 f2bf(float f) { return __float2bfloat16(f); }

__device__ __forceinline__ void gload16(const void* gp, void* lp) {
    __builtin_amdgcn_global_load_lds(
        (const __attribute__((address_space(1))) unsigned int*)gp,
        (__attribute__((address_space(3))) unsigned int*)lp, 16, 0, 0);
}

// ---------------------------------------------------------------------------
__global__ __launch_bounds__(256) void embed_kernel(const int* __restrict__ tok,
                                                    const float* __restrict__ emb,
                                                    float* __restrict__ x) {
    int r = blockIdx.x, t = threadIdx.x;
    int id = tok[r];
    const float* er = emb + (size_t)id * DIM;
    float* xr = x + (size_t)r * DIM;
#pragma unroll
    for (int i = 0; i < 4; i++) xr[t + 256 * i] = er[t + 256 * i];
}

// ---------------------------------------------------------------------------
// Row LayerNorm over DIM=1024, fp32 in, split-bf16 (hi/lo planes) out
__global__ __launch_bounds__(256) void ln_kernel(const float* __restrict__ x,
                                                 const float* __restrict__ w,
                                                 const float* __restrict__ b,
                                                 __hip_bfloat16* __restrict__ y,
                                                 size_t ypS) {
    __shared__ float red[256];
    int r = blockIdx.x, t = threadIdx.x;
    const float* xr = x + (size_t)r * DIM;
    float v[4];
#pragma unroll
    for (int i = 0; i < 4; i++) v[i] = xr[t + 256 * i];
    float s = v[0] + v[1] + v[2] + v[3];
    red[t] = s; __syncthreads();
    for (int st = 128; st; st >>= 1) { if (t < st) red[t] += red[t + st]; __syncthreads(); }
    float mean = red[0] * (1.0f / DIM);
    __syncthreads();
    float s2 = 0.f;
#pragma unroll
    for (int i = 0; i < 4; i++) { float d = v[i] - mean; s2 += d * d; }
    red[t] = s2; __syncthreads();
    for (int st = 128; st; st >>= 1) { if (t < st) red[t] += red[t + st]; __syncthreads(); }
    float rs = rsqrtf(red[0] * (1.0f / DIM) + 1e-5f);
    __hip_bfloat16* yr = y + (size_t)r * DIM;
#pragma unroll
    for (int i = 0; i < 4; i++) {
        int c = t + 256 * i;
        float val = (v[i] - mean) * rs * w[c] + b[c];
        __hip_bfloat16 hv = f2bf(val);
        yr[c] = hv;
        yr[c + ypS] = f2bf(val - bf2f(hv));
    }
}

// ---------------------------------------------------------------------------
// L2-normalize fp32 rows of length 64 (row stride configurable), in-place
__global__ void l2norm_kernel(float* __restrict__ p, int stride) {
    int r = blockIdx.x, t = threadIdx.x; // 64 threads
    float* pr = p + (size_t)r * stride;
    float v = pr[t];
    float s = v * v;
#pragma unroll
    for (int off = 32; off; off >>= 1) s += __shfl_xor(s, off, 64);
    float n = fmaxf(sqrtf(s), 1e-12f);
    pr[t] = v / n;
}

__global__ void dbnorm_kernel(const float* __restrict__ db, float* __restrict__ dbkn) {
    int r = blockIdx.x, t = threadIdx.x; // 64 threads
    float v = db[((size_t)r * 2 + 0) * DH + t];
    float s = v * v;
#pragma unroll
    for (int off = 32; off; off >>= 1) s += __shfl_xor(s, off, 64);
    float n = fmaxf(sqrtf(s), 1e-12f);
    dbkn[(size_t)r * DH + t] = v / n;
}

// ---------------------------------------------------------------------------
// Weight convert + transpose: W (K x N fp32, row stride ldw) ->
// WT (N x K split-bf16, hi plane + lo plane at +wpS)
__global__ __launch_bounds__(256) void wconv(const float* __restrict__ W,
                                             __hip_bfloat16* __restrict__ WT,
                                             size_t wpS, int K, int N, int ldw) {
    __shared__ float tile[64][65];
    int k0 = blockIdx.x * 64, n0 = blockIdx.y * 64;
    int t = threadIdx.x;
    int r = t >> 4, c4 = (t & 15) * 4;
#pragma unroll
    for (int rr = 0; rr < 4; rr++) {
        int row = rr * 16 + r;
        float4 v = *(const float4*)&W[(size_t)(k0 + row) * ldw + n0 + c4];
        tile[row][c4] = v.x; tile[row][c4 + 1] = v.y; tile[row][c4 + 2] = v.z; tile[row][c4 + 3] = v.w;
    }
    __syncthreads();
#pragma unroll
    for (int rr = 0; rr < 4; rr++) {
        int nrow = rr * 16 + r;
        size_t base = (size_t)(n0 + nrow) * K + k0 + c4;
#pragma unroll
        for (int j = 0; j < 4; j++) {
            float val = tile[c4 + j][nrow];
            __hip_bfloat16 hv = f2bf(val);
            WT[base + j] = hv;
            WT[base + j + wpS] = f2bf(val - bf2f(hv));
        }
    }
}

// ---------------------------------------------------------------------------
// Split-bf16 MFMA GEMM: C(MxN) = A(MxK) @ BT(NxK)^T with A,B as hi/lo planes.
template <typename OT, int ACT>
__global__ __launch_bounds__(256) void gemm_split(const __hip_bfloat16* __restrict__ A, int lda, size_t apS,
                                                  const __hip_bfloat16* __restrict__ BT, int ldb, size_t bpS,
                                                  OT* __restrict__ C, int ldc, size_t cpS, int K,
                                                  const float* __restrict__ bias,
                                                  const float* __restrict__ res) {
    __shared__ __align__(16) __hip_bfloat16 sAh[128 * 32];
    __shared__ __align__(16) __hip_bfloat16 sAl[128 * 32];
    __shared__ __align__(16) __hip_bfloat16 sBh[128 * 32];
    __shared__ __align__(16) __hip_bfloat16 sBl[128 * 32];
    int bn = blockIdx.x * 128;
    int bm = blockIdx.y * 128;
    int t = threadIdx.x;
    int lane = t & 63, wid = t >> 6;
    int wr = wid >> 1, wc = wid & 1;
    int lr = lane & 15, kc = lane >> 4;

    f32x4v acc[4][4];
#pragma unroll
    for (int m = 0; m < 4; m++)
#pragma unroll
        for (int n = 0; n < 4; n++) acc[m][n] = (f32x4v){0.f, 0.f, 0.f, 0.f};

    for (int k0 = 0; k0 < K; k0 += 32) {
        __syncthreads();
#pragma unroll
        for (int it = 0; it < 2; it++) {
            int e = wid * 128 + it * 64 + lane;
            int r = e >> 2;
            int cl = (e & 3) ^ ((r >> 1) & 3);
            size_t aoff = (size_t)(bm + r) * lda + k0 + cl * 8;
            size_t boff = (size_t)(bn + r) * ldb + k0 + cl * 8;
            int dst = (wid * 128 + it * 64) * 8;
            gload16(&A[aoff], &sAh[dst]);
            gload16(&A[aoff + apS], &sAl[dst]);
            gload16(&BT[boff], &sBh[dst]);
            gload16(&BT[boff + bpS], &sBl[dst]);
        }
        __syncthreads();

        bf16x8v ah[4], al[4], bh[4], bl[4];
#pragma unroll
        for (int m = 0; m < 4; m++) {
            int row = wr * 64 + m * 16 + lr;
            int off = row * 32 + ((kc ^ ((row >> 1) & 3)) << 3);
            ah[m] = *(const bf16x8v*)&sAh[off];
            al[m] = *(const bf16x8v*)&sAl[off];
        }
#pragma unroll
        for (int n = 0; n < 4; n++) {
            int row = wc * 64 + n * 16 + lr;
            int off = row * 32 + ((kc ^ ((row >> 1) & 3)) << 3);
            bh[n] = *(const bf16x8v*)&sBh[off];
            bl[n] = *(const bf16x8v*)&sBl[off];
        }
#pragma unroll
        for (int m = 0; m < 4; m++)
#pragma unroll
            for (int n = 0; n < 4; n++) {
                acc[m][n] = __builtin_amdgcn_mfma_f32_16x16x32_bf16(ah[m], bh[n], acc[m][n], 0, 0, 0);
                acc[m][n] = __builtin_amdgcn_mfma_f32_16x16x32_bf16(al[m], bh[n], acc[m][n], 0, 0, 0);
                acc[m][n] = __builtin_amdgcn_mfma_f32_16x16x32_bf16(ah[m], bl[n], acc[m][n], 0, 0, 0);
            }
    }

#pragma unroll
    for (int m = 0; m < 4; m++) {
#pragma unroll
        for (int n = 0; n < 4; n++) {
            int gcol = bn + wc * 64 + n * 16 + lr;
            float bv = bias ? bias[gcol] : 0.f;
#pragma unroll
            for (int j = 0; j < 4; j++) {
                int grow = bm + wr * 64 + m * 16 + kc * 4 + j;
                float v = acc[m][n][j] + bv;
                if (ACT == 1) v = 0.5f * v * (1.0f + erff(v * 0.70710678118654752f));
                if (res) v += res[(size_t)grow * ldc + gcol];
                size_t idx = (size_t)grow * ldc + gcol;
                if constexpr (__is_same(OT, float)) {
                    C[idx] = v;
                } else {
                    __hip_bfloat16 hv = f2bf(v);
                    C[idx] = hv;
                    C[idx + cpS] = f2bf(v - bf2f(hv));
                }
            }
        }
    }
}

// ---------------------------------------------------------------------------
// Split-bf16 MFMA flash attention over XL + causal local keys.
// Block = 256 thr = 4 waves; wave w owns q rows [q0+w*16, q0+w*16+16).
// Per 64-key tile: K[key][dim] and Vt[dim][key] staged in LDS (hi/lo planes,
// XOR chunk swizzle); QK^T and PV use 3-term split MFMA (fp32-grade).
// P kept fp32 in wave-private LDS (chunk-swizzled); online softmax in regs.
template <int KNNL>
__global__ __launch_bounds__(256) void flash_kernel(const float* __restrict__ q,
                                                    const float* __restrict__ kv,
                                                    const float* __restrict__ xlm,
                                                    const float* __restrict__ knn_scale,
                                                    __hip_bfloat16* __restrict__ out,
                                                    size_t opS,
                                                    float* __restrict__ stats) {
    __shared__ __align__(16) unsigned short sKh[64 * 64];
    __shared__ __align__(16) unsigned short sKl[64 * 64];
    __shared__ __align__(16) unsigned short sVh[64 * 64];   // transposed [dim][key]
    __shared__ __align__(16) unsigned short sVl[64 * 64];
    __shared__ __align__(16) float sPf[4 * 16 * 64];        // per-wave P fp32

    int qt = blockIdx.x, h = blockIdx.y, b = blockIdx.z;
    int q0 = qt * 64;
    int t = threadIdx.x;
    int w = t >> 6;
    int lane = t & 63;
    int lr = lane & 15, kc = lane >> 4;
    int wbase = w * 1024;

    float scale = KNNL ? __expf(knn_scale[h]) : 0.125f;

    // Q fragments (A-layout: row=lr, k=kc*8+e per kstep), held in registers
    bf16x8v qh[2], ql[2];
    {
        const float* qbase = q + (size_t)(b * NSEQ + q0 + w * 16 + lr) * DIM + h * DH;
#pragma unroll
        for (int ks = 0; ks < 2; ks++) {
            const float* s = qbase + ks * 32 + kc * 8;
            float4 a = *(const float4*)s;
            float4 c2 = *(const float4*)(s + 4);
            float vv[8] = {a.x, a.y, a.z, a.w, c2.x, c2.y, c2.z, c2.w};
            u16x8v hi, lo;
#pragma unroll
            for (int j = 0; j < 8; j++) {
                hi[j] = f2bfbits(vv[j]);
                lo[j] = f2bfbits(vv[j] - bfbits2f(hi[j]));
            }
            qh[ks] = *(bf16x8v*)&hi;
            ql[ks] = *(bf16x8v*)&lo;
        }
    }

    float m[4], l[4];
    f32x4v o[4];
#pragma unroll
    for (int j = 0; j < 4; j++) { m[j] = -1e30f; l[j] = 0.f; }
#pragma unroll
    for (int f = 0; f < 4; f++) o[f] = (f32x4v){0.f, 0.f, 0.f, 0.f};

    int ntiles = 5 + qt;

    for (int T = 0; T < ntiles; T++) {
        const float* srcK = (T < 4)
            ? xlm + ((size_t)(b * XLM + T * 64) * 2) * DH
            : kv + (size_t)(b * NSEQ + T * 64 - XLM) * 128;
        __syncthreads();
        // ---- stage K: [key][dim], 16B chunks, chunk slot = ch ^ (key&7)
#pragma unroll
        for (int i = 0; i < 2; i++) {
            int idx = i * 256 + t;
            int key = idx >> 3, ch = idx & 7;
            const float* s = srcK + key * 128 + ch * 8;
            float4 a = *(const float4*)s;
            float4 c2 = *(const float4*)(s + 4);
            float vv[8] = {a.x, a.y, a.z, a.w, c2.x, c2.y, c2.z, c2.w};
            u16x8v hi, lo;
#pragma unroll
            for (int j = 0; j < 8; j++) {
                hi[j] = f2bfbits(vv[j]);
                lo[j] = f2bfbits(vv[j] - bfbits2f(hi[j]));
            }
            int off = key * 64 + ((ch ^ (key & 7)) << 3);
            *(u16x8v*)&sKh[off] = hi;
            *(u16x8v*)&sKl[off] = lo;
        }
        // ---- stage V transposed: [dim][key], key-chunk slot = (key>>3)^(dim&7)
#pragma unroll
        for (int i = 0; i < 4; i++) {
            int idx = i * 256 + t;
            int key = idx & 63, dg = idx >> 6;
            const float* s = srcK + key * 128 + 64 + dg * 4;
            float4 v = *(const float4*)s;
            float vv[4] = {v.x, v.y, v.z, v.w};
#pragma unroll
            for (int j = 0; j < 4; j++) {
                int dim = dg * 4 + j;
                unsigned short hi = f2bfbits(vv[j]);
                unsigned short lo = f2bfbits(vv[j] - bfbits2f(hi));
                int off = dim * 64 + (((key >> 3) ^ (dim & 7)) << 3) + (key & 7);
                sVh[off] = hi;
                sVl[off] = lo;
            }
        }
        __syncthreads();

        // ---- QK^T (split, 3 mfma per frag)
        f32x4v s4[4];
#pragma unroll
        for (int n = 0; n < 4; n++) s4[n] = (f32x4v){0.f, 0.f, 0.f, 0.f};
#pragma unroll
        for (int ks = 0; ks < 2; ks++) {
            bf16x8v qh_ = qh[ks], ql_ = ql[ks];
#pragma unroll
            for (int n = 0; n < 4; n++) {
                int row = n * 16 + lr;
                int off = row * 64 + (((ks * 4 + kc) ^ (lr & 7)) << 3);
                bf16x8v kh = *(const bf16x8v*)&sKh[off];
                bf16x8v kl = *(const bf16x8v*)&sKl[off];
                s4[n] = __builtin_amdgcn_mfma_f32_16x16x32_bf16(qh_, kh, s4[n], 0, 0, 0);
                s4[n] = __builtin_amdgcn_mfma_f32_16x16x32_bf16(ql_, kh, s4[n], 0, 0, 0);
                s4[n] = __builtin_amdgcn_mfma_f32_16x16x32_bf16(qh_, kl, s4[n], 0, 0, 0);
            }
        }

        // ---- scale + causal mask (allowed: key <= XLM + gq)
#pragma unroll
        for (int n = 0; n < 4; n++) {
            int key = T * 64 + n * 16 + lr;
#pragma unroll
            for (int j = 0; j < 4; j++) {
                int gq = q0 + w * 16 + kc * 4 + j;
                float sv = s4[n][j] * scale;
                s4[n][j] = (key <= XLM + gq) ? sv : -1e30f;
            }
        }

        // ---- online softmax (row stats in 16-lane shfl group)
        float tm[4];
#pragma unroll
        for (int j = 0; j < 4; j++) {
            float v = fmaxf(fmaxf(s4[0][j], s4[1][j]), fmaxf(s4[2][j], s4[3][j]));
            v = fmaxf(v, __shfl_xor(v, 1, 64));
            v = fmaxf(v, __shfl_xor(v, 2, 64));
            v = fmaxf(v, __shfl_xor(v, 4, 64));
            v = fmaxf(v, __shfl_xor(v, 8, 64));
            tm[j] = v;
        }
        float alpha[4];
#pragma unroll
        for (int j = 0; j < 4; j++) {
            float mnew = fmaxf(m[j], tm[j]);
            alpha[j] = __expf(m[j] - mnew);
            m[j] = mnew;
        }
        float psum[4] = {0.f, 0.f, 0.f, 0.f};
#pragma unroll
        for (int n = 0; n < 4; n++)
#pragma unroll
            for (int j = 0; j < 4; j++) {
                float p = __expf(s4[n][j] - m[j]);
                s4[n][j] = p;
                psum[j] += p;
            }
#pragma unroll
        for (int j = 0; j < 4; j++) {
            float v = psum[j];
            v += __shfl_xor(v, 1, 64);
            v += __shfl_xor(v, 2, 64);
            v += __shfl_xor(v, 4, 64);
            v += __shfl_xor(v, 8, 64);
            l[j] = l[j] * alpha[j] + v;
        }
#pragma unroll
        for (int f = 0; f < 4; f++)
#pragma unroll
            for (int j = 0; j < 4; j++) o[f][j] *= alpha[j];

        // ---- write P (fp32) to wave-private LDS, 8-elem chunk swizzle
#pragma unroll
        for (int n = 0; n < 4; n++) {
            int chunkcol = 2 * n + (lr >> 3);
#pragma unroll
            for (int j = 0; j < 4; j++) {
                int row = kc * 4 + j;
                int off = wbase + row * 64 + (((chunkcol ^ (row & 7)) << 3) + (lr & 7));
                sPf[off] = s4[n][j];
            }
        }

        // ---- PV (split, 3 mfma per frag); A = P from LDS, B = Vt
#pragma unroll
        for (int ks = 0; ks < 2; ks++) {
            int poff = wbase + lr * 64 + (((ks * 4 + kc) ^ (lr & 7)) << 3);
            float4 a = *(const float4*)&sPf[poff];
            float4 c2 = *(const float4*)&sPf[poff + 4];
            float vv[8] = {a.x, a.y, a.z, a.w, c2.x, c2.y, c2.z, c2.w};
            u16x8v hib, lob;
#pragma unroll
            for (int j = 0; j < 8; j++) {
                hib[j] = f2bfbits(vv[j]);
                lob[j] = f2bfbits(vv[j] - bfbits2f(hib[j]));
            }
            bf16x8v ph = *(bf16x8v*)&hib;
            bf16x8v pl = *(bf16x8v*)&lob;
#pragma unroll
            for (int f = 0; f < 4; f++) {
                int row = f * 16 + lr;
                int off = row * 64 + (((ks * 4 + kc) ^ (lr & 7)) << 3);
                bf16x8v vh = *(const bf16x8v*)&sVh[off];
                bf16x8v vl = *(const bf16x8v*)&sVl[off];
                o[f] = __builtin_amdgcn_mfma_f32_16x16x32_bf16(ph, vh, o[f], 0, 0, 0);
                o[f] = __builtin_amdgcn_mfma_f32_16x16x32_bf16(pl, vh, o[f], 0, 0, 0);
                o[f] = __builtin_amdgcn_mfma_f32_16x16x32_bf16(ph, vl, o[f], 0, 0, 0);
            }
        }
    }

    // ---- epilogue: O / l, split-bf16 write; stats for KNN combine
    float inv[4];
#pragma unroll
    for (int j = 0; j < 4; j++) inv[j] = 1.0f / l[j];
    unsigned short* outu = (unsigned short*)out;
#pragma unroll
    for (int f = 0; f < 4; f++)
#pragma unroll
        for (int j = 0; j < 4; j++) {
            int gq = q0 + w * 16 + kc * 4 + j;
            size_t oidx = (size_t)(b * NSEQ + gq) * DIM + h * DH + f * 16 + lr;
            float v = o[f][j] * inv[j];
            unsigned short hv = f2bfbits(v);
            outu[oidx] = hv;
            outu[oidx + opS] = f2bfbits(v - bfbits2f(hv));
        }
    if (KNNL && lr == 0) {
#pragma unroll
        for (int j = 0; j < 4; j++) {
            int gq = q0 + w * 16 + kc * 4 + j;
            size_t srow = (((size_t)b * NH + h) * NSEQ + gq) * 2;
            stats[srow] = m[j];
            stats[srow + 1] = l[j];
        }
    }
}

// ---------------------------------------------------------------------------
// simdb = q_bh (1024x64 fp32, normalized) @ dbkn_b^T (64x4096), batched.
__global__ __launch_bounds__(256) void simdb_gemm(const float* __restrict__ q,
                                                  const float* __restrict__ dbkn,
                                                  float* __restrict__ simdb,
                                                  int bh0) {
    __shared__ float sQ[64][65];
    __shared__ float sK[64][65];
    int bh = bh0 + blockIdx.z;
    int b = bh >> 4, h = bh & 15;
    int m0 = blockIdx.x * 64, i0 = blockIdx.y * 64;
    int t = threadIdx.x;
    {
        int r = t >> 4, c4 = (t & 15) * 4;
#pragma unroll
        for (int rr = 0; rr < 4; rr++) {
            int row = rr * 16 + r;
            float4 qv = *(const float4*)&q[(size_t)(b * NSEQ + i0 + row) * DIM + h * DH + c4];
            sQ[row][c4] = qv.x; sQ[row][c4 + 1] = qv.y; sQ[row][c4 + 2] = qv.z; sQ[row][c4 + 3] = qv.w;
            float4 kk = *(const float4*)&dbkn[(size_t)(b * MDB + m0 + row) * DH + c4];
            sK[row][c4] = kk.x; sK[row][c4 + 1] = kk.y; sK[row][c4 + 2] = kk.z; sK[row][c4 + 3] = kk.w;
        }
    }
    __syncthreads();
    int ti = t >> 4, tm = t & 15;
    float acc[4][4] = {};
    for (int d = 0; d < 64; d++) {
        float a[4], bv[4];
#pragma unroll
        for (int j = 0; j < 4; j++) { a[j] = sQ[ti * 4 + j][d]; bv[j] = sK[tm * 4 + j][d]; }
#pragma unroll
        for (int i = 0; i < 4; i++)
#pragma unroll
            for (int j = 0; j < 4; j++) acc[i][j] += a[i] * bv[j];
    }
#pragma unroll
    for (int i = 0; i < 4; i++)
#pragma unroll
        for (int j = 0; j < 4; j++)
            simdb[((size_t)blockIdx.z * NSEQ + i0 + ti * 4 + i) * MDB + m0 + tm * 4 + j] = acc[i][j];
}

// ---------------------------------------------------------------------------
// Per-row top-32 over simdb + mem softmax + combine with local flash stats.
__global__ void knn_select(const float* __restrict__ simdb,
                           const float* __restrict__ db,
                           const float* __restrict__ knn_scale,
                           const float* __restrict__ stats,
                           __hip_bfloat16* __restrict__ out,
                           size_t opS,
                           int bh0) {
    __shared__ float sv[64 * 65];
    int bh = bh0 + blockIdx.y;
    int b = bh >> 4, h = bh & 15;
    int i = blockIdx.x;
    int lane = threadIdx.x;

    const float* srow = &simdb[((size_t)blockIdx.y * NSEQ + i) * MDB];
    float lmax = -1e30f; int lidx = 0;
    for (int ii = 0; ii < 64; ii++) {
        float v = srow[ii * 64 + lane];
        sv[ii * 65 + lane] = v;
        if (v > lmax) { lmax = v; lidx = ii * 64 + lane; }
    }
    __syncthreads();

    float tv = 0.f; int ti = 0;
    for (int it = 0; it < TOPK; it++) {
        float v = lmax; int idx = lidx;
#pragma unroll
        for (int off = 32; off; off >>= 1) {
            float v2 = __shfl_xor(v, off, 64);
            int i2 = __shfl_xor(idx, off, 64);
            if (v2 > v || (v2 == v && i2 < idx)) { v = v2; idx = i2; }
        }
        if (lane == it) { tv = v; ti = idx; }
        int col = idx & 63;
        if (lane == (idx >> 6)) sv[(idx >> 6) * 65 + col] = -1e30f;
        __syncthreads();
        float rv = sv[lane * 65 + col];
        int ridx = lane * 64 + col;
#pragma unroll
        for (int off = 32; off; off >>= 1) {
            float v2 = __shfl_xor(rv, off, 64);
            int i2 = __shfl_xor(ridx, off, 64);
            if (v2 > rv || (v2 == rv && i2 < ridx)) { rv = v2; ridx = i2; }
        }
        if (lane == col) { lmax = rv; lidx = ridx; }
        __syncthreads();
    }

    float scl = __expf(knn_scale[h]);
    size_t srow_idx = (((size_t)b * NH + h) * NSEQ + i) * 2;
    float m_loc = stats[srow_idx], l_loc = stats[srow_idx + 1];
    float m_mem = __shfl(tv, 0, 64) * scl;
    float M = fmaxf(m_loc, m_mem);
    float e = (lane < TOPK) ? __expf(tv * scl - M) : 0.f;
    float esum = e;
#pragma unroll
    for (int off = 32; off; off >>= 1) esum += __shfl_xor(esum, off, 64);
    float co = __expf(m_loc - M);
    float denom = l_loc * co + esum;

    float acc = 0.f;
    for (int j = 0; j < TOPK; j++) {
        int idxj = __shfl(ti, j, 64);
        float ej = __shfl(e, j, 64);
        acc += ej * db[(((size_t)b * MDB + idxj) * 2 + 1) * DH + lane];
    }
    size_t op = (size_t)(b * NSEQ + i) * DIM + h * DH + lane;
    float o_loc = bf2f(out[op]) + bf2f(out[op + opS]);
    float nv = (o_loc * l_loc * co + acc) / denom;
    __hip_bfloat16 hv = f2bf(nv);
    out[op] = hv;
    out[op + opS] = f2bf(nv - bf2f(hv));
}

// ---------------------------------------------------------------------------
extern "C" void kernel_launch(void* const* d_in, const int* in_sizes, int n_in,
                              void* d_out, int out_size, void* d_ws, size_t ws_size,
                              hipStream_t stream) {
    const int* tokens = (const int*)d_in[0];
    const float* emb = (const float*)d_in[1];
    const float* ln1_w = (const float*)d_in[2];
    const float* ln1_b = (const float*)d_in[3];
    const float* wq = (const float*)d_in[4];
    const float* wkv = (const float*)d_in[5];
    const float* wo = (const float*)d_in[6];
    const float* wo_b = (const float*)d_in[7];
    const float* knn_scale = (const float*)d_in[8];
    const float* ln2_w = (const float*)d_in[9];
    const float* ln2_b = (const float*)d_in[10];
    const float* ff_w1 = (const float*)d_in[11];
    const float* ff_b1 = (const float*)d_in[12];
    const float* ff_w2 = (const float*)d_in[13];
    const float* ff_b2 = (const float*)d_in[14];
    const float* lnf_w = (const float*)d_in[15];
    const float* lnf_b = (const float*)d_in[16];
    const float* w_logits = (const float*)d_in[17];
    const float* b_logits = (const float*)d_in[18];
    const float* xl_mems = (const float*)d_in[19];
    const float* db_kv = (const float*)d_in[20];

    // ---- workspace layout ----
    const size_t PS_H = (size_t)BNROWS * DIM;        // plane stride for h / attn-out
    char* p = (char*)d_ws;
    float* x = (float*)p;                p += PS_H * 4;                        // 8 MB
    __hip_bfloat16* hb = (__hip_bfloat16*)p;  p += PS_H * 2 * 2;               // 8 MB (2 planes)
    float* qf = (float*)p;               p += PS_H * 4;                        // 8 MB
    float* kvf = (float*)p;              p += (size_t)BNROWS * 128 * 4;        // 1 MB
    float* dbkn = (float*)p;             p += (size_t)BB * MDB * DH * 4;       // 2 MB
    float* stats = (float*)p;            p += (size_t)BB * NH * NSEQ * 2 * 4;  // 0.25 MB
    __hip_bfloat16* wT = (__hip_bfloat16*)p; p += (size_t)4096 * DIM * 2 * 2;  // 16 MB (2 planes, max N=4096)

    const size_t PS_MID = (size_t)BNROWS * 4 * DIM;  // 8M elems per plane
    __hip_bfloat16* midb = (__hip_bfloat16*)d_out;   // 32 MB of the 262 MB out buf
    float* logits = (float*)d_out;
    int nbh_cap = (int)((size_t)out_size / ((size_t)NSEQ * MDB));
    if (nbh_cap > BB * NH) nbh_cap = BB * NH;
    if (nbh_cap < 1) nbh_cap = 1;

    embed_kernel<<<BNROWS, 256, 0, stream>>>(tokens, emb, x);
    dbnorm_kernel<<<BB * MDB, 64, 0, stream>>>(db_kv, dbkn);

    for (int l = 0; l < DEPTH; l++) {
        const float* wq_l = wq + (size_t)l * DIM * DIM;
        const float* wkv_l = wkv + (size_t)l * DIM * 128;
        const float* wo_l = wo + (size_t)l * DIM * DIM;
        const float* xlm_l = xl_mems + (size_t)l * BB * XLM * 2 * DH;

        // h = LN1(x) -> split bf16
        ln_kernel<<<BNROWS, 256, 0, stream>>>(x, ln1_w + (size_t)l * DIM, ln1_b + (size_t)l * DIM, hb, PS_H);

        // q = h @ wq  (fp32 out)
        wconv<<<dim3(16, 16), 256, 0, stream>>>(wq_l, wT, (size_t)DIM * DIM, DIM, DIM, DIM);
        gemm_split<float, 0><<<dim3(DIM / 128, BNROWS / 128), 256, 0, stream>>>(
            hb, DIM, PS_H, wT, DIM, (size_t)DIM * DIM, qf, DIM, 0, DIM, nullptr, nullptr);
        // kv = h @ wkv (fp32 out)
        wconv<<<dim3(16, 2), 256, 0, stream>>>(wkv_l, wT, (size_t)128 * DIM, DIM, 128, 128);
        gemm_split<float, 0><<<dim3(1, BNROWS / 128), 256, 0, stream>>>(
            hb, DIM, PS_H, wT, DIM, (size_t)128 * DIM, kvf, 128, 0, DIM, nullptr, nullptr);

        if (l == KNN_LAYER) {
            l2norm_kernel<<<BNROWS * NH, 64, 0, stream>>>(qf, DH);
            l2norm_kernel<<<BNROWS, 64, 0, stream>>>(kvf, 128);
            flash_kernel<1><<<dim3(NSEQ / 64, NH, BB), 256, 0, stream>>>(
                qf, kvf, xlm_l, knn_scale, hb, PS_H, stats);
            for (int bh0 = 0; bh0 < BB * NH; bh0 += nbh_cap) {
                int nb = BB * NH - bh0; if (nb > nbh_cap) nb = nbh_cap;
                simdb_gemm<<<dim3(MDB / 64, NSEQ / 64, nb), 256, 0, stream>>>(
                    qf, dbkn, (float*)d_out, bh0);
                knn_select<<<dim3(NSEQ, nb), 64, 0, stream>>>(
                    (float*)d_out, db_kv, knn_scale, stats, hb, PS_H, bh0);
            }
        } else {
            flash_kernel<0><<<dim3(NSEQ / 64, NH, BB), 256, 0, stream>>>(
                qf, kvf, xlm_l, knn_scale, hb, PS_H, stats);
        }

        // x = attn @ wo + wo_b + x
        wconv<<<dim3(16, 16), 256, 0, stream>>>(wo_l, wT, (size_t)DIM * DIM, DIM, DIM, DIM);
        gemm_split<float, 0><<<dim3(DIM / 128, BNROWS / 128), 256, 0, stream>>>(
            hb, DIM, PS_H, wT, DIM, (size_t)DIM * DIM, x, DIM, 0, DIM,
            wo_b + (size_t)l * DIM, x);

        // h = LN2(x)
        ln_kernel<<<BNROWS, 256, 0, stream>>>(x, ln2_w + (size_t)l * DIM, ln2_b + (size_t)l * DIM, hb, PS_H);
        // mid = gelu(h @ ff_w1 + b1) -> split bf16 (in d_out)
        wconv<<<dim3(16, 64), 256, 0, stream>>>(ff_w1 + (size_t)l * DIM * 4 * DIM, wT, (size_t)4096 * DIM, DIM, 4 * DIM, 4 * DIM);
        gemm_split<__hip_bfloat16, 1><<<dim3(4 * DIM / 128, BNROWS / 128), 256, 0, stream>>>(
            hb, DIM, PS_H, wT, DIM, (size_t)4096 * DIM, midb, 4 * DIM, PS_MID, DIM,
            ff_b1 + (size_t)l * 4 * DIM, nullptr);
        // x = mid @ ff_w2 + b2 + x
        wconv<<<dim3(64, 16), 256, 0, stream>>>(ff_w2 + (size_t)l * 4 * DIM * DIM, wT, (size_t)DIM * 4096, 4 * DIM, DIM, DIM);
        gemm_split<float, 0><<<dim3(DIM / 128, BNROWS / 128), 256, 0, stream>>>(
            midb, 4 * DIM, PS_MID, wT, 4 * DIM, (size_t)DIM * 4096, x, DIM, 0, 4 * DIM,
            ff_b2 + (size_t)l * DIM, x);
    }

    // final LN + logits (10 column chunks of 3200)
    ln_kernel<<<BNROWS, 256, 0, stream>>>(x, lnf_w, lnf_b, hb, PS_H);
    for (int c0 = 0; c0 < VOCAB; c0 += LOGITS_CHUNK) {
        wconv<<<dim3(16, LOGITS_CHUNK / 64), 256, 0, stream>>>(
            w_logits + c0, wT, (size_t)LOGITS_CHUNK * DIM, DIM, LOGITS_CHUNK, VOCAB);
        gemm_split<float, 0><<<dim3(LOGITS_CHUNK / 128, BNROWS / 128), 256, 0, stream>>>(
            hb, DIM, PS_H, wT, DIM, (size_t)LOGITS_CHUNK * DIM, logits + c0, VOCAB, 0, DIM,
            b_logits + c0, nullptr);
    }
}

// Round 7
// 3250.577 us; speedup vs baseline: 5.8448x; 1.1158x over previous
//
#include <hip/hip_runtime.h>
#include <hip/hip_bf16.h>
#include <math.h>

// Problem constants (from setup_inputs)
#define BB 2
#define NSEQ 1024
#define DIM 1024
#define NH 16
#define DH 64
#define DEPTH 4
#define VOCAB 32000
#define XLM 256
#define MDB 4096
#define TOPK 32
#define KNN_LAYER 2
#define BNROWS (BB * NSEQ)   // 2048
#define LOGITS_CHUNK 6400    // 32000 = 5 * 6400; 6400 % 128 == 0

typedef __bf16 bf16x8v __attribute__((ext_vector_type(8)));
typedef float f32x4v __attribute__((ext_vector_type(4)));
typedef unsigned short u16x8v __attribute__((ext_vector_type(8)));

__device__ __forceinline__ float bfbits2f(unsigned short u) {
    union { float f; unsigned int i; } v; v.i = ((unsigned int)u) << 16; return v.f;
}
__device__ __forceinline__ unsigned short f2bfbits(float f) {
    union { __hip_bfloat16 b; unsigned short u; } v;
    v.b = __float2bfloat16(f);
    return v.u;
}
__device__ __forceinline__ float bf2f(__hip_bfloat16 h) { return __bfloat162float(h); }
__device__ __forceinline__ __hip_bfloat16 f2bf(float f) { return __float2bfloat16(f); }

__device__ __forceinline__ void gload16(const void* gp, void* lp) {
    __builtin_amdgcn_global_load_lds(
        (const __attribute__((address_space(1))) unsigned int*)gp,
        (__attribute__((address_space(3))) unsigned int*)lp, 16, 0, 0);
}

// ---------------------------------------------------------------------------
__global__ __launch_bounds__(256) void embed_kernel(const int* __restrict__ tok,
                                                    const float* __restrict__ emb,
                                                    float* __restrict__ x) {
    int r = blockIdx.x, t = threadIdx.x;
    int id = tok[r];
    const float* er = emb + (size_t)id * DIM;
    float* xr = x + (size_t)r * DIM;
#pragma unroll
    for (int i = 0; i < 4; i++) xr[t + 256 * i] = er[t + 256 * i];
}

// ---------------------------------------------------------------------------
// Row LayerNorm over DIM=1024, fp32 in, split-bf16 (hi/lo planes) out
__global__ __launch_bounds__(256) void ln_kernel(const float* __restrict__ x,
                                                 const float* __restrict__ w,
                                                 const float* __restrict__ b,
                                                 __hip_bfloat16* __restrict__ y,
                                                 size_t ypS) {
    __shared__ float red[256];
    int r = blockIdx.x, t = threadIdx.x;
    const float* xr = x + (size_t)r * DIM;
    float v[4];
#pragma unroll
    for (int i = 0; i < 4; i++) v[i] = xr[t + 256 * i];
    float s = v[0] + v[1] + v[2] + v[3];
    red[t] = s; __syncthreads();
    for (int st = 128; st; st >>= 1) { if (t < st) red[t] += red[t + st]; __syncthreads(); }
    float mean = red[0] * (1.0f / DIM);
    __syncthreads();
    float s2 = 0.f;
#pragma unroll
    for (int i = 0; i < 4; i++) { float d = v[i] - mean; s2 += d * d; }
    red[t] = s2; __syncthreads();
    for (int st = 128; st; st >>= 1) { if (t < st) red[t] += red[t + st]; __syncthreads(); }
    float rs = rsqrtf(red[0] * (1.0f / DIM) + 1e-5f);
    __hip_bfloat16* yr = y + (size_t)r * DIM;
#pragma unroll
    for (int i = 0; i < 4; i++) {
        int c = t + 256 * i;
        float val = (v[i] - mean) * rs * w[c] + b[c];
        __hip_bfloat16 hv = f2bf(val);
        yr[c] = hv;
        yr[c + ypS] = f2bf(val - bf2f(hv));
    }
}

// ---------------------------------------------------------------------------
// L2-normalize fp32 rows of length 64 (row stride configurable), in-place
__global__ void l2norm_kernel(float* __restrict__ p, int stride) {
    int r = blockIdx.x, t = threadIdx.x; // 64 threads
    float* pr = p + (size_t)r * stride;
    float v = pr[t];
    float s = v * v;
#pragma unroll
    for (int off = 32; off; off >>= 1) s += __shfl_xor(s, off, 64);
    float n = fmaxf(sqrtf(s), 1e-12f);
    pr[t] = v / n;
}

__global__ void dbnorm_kernel(const float* __restrict__ db, float* __restrict__ dbkn) {
    int r = blockIdx.x, t = threadIdx.x; // 64 threads
    float v = db[((size_t)r * 2 + 0) * DH + t];
    float s = v * v;
#pragma unroll
    for (int off = 32; off; off >>= 1) s += __shfl_xor(s, off, 64);
    float n = fmaxf(sqrtf(s), 1e-12f);
    dbkn[(size_t)r * DH + t] = v / n;
}

// ---------------------------------------------------------------------------
// fp32 -> split-bf16 planes (hi at y, lo at y+pS). n4 = n/4 float4 groups.
__global__ __launch_bounds__(256) void split_conv(const float* __restrict__ x,
                                                  unsigned short* __restrict__ y,
                                                  size_t pS, size_t n4) {
    size_t idx = (size_t)blockIdx.x * 256 + threadIdx.x;
    if (idx >= n4) return;
    float4 v = *(const float4*)&x[idx * 4];
    float vv[4] = {v.x, v.y, v.z, v.w};
    ushort4 h4, l4;
    unsigned short* hp = (unsigned short*)&h4;
    unsigned short* lp = (unsigned short*)&l4;
#pragma unroll
    for (int j = 0; j < 4; j++) {
        hp[j] = f2bfbits(vv[j]);
        lp[j] = f2bfbits(vv[j] - bfbits2f(hp[j]));
    }
    *(ushort4*)&y[idx * 4] = h4;
    *(ushort4*)&y[idx * 4 + pS] = l4;
}

// ---------------------------------------------------------------------------
// Weight convert + transpose: W (K x N fp32, row stride ldw) ->
// WT (N x K split-bf16, hi plane + lo plane at +wpS). wlo=0: hi only.
__global__ __launch_bounds__(256) void wconv(const float* __restrict__ W,
                                             __hip_bfloat16* __restrict__ WT,
                                             size_t wpS, int K, int N, int ldw,
                                             int wlo) {
    __shared__ float tile[64][65];
    int k0 = blockIdx.x * 64, n0 = blockIdx.y * 64;
    int t = threadIdx.x;
    int r = t >> 4, c4 = (t & 15) * 4;
#pragma unroll
    for (int rr = 0; rr < 4; rr++) {
        int row = rr * 16 + r;
        float4 v = *(const float4*)&W[(size_t)(k0 + row) * ldw + n0 + c4];
        tile[row][c4] = v.x; tile[row][c4 + 1] = v.y; tile[row][c4 + 2] = v.z; tile[row][c4 + 3] = v.w;
    }
    __syncthreads();
#pragma unroll
    for (int rr = 0; rr < 4; rr++) {
        int nrow = rr * 16 + r;
        size_t base = (size_t)(n0 + nrow) * K + k0 + c4;
#pragma unroll
        for (int j = 0; j < 4; j++) {
            float val = tile[c4 + j][nrow];
            __hip_bfloat16 hv = f2bf(val);
            WT[base + j] = hv;
            if (wlo) WT[base + j + wpS] = f2bf(val - bf2f(hv));
        }
    }
}

// ---------------------------------------------------------------------------
// Split-bf16 MFMA GEMM: C(MxN) = A(MxK) @ BT(NxK)^T with A,B as hi/lo planes.
// TERMS: 3 = hi*hi + lo*hi + hi*lo (fp32-grade); 1 = hi*hi only (bf16-grade).
// SIMDB: batch mode over bh (z dim); A=q planes (row b*NSEQ+i, col h*DH+k),
//        BT=dbkn planes (b*MDB+m, k), C=chunk-local (z*NSEQ+i)*ldc+m.
template <typename OT, int ACT, int TERMS, int SIMDB>
__global__ __launch_bounds__(256) void gemm_split(const __hip_bfloat16* __restrict__ A, int lda, size_t apS,
                                                  const __hip_bfloat16* __restrict__ BT, int ldb, size_t bpS,
                                                  OT* __restrict__ C, int ldc, size_t cpS, int K,
                                                  const float* __restrict__ bias,
                                                  const float* __restrict__ res,
                                                  int bh0) {
    __shared__ __align__(16) __hip_bfloat16 sAh[128 * 32];
    __shared__ __align__(16) __hip_bfloat16 sBh[128 * 32];
    __shared__ __align__(16) __hip_bfloat16 sAl[TERMS > 1 ? 128 * 32 : 1];
    __shared__ __align__(16) __hip_bfloat16 sBl[TERMS > 1 ? 128 * 32 : 1];
    if constexpr (SIMDB) {
        int bh = bh0 + blockIdx.z;
        A += ((size_t)(bh >> 4) * NSEQ) * lda + (bh & 15) * DH;
        BT += (size_t)(bh >> 4) * MDB * ldb;
        C += (size_t)blockIdx.z * NSEQ * ldc;
    }
    int bn = blockIdx.x * 128;
    int bm = blockIdx.y * 128;
    int t = threadIdx.x;
    int lane = t & 63, wid = t >> 6;
    int wr = wid >> 1, wc = wid & 1;
    int lr = lane & 15, kc = lane >> 4;

    f32x4v acc[4][4];
#pragma unroll
    for (int m = 0; m < 4; m++)
#pragma unroll
        for (int n = 0; n < 4; n++) acc[m][n] = (f32x4v){0.f, 0.f, 0.f, 0.f};

    for (int k0 = 0; k0 < K; k0 += 32) {
        __syncthreads();
#pragma unroll
        for (int it = 0; it < 2; it++) {
            int e = wid * 128 + it * 64 + lane;
            int r = e >> 2;
            int cl = (e & 3) ^ ((r >> 1) & 3);
            size_t aoff = (size_t)(bm + r) * lda + k0 + cl * 8;
            size_t boff = (size_t)(bn + r) * ldb + k0 + cl * 8;
            int dst = (wid * 128 + it * 64) * 8;
            gload16(&A[aoff], &sAh[dst]);
            gload16(&BT[boff], &sBh[dst]);
            if constexpr (TERMS > 1) {
                gload16(&A[aoff + apS], &sAl[dst]);
                gload16(&BT[boff + bpS], &sBl[dst]);
            }
        }
        __syncthreads();

        bf16x8v ah[4], al[4], bh[4], bl[4];
#pragma unroll
        for (int m = 0; m < 4; m++) {
            int row = wr * 64 + m * 16 + lr;
            int off = row * 32 + ((kc ^ ((row >> 1) & 3)) << 3);
            ah[m] = *(const bf16x8v*)&sAh[off];
            if constexpr (TERMS > 1) al[m] = *(const bf16x8v*)&sAl[off];
        }
#pragma unroll
        for (int n = 0; n < 4; n++) {
            int row = wc * 64 + n * 16 + lr;
            int off = row * 32 + ((kc ^ ((row >> 1) & 3)) << 3);
            bh[n] = *(const bf16x8v*)&sBh[off];
            if constexpr (TERMS > 1) bl[n] = *(const bf16x8v*)&sBl[off];
        }
#pragma unroll
        for (int m = 0; m < 4; m++)
#pragma unroll
            for (int n = 0; n < 4; n++) {
                acc[m][n] = __builtin_amdgcn_mfma_f32_16x16x32_bf16(ah[m], bh[n], acc[m][n], 0, 0, 0);
                if constexpr (TERMS > 1) {
                    acc[m][n] = __builtin_amdgcn_mfma_f32_16x16x32_bf16(al[m], bh[n], acc[m][n], 0, 0, 0);
                    acc[m][n] = __builtin_amdgcn_mfma_f32_16x16x32_bf16(ah[m], bl[n], acc[m][n], 0, 0, 0);
                }
            }
    }

#pragma unroll
    for (int m = 0; m < 4; m++) {
#pragma unroll
        for (int n = 0; n < 4; n++) {
            int gcol = bn + wc * 64 + n * 16 + lr;
            float bv = bias ? bias[gcol] : 0.f;
#pragma unroll
            for (int j = 0; j < 4; j++) {
                int grow = bm + wr * 64 + m * 16 + kc * 4 + j;
                float v = acc[m][n][j] + bv;
                if (ACT == 1) v = 0.5f * v * (1.0f + erff(v * 0.70710678118654752f));
                if (res) v += res[(size_t)grow * ldc + gcol];
                size_t idx = (size_t)grow * ldc + gcol;
                if constexpr (__is_same(OT, float)) {
                    C[idx] = v;
                } else {
                    __hip_bfloat16 hv = f2bf(v);
                    C[idx] = hv;
                    C[idx + cpS] = f2bf(v - bf2f(hv));
                }
            }
        }
    }
}

// ---------------------------------------------------------------------------
// Split-bf16 MFMA flash attention over XL + causal local keys. (unchanged)
template <int KNNL>
__global__ __launch_bounds__(256) void flash_kernel(const float* __restrict__ q,
                                                    const float* __restrict__ kv,
                                                    const float* __restrict__ xlm,
                                                    const float* __restrict__ knn_scale,
                                                    __hip_bfloat16* __restrict__ out,
                                                    size_t opS,
                                                    float* __restrict__ stats) {
    __shared__ __align__(16) unsigned short sKh[64 * 64];
    __shared__ __align__(16) unsigned short sKl[64 * 64];
    __shared__ __align__(16) unsigned short sVh[64 * 64];   // transposed [dim][key]
    __shared__ __align__(16) unsigned short sVl[64 * 64];
    __shared__ __align__(16) float sPf[4 * 16 * 64];        // per-wave P fp32

    int qt = blockIdx.x, h = blockIdx.y, b = blockIdx.z;
    int q0 = qt * 64;
    int t = threadIdx.x;
    int w = t >> 6;
    int lane = t & 63;
    int lr = lane & 15, kc = lane >> 4;
    int wbase = w * 1024;

    float scale = KNNL ? __expf(knn_scale[h]) : 0.125f;

    bf16x8v qh[2], ql[2];
    {
        const float* qbase = q + (size_t)(b * NSEQ + q0 + w * 16 + lr) * DIM + h * DH;
#pragma unroll
        for (int ks = 0; ks < 2; ks++) {
            const float* s = qbase + ks * 32 + kc * 8;
            float4 a = *(const float4*)s;
            float4 c2 = *(const float4*)(s + 4);
            float vv[8] = {a.x, a.y, a.z, a.w, c2.x, c2.y, c2.z, c2.w};
            u16x8v hi, lo;
#pragma unroll
            for (int j = 0; j < 8; j++) {
                hi[j] = f2bfbits(vv[j]);
                lo[j] = f2bfbits(vv[j] - bfbits2f(hi[j]));
            }
            qh[ks] = *(bf16x8v*)&hi;
            ql[ks] = *(bf16x8v*)&lo;
        }
    }

    float m[4], l[4];
    f32x4v o[4];
#pragma unroll
    for (int j = 0; j < 4; j++) { m[j] = -1e30f; l[j] = 0.f; }
#pragma unroll
    for (int f = 0; f < 4; f++) o[f] = (f32x4v){0.f, 0.f, 0.f, 0.f};

    int ntiles = 5 + qt;

    for (int T = 0; T < ntiles; T++) {
        const float* srcK = (T < 4)
            ? xlm + ((size_t)(b * XLM + T * 64) * 2) * DH
            : kv + (size_t)(b * NSEQ + T * 64 - XLM) * 128;
        __syncthreads();
#pragma unroll
        for (int i = 0; i < 2; i++) {
            int idx = i * 256 + t;
            int key = idx >> 3, ch = idx & 7;
            const float* s = srcK + key * 128 + ch * 8;
            float4 a = *(const float4*)s;
            float4 c2 = *(const float4*)(s + 4);
            float vv[8] = {a.x, a.y, a.z, a.w, c2.x, c2.y, c2.z, c2.w};
            u16x8v hi, lo;
#pragma unroll
            for (int j = 0; j < 8; j++) {
                hi[j] = f2bfbits(vv[j]);
                lo[j] = f2bfbits(vv[j] - bfbits2f(hi[j]));
            }
            int off = key * 64 + ((ch ^ (key & 7)) << 3);
            *(u16x8v*)&sKh[off] = hi;
            *(u16x8v*)&sKl[off] = lo;
        }
#pragma unroll
        for (int i = 0; i < 4; i++) {
            int idx = i * 256 + t;
            int key = idx & 63, dg = idx >> 6;
            const float* s = srcK + key * 128 + 64 + dg * 4;
            float4 v = *(const float4*)s;
            float vv[4] = {v.x, v.y, v.z, v.w};
#pragma unroll
            for (int j = 0; j < 4; j++) {
                int dim = dg * 4 + j;
                unsigned short hi = f2bfbits(vv[j]);
                unsigned short lo = f2bfbits(vv[j] - bfbits2f(hi));
                int off = dim * 64 + (((key >> 3) ^ (dim & 7)) << 3) + (key & 7);
                sVh[off] = hi;
                sVl[off] = lo;
            }
        }
        __syncthreads();

        f32x4v s4[4];
#pragma unroll
        for (int n = 0; n < 4; n++) s4[n] = (f32x4v){0.f, 0.f, 0.f, 0.f};
#pragma unroll
        for (int ks = 0; ks < 2; ks++) {
            bf16x8v qh_ = qh[ks], ql_ = ql[ks];
#pragma unroll
            for (int n = 0; n < 4; n++) {
                int row = n * 16 + lr;
                int off = row * 64 + (((ks * 4 + kc) ^ (lr & 7)) << 3);
                bf16x8v kh = *(const bf16x8v*)&sKh[off];
                bf16x8v kl = *(const bf16x8v*)&sKl[off];
                s4[n] = __builtin_amdgcn_mfma_f32_16x16x32_bf16(qh_, kh, s4[n], 0, 0, 0);
                s4[n] = __builtin_amdgcn_mfma_f32_16x16x32_bf16(ql_, kh, s4[n], 0, 0, 0);
                s4[n] = __builtin_amdgcn_mfma_f32_16x16x32_bf16(qh_, kl, s4[n], 0, 0, 0);
            }
        }

#pragma unroll
        for (int n = 0; n < 4; n++) {
            int key = T * 64 + n * 16 + lr;
#pragma unroll
            for (int j = 0; j < 4; j++) {
                int gq = q0 + w * 16 + kc * 4 + j;
                float sv = s4[n][j] * scale;
                s4[n][j] = (key <= XLM + gq) ? sv : -1e30f;
            }
        }

        float tm[4];
#pragma unroll
        for (int j = 0; j < 4; j++) {
            float v = fmaxf(fmaxf(s4[0][j], s4[1][j]), fmaxf(s4[2][j], s4[3][j]));
            v = fmaxf(v, __shfl_xor(v, 1, 64));
            v = fmaxf(v, __shfl_xor(v, 2, 64));
            v = fmaxf(v, __shfl_xor(v, 4, 64));
            v = fmaxf(v, __shfl_xor(v, 8, 64));
            tm[j] = v;
        }
        float alpha[4];
#pragma unroll
        for (int j = 0; j < 4; j++) {
            float mnew = fmaxf(m[j], tm[j]);
            alpha[j] = __expf(m[j] - mnew);
            m[j] = mnew;
        }
        float psum[4] = {0.f, 0.f, 0.f, 0.f};
#pragma unroll
        for (int n = 0; n < 4; n++)
#pragma unroll
            for (int j = 0; j < 4; j++) {
                float p = __expf(s4[n][j] - m[j]);
                s4[n][j] = p;
                psum[j] += p;
            }
#pragma unroll
        for (int j = 0; j < 4; j++) {
            float v = psum[j];
            v += __shfl_xor(v, 1, 64);
            v += __shfl_xor(v, 2, 64);
            v += __shfl_xor(v, 4, 64);
            v += __shfl_xor(v, 8, 64);
            l[j] = l[j] * alpha[j] + v;
        }
#pragma unroll
        for (int f = 0; f < 4; f++)
#pragma unroll
            for (int j = 0; j < 4; j++) o[f][j] *= alpha[j];

#pragma unroll
        for (int n = 0; n < 4; n++) {
            int chunkcol = 2 * n + (lr >> 3);
#pragma unroll
            for (int j = 0; j < 4; j++) {
                int row = kc * 4 + j;
                int off = wbase + row * 64 + (((chunkcol ^ (row & 7)) << 3) + (lr & 7));
                sPf[off] = s4[n][j];
            }
        }

#pragma unroll
        for (int ks = 0; ks < 2; ks++) {
            int poff = wbase + lr * 64 + (((ks * 4 + kc) ^ (lr & 7)) << 3);
            float4 a = *(const float4*)&sPf[poff];
            float4 c2 = *(const float4*)&sPf[poff + 4];
            float vv[8] = {a.x, a.y, a.z, a.w, c2.x, c2.y, c2.z, c2.w};
            u16x8v hib, lob;
#pragma unroll
            for (int j = 0; j < 8; j++) {
                hib[j] = f2bfbits(vv[j]);
                lob[j] = f2bfbits(vv[j] - bfbits2f(hib[j]));
            }
            bf16x8v ph = *(bf16x8v*)&hib;
            bf16x8v pl = *(bf16x8v*)&lob;
#pragma unroll
            for (int f = 0; f < 4; f++) {
                int row = f * 16 + lr;
                int off = row * 64 + (((ks * 4 + kc) ^ (lr & 7)) << 3);
                bf16x8v vh = *(const bf16x8v*)&sVh[off];
                bf16x8v vl = *(const bf16x8v*)&sVl[off];
                o[f] = __builtin_amdgcn_mfma_f32_16x16x32_bf16(ph, vh, o[f], 0, 0, 0);
                o[f] = __builtin_amdgcn_mfma_f32_16x16x32_bf16(pl, vh, o[f], 0, 0, 0);
                o[f] = __builtin_amdgcn_mfma_f32_16x16x32_bf16(ph, vl, o[f], 0, 0, 0);
            }
        }
    }

    float inv[4];
#pragma unroll
    for (int j = 0; j < 4; j++) inv[j] = 1.0f / l[j];
    unsigned short* outu = (unsigned short*)out;
#pragma unroll
    for (int f = 0; f < 4; f++)
#pragma unroll
        for (int j = 0; j < 4; j++) {
            int gq = q0 + w * 16 + kc * 4 + j;
            size_t oidx = (size_t)(b * NSEQ + gq) * DIM + h * DH + f * 16 + lr;
            float v = o[f][j] * inv[j];
            unsigned short hv = f2bfbits(v);
            outu[oidx] = hv;
            outu[oidx + opS] = f2bfbits(v - bfbits2f(hv));
        }
    if (KNNL && lr == 0) {
#pragma unroll
        for (int j = 0; j < 4; j++) {
            int gq = q0 + w * 16 + kc * 4 + j;
            size_t srow = (((size_t)b * NH + h) * NSEQ + gq) * 2;
            stats[srow] = m[j];
            stats[srow + 1] = l[j];
        }
    }
}

// ---------------------------------------------------------------------------
// Per-row top-32 over simdb + mem softmax + combine with local flash stats.
// 256 threads (4 waves): cooperative row load, wave-0 barrier-free selection,
// wave-parallel dbv gather.
__global__ __launch_bounds__(256) void knn_select(const float* __restrict__ simdb,
                                                  const float* __restrict__ db,
                                                  const float* __restrict__ knn_scale,
                                                  const float* __restrict__ stats,
                                                  __hip_bfloat16* __restrict__ out,
                                                  size_t opS,
                                                  int bh0) {
    __shared__ float sv[64 * 65];
    __shared__ float cval[4 * 64];
    __shared__ int cidx[4 * 64];
    __shared__ float stopv[TOPK];
    __shared__ int stopi[TOPK];
    __shared__ float part[4][64];

    int bh = bh0 + blockIdx.y;
    int b = bh >> 4, h = bh & 15;
    int i = blockIdx.x;
    int t = threadIdx.x;
    int w = t >> 6, lane = t & 63;

    // cooperative load + per-thread candidate (chunks w, w+4, ..., w+60)
    const float* srow = &simdb[((size_t)blockIdx.y * NSEQ + i) * MDB];
    float lmax = -1e30f; int lidx = 0;
#pragma unroll
    for (int ii = 0; ii < 16; ii++) {
        int chunk = ii * 4 + w;
        float v = srow[chunk * 64 + lane];
        sv[chunk * 65 + lane] = v;
        if (v > lmax) { lmax = v; lidx = chunk * 64 + lane; }
    }
    cval[w * 64 + lane] = lmax; cidx[w * 64 + lane] = lidx;
    __syncthreads();

    if (w == 0) {
        // combine per-column candidates (idx-asc tiebreak)
        float bvv = cval[lane]; int bii = cidx[lane];
#pragma unroll
        for (int g = 1; g < 4; g++) {
            float v2 = cval[g * 64 + lane]; int i2 = cidx[g * 64 + lane];
            if (v2 > bvv || (v2 == bvv && i2 < bii)) { bvv = v2; bii = i2; }
        }
        lmax = bvv; lidx = bii;
        // 32 selection iterations, wave-synchronous (no barriers)
        for (int it = 0; it < TOPK; it++) {
            float v = lmax; int idx = lidx;
#pragma unroll
            for (int off = 32; off; off >>= 1) {
                float v2 = __shfl_xor(v, off, 64);
                int i2 = __shfl_xor(idx, off, 64);
                if (v2 > v || (v2 == v && i2 < idx)) { v = v2; idx = i2; }
            }
            if (lane == it) { stopv[it] = v; stopi[it] = idx; }
            int col = idx & 63;
            if (lane == (idx >> 6)) sv[(idx >> 6) * 65 + col] = -1e30f;
            // rescan invalidated column
            float rv = sv[lane * 65 + col];
            int ridx = lane * 64 + col;
#pragma unroll
            for (int off = 32; off; off >>= 1) {
                float v2 = __shfl_xor(rv, off, 64);
                int i2 = __shfl_xor(ridx, off, 64);
                if (v2 > rv || (v2 == rv && i2 < ridx)) { rv = v2; ridx = i2; }
            }
            if (lane == col) { lmax = rv; lidx = ridx; }
        }
    }
    __syncthreads();

    float scl = __expf(knn_scale[h]);
    size_t srow_idx = (((size_t)b * NH + h) * NSEQ + i) * 2;
    float m_loc = stats[srow_idx], l_loc = stats[srow_idx + 1];
    float M = fmaxf(m_loc, stopv[0] * scl);
    float co = __expf(m_loc - M);
    // esum (wave-redundant)
    float e = (lane < TOPK) ? __expf(stopv[lane] * scl - M) : 0.f;
    float esum = e;
#pragma unroll
    for (int off = 32; off; off >>= 1) esum += __shfl_xor(esum, off, 64);
    float denom = l_loc * co + esum;

    // gather: wave w handles 8 of the 32 selected keys
    float acc = 0.f;
#pragma unroll
    for (int jj = 0; jj < 8; jj++) {
        int j = w * 8 + jj;
        float ej = __expf(stopv[j] * scl - M);
        acc += ej * db[(((size_t)b * MDB + stopi[j]) * 2 + 1) * DH + lane];
    }
    part[w][lane] = acc;
    __syncthreads();
    if (w == 0) {
        float a = part[0][lane] + part[1][lane] + part[2][lane] + part[3][lane];
        size_t op = (size_t)(b * NSEQ + i) * DIM + h * DH + lane;
        float o_loc = bf2f(out[op]) + bf2f(out[op + opS]);
        float nv = (o_loc * l_loc * co + a) / denom;
        __hip_bfloat16 hv = f2bf(nv);
        out[op] = hv;
        out[op + opS] = f2bf(nv - bf2f(hv));
    }
}

// ---------------------------------------------------------------------------
extern "C" void kernel_launch(void* const* d_in, const int* in_sizes, int n_in,
                              void* d_out, int out_size, void* d_ws, size_t ws_size,
                              hipStream_t stream) {
    const int* tokens = (const int*)d_in[0];
    const float* emb = (const float*)d_in[1];
    const float* ln1_w = (const float*)d_in[2];
    const float* ln1_b = (const float*)d_in[3];
    const float* wq = (const float*)d_in[4];
    const float* wkv = (const float*)d_in[5];
    const float* wo = (const float*)d_in[6];
    const float* wo_b = (const float*)d_in[7];
    const float* knn_scale = (const float*)d_in[8];
    const float* ln2_w = (const float*)d_in[9];
    const float* ln2_b = (const float*)d_in[10];
    const float* ff_w1 = (const float*)d_in[11];
    const float* ff_b1 = (const float*)d_in[12];
    const float* ff_w2 = (const float*)d_in[13];
    const float* ff_b2 = (const float*)d_in[14];
    const float* lnf_w = (const float*)d_in[15];
    const float* lnf_b = (const float*)d_in[16];
    const float* w_logits = (const float*)d_in[17];
    const float* b_logits = (const float*)d_in[18];
    const float* xl_mems = (const float*)d_in[19];
    const float* db_kv = (const float*)d_in[20];

    // ---- workspace layout ----
    const size_t PS_H = (size_t)BNROWS * DIM;        // plane stride for h / attn-out
    char* p = (char*)d_ws;
    float* x = (float*)p;                p += PS_H * 4;                        // 8 MB
    __hip_bfloat16* hb = (__hip_bfloat16*)p;  p += PS_H * 2 * 2;               // 8 MB (2 planes)
    float* qf = (float*)p;               p += PS_H * 4;                        // 8 MB
    float* kvf = (float*)p;              p += (size_t)BNROWS * 128 * 4;        // 1 MB
    float* dbkn = (float*)p;             p += (size_t)BB * MDB * DH * 4;       // 2 MB
    float* stats = (float*)p;            p += (size_t)BB * NH * NSEQ * 2 * 4;  // 0.25 MB
    __hip_bfloat16* wT = (__hip_bfloat16*)p; p += (size_t)4096 * DIM * 2 * 2;  // 16 MB (2 planes, max N=4096)

    // qsplit/dbkn-split live in the wT region during the KNN phase (wT idle)
    unsigned short* qsplit = (unsigned short*)wT;                  // 2 planes x PS_H
    unsigned short* dbks = (unsigned short*)wT + 2 * PS_H;         // 2 planes x BB*MDB*DH
    const size_t PS_DB = (size_t)BB * MDB * DH;

    const size_t PS_MID = (size_t)BNROWS * 4 * DIM;  // 8M elems per plane
    __hip_bfloat16* midb = (__hip_bfloat16*)d_out;   // 32 MB of the 262 MB out buf
    float* logits = (float*)d_out;
    int nbh_cap = (int)((size_t)out_size / ((size_t)NSEQ * MDB));
    if (nbh_cap > BB * NH) nbh_cap = BB * NH;
    if (nbh_cap < 1) nbh_cap = 1;

    embed_kernel<<<BNROWS, 256, 0, stream>>>(tokens, emb, x);
    dbnorm_kernel<<<BB * MDB, 64, 0, stream>>>(db_kv, dbkn);

    for (int l = 0; l < DEPTH; l++) {
        const float* wq_l = wq + (size_t)l * DIM * DIM;
        const float* wkv_l = wkv + (size_t)l * DIM * 128;
        const float* wo_l = wo + (size_t)l * DIM * DIM;
        const float* xlm_l = xl_mems + (size_t)l * BB * XLM * 2 * DH;

        // h = LN1(x) -> split bf16
        ln_kernel<<<BNROWS, 256, 0, stream>>>(x, ln1_w + (size_t)l * DIM, ln1_b + (size_t)l * DIM, hb, PS_H);

        // q = h @ wq  (fp32 out)
        wconv<<<dim3(16, 16), 256, 0, stream>>>(wq_l, wT, (size_t)DIM * DIM, DIM, DIM, DIM, 1);
        gemm_split<float, 0, 3, 0><<<dim3(DIM / 128, BNROWS / 128), 256, 0, stream>>>(
            hb, DIM, PS_H, wT, DIM, (size_t)DIM * DIM, qf, DIM, 0, DIM, nullptr, nullptr, 0);
        // kv = h @ wkv (fp32 out)
        wconv<<<dim3(16, 2), 256, 0, stream>>>(wkv_l, wT, (size_t)128 * DIM, DIM, 128, 128, 1);
        gemm_split<float, 0, 3, 0><<<dim3(1, BNROWS / 128), 256, 0, stream>>>(
            hb, DIM, PS_H, wT, DIM, (size_t)128 * DIM, kvf, 128, 0, DIM, nullptr, nullptr, 0);

        if (l == KNN_LAYER) {
            l2norm_kernel<<<BNROWS * NH, 64, 0, stream>>>(qf, DH);
            l2norm_kernel<<<BNROWS, 64, 0, stream>>>(kvf, 128);
            // split-bf16 planes of normalized q and db keys (into idle wT region)
            split_conv<<<(PS_H / 4 + 255) / 256, 256, 0, stream>>>(qf, qsplit, PS_H, PS_H / 4);
            split_conv<<<(PS_DB / 4 + 255) / 256, 256, 0, stream>>>(dbkn, dbks, PS_DB, PS_DB / 4);
            flash_kernel<1><<<dim3(NSEQ / 64, NH, BB), 256, 0, stream>>>(
                qf, kvf, xlm_l, knn_scale, hb, PS_H, stats);
            for (int bh0 = 0; bh0 < BB * NH; bh0 += nbh_cap) {
                int nb = BB * NH - bh0; if (nb > nbh_cap) nb = nbh_cap;
                gemm_split<float, 0, 3, 1><<<dim3(MDB / 128, NSEQ / 128, nb), 256, 0, stream>>>(
                    (const __hip_bfloat16*)qsplit, DIM, PS_H,
                    (const __hip_bfloat16*)dbks, DH, PS_DB,
                    (float*)d_out, MDB, 0, DH, nullptr, nullptr, bh0);
                knn_select<<<dim3(NSEQ, nb), 256, 0, stream>>>(
                    (float*)d_out, db_kv, knn_scale, stats, hb, PS_H, bh0);
            }
        } else {
            flash_kernel<0><<<dim3(NSEQ / 64, NH, BB), 256, 0, stream>>>(
                qf, kvf, xlm_l, knn_scale, hb, PS_H, stats);
        }

        // x = attn @ wo + wo_b + x
        wconv<<<dim3(16, 16), 256, 0, stream>>>(wo_l, wT, (size_t)DIM * DIM, DIM, DIM, DIM, 1);
        gemm_split<float, 0, 3, 0><<<dim3(DIM / 128, BNROWS / 128), 256, 0, stream>>>(
            hb, DIM, PS_H, wT, DIM, (size_t)DIM * DIM, x, DIM, 0, DIM,
            wo_b + (size_t)l * DIM, x, 0);

        // h = LN2(x)
        ln_kernel<<<BNROWS, 256, 0, stream>>>(x, ln2_w + (size_t)l * DIM, ln2_b + (size_t)l * DIM, hb, PS_H);
        // mid = gelu(h @ ff_w1 + b1) -> split bf16 (in d_out)
        wconv<<<dim3(16, 64), 256, 0, stream>>>(ff_w1 + (size_t)l * DIM * 4 * DIM, wT, (size_t)4096 * DIM, DIM, 4 * DIM, 4 * DIM, 1);
        gemm_split<__hip_bfloat16, 1, 3, 0><<<dim3(4 * DIM / 128, BNROWS / 128), 256, 0, stream>>>(
            hb, DIM, PS_H, wT, DIM, (size_t)4096 * DIM, midb, 4 * DIM, PS_MID, DIM,
            ff_b1 + (size_t)l * 4 * DIM, nullptr, 0);
        // x = mid @ ff_w2 + b2 + x
        wconv<<<dim3(64, 16), 256, 0, stream>>>(ff_w2 + (size_t)l * 4 * DIM * DIM, wT, (size_t)DIM * 4096, 4 * DIM, DIM, DIM, 1);
        gemm_split<float, 0, 3, 0><<<dim3(DIM / 128, BNROWS / 128), 256, 0, stream>>>(
            midb, 4 * DIM, PS_MID, wT, 4 * DIM, (size_t)DIM * 4096, x, DIM, 0, 4 * DIM,
            ff_b2 + (size_t)l * DIM, x, 0);
    }

    // final LN + logits (5 column chunks of 6400, hi-plane-only bf16 GEMM)
    ln_kernel<<<BNROWS, 256, 0, stream>>>(x, lnf_w, lnf_b, hb, PS_H);
    for (int c0 = 0; c0 < VOCAB; c0 += LOGITS_CHUNK) {
        wconv<<<dim3(16, LOGITS_CHUNK / 64), 256, 0, stream>>>(
            w_logits + c0, wT, 0, DIM, LOGITS_CHUNK, VOCAB, 0);
        gemm_split<float, 0, 1, 0><<<dim3(LOGITS_CHUNK / 128, BNROWS / 128), 256, 0, stream>>>(
            hb, DIM, PS_H, wT, DIM, 0, logits + c0, VOCAB, 0, DIM,
            b_logits + c0, nullptr, 0);
    }
}

// Round 8
// 3194.644 us; speedup vs baseline: 5.9471x; 1.0175x over previous
//
#include <hip/hip_runtime.h>
#include <hip/hip_bf16.h>
#include <math.h>

// Problem constants (from setup_inputs)
#define BB 2
#define NSEQ 1024
#define DIM 1024
#define NH 16
#define DH 64
#define DEPTH 4
#define VOCAB 32000
#define XLM 256
#define MDB 4096
#define TOPK 32
#define KNN_LAYER 2
#define BNROWS (BB * NSEQ)   // 2048
#define LOGITS_CHUNK 6400    // 32000 = 5 * 6400
#define NKEYS 1280           // XLM + NSEQ
#define KSP_PS ((size_t)BB * NKEYS * DH)   // plane stride for K/V split planes

typedef __bf16 bf16x8v __attribute__((ext_vector_type(8)));
typedef float f32x4v __attribute__((ext_vector_type(4)));
typedef unsigned short u16x8v __attribute__((ext_vector_type(8)));

__device__ __forceinline__ float bfbits2f(unsigned short u) {
    union { float f; unsigned int i; } v; v.i = ((unsigned int)u) << 16; return v.f;
}
__device__ __forceinline__ unsigned short f2bfbits(float f) {
    union { __hip_bfloat16 b; unsigned short u; } v;
    v.b = __float2bfloat16(f);
    return v.u;
}
__device__ __forceinline__ float bf2f(__hip_bfloat16 h) { return __bfloat162float(h); }
__device__ __forceinline__ __hip_bfloat16 f2bf(float f) { return __float2bfloat16(f); }

__device__ __forceinline__ void gload16(const void* gp, void* lp) {
    __builtin_amdgcn_global_load_lds(
        (const __attribute__((address_space(1))) unsigned int*)gp,
        (__attribute__((address_space(3))) unsigned int*)lp, 16, 0, 0);
}

// ---------------------------------------------------------------------------
__global__ __launch_bounds__(256) void embed_kernel(const int* __restrict__ tok,
                                                    const float* __restrict__ emb,
                                                    float* __restrict__ x) {
    int r = blockIdx.x, t = threadIdx.x;
    int id = tok[r];
    const float* er = emb + (size_t)id * DIM;
    float* xr = x + (size_t)r * DIM;
#pragma unroll
    for (int i = 0; i < 4; i++) xr[t + 256 * i] = er[t + 256 * i];
}

// ---------------------------------------------------------------------------
// Row LayerNorm over DIM=1024, fp32 in, split-bf16 (hi/lo planes) out
__global__ __launch_bounds__(256) void ln_kernel(const float* __restrict__ x,
                                                 const float* __restrict__ w,
                                                 const float* __restrict__ b,
                                                 __hip_bfloat16* __restrict__ y,
                                                 size_t ypS) {
    __shared__ float red[256];
    int r = blockIdx.x, t = threadIdx.x;
    const float* xr = x + (size_t)r * DIM;
    float v[4];
#pragma unroll
    for (int i = 0; i < 4; i++) v[i] = xr[t + 256 * i];
    float s = v[0] + v[1] + v[2] + v[3];
    red[t] = s; __syncthreads();
    for (int st = 128; st; st >>= 1) { if (t < st) red[t] += red[t + st]; __syncthreads(); }
    float mean = red[0] * (1.0f / DIM);
    __syncthreads();
    float s2 = 0.f;
#pragma unroll
    for (int i = 0; i < 4; i++) { float d = v[i] - mean; s2 += d * d; }
    red[t] = s2; __syncthreads();
    for (int st = 128; st; st >>= 1) { if (t < st) red[t] += red[t + st]; __syncthreads(); }
    float rs = rsqrtf(red[0] * (1.0f / DIM) + 1e-5f);
    __hip_bfloat16* yr = y + (size_t)r * DIM;
#pragma unroll
    for (int i = 0; i < 4; i++) {
        int c = t + 256 * i;
        float val = (v[i] - mean) * rs * w[c] + b[c];
        __hip_bfloat16 hv = f2bf(val);
        yr[c] = hv;
        yr[c + ypS] = f2bf(val - bf2f(hv));
    }
}

// ---------------------------------------------------------------------------
// L2-normalize fp32 rows of length 64 (row stride configurable), in-place
__global__ void l2norm_kernel(float* __restrict__ p, int stride) {
    int r = blockIdx.x, t = threadIdx.x; // 64 threads
    float* pr = p + (size_t)r * stride;
    float v = pr[t];
    float s = v * v;
#pragma unroll
    for (int off = 32; off; off >>= 1) s += __shfl_xor(s, off, 64);
    float n = fmaxf(sqrtf(s), 1e-12f);
    pr[t] = v / n;
}

__global__ void dbnorm_kernel(const float* __restrict__ db, float* __restrict__ dbkn) {
    int r = blockIdx.x, t = threadIdx.x; // 64 threads
    float v = db[((size_t)r * 2 + 0) * DH + t];
    float s = v * v;
#pragma unroll
    for (int off = 32; off; off >>= 1) s += __shfl_xor(s, off, 64);
    float n = fmaxf(sqrtf(s), 1e-12f);
    dbkn[(size_t)r * DH + t] = v / n;
}

// ---------------------------------------------------------------------------
// fp32 -> split-bf16 planes (hi at y, lo at y+pS). n4 = n/4 float4 groups.
__global__ __launch_bounds__(256) void split_conv(const float* __restrict__ x,
                                                  unsigned short* __restrict__ y,
                                                  size_t pS, size_t n4) {
    size_t idx = (size_t)blockIdx.x * 256 + threadIdx.x;
    if (idx >= n4) return;
    float4 v = *(const float4*)&x[idx * 4];
    float vv[4] = {v.x, v.y, v.z, v.w};
    ushort4 h4, l4;
    unsigned short* hp = (unsigned short*)&h4;
    unsigned short* lp = (unsigned short*)&l4;
#pragma unroll
    for (int j = 0; j < 4; j++) {
        hp[j] = f2bfbits(vv[j]);
        lp[j] = f2bfbits(vv[j] - bfbits2f(hp[j]));
    }
    *(ushort4*)&y[idx * 4] = h4;
    *(ushort4*)&y[idx * 4 + pS] = l4;
}

// ---------------------------------------------------------------------------
// Per-layer K/V split-bf16 prep: K planes [b][key][dim]; V transposed planes
// [b][dim][key]. keys 0..255 from xlm, 256..1279 from fresh kv.
__global__ void kv_prep(const float* __restrict__ kvf, const float* __restrict__ xlm,
                        unsigned short* __restrict__ ksp, unsigned short* __restrict__ vtp) {
    int key = blockIdx.x, b = blockIdx.y, d = threadIdx.x; // 64 threads
    float kvv, vvv;
    if (key < XLM) {
        kvv = xlm[(((size_t)b * XLM + key) * 2 + 0) * DH + d];
        vvv = xlm[(((size_t)b * XLM + key) * 2 + 1) * DH + d];
    } else {
        const float* r = &kvf[(size_t)(b * NSEQ + key - XLM) * 128];
        kvv = r[d]; vvv = r[64 + d];
    }
    unsigned short kh = f2bfbits(kvv), kl = f2bfbits(kvv - bfbits2f(kh));
    unsigned short vh = f2bfbits(vvv), vl = f2bfbits(vvv - bfbits2f(vh));
    size_t ko = (size_t)b * NKEYS * DH + (size_t)key * DH + d;
    ksp[ko] = kh; ksp[ko + KSP_PS] = kl;
    size_t vo = (size_t)b * DH * NKEYS + (size_t)d * NKEYS + key;
    vtp[vo] = vh; vtp[vo + KSP_PS] = vl;
}

// ---------------------------------------------------------------------------
// Weight convert + transpose: W (K x N fp32, row stride ldw) ->
// WT (N x K split-bf16, hi plane + lo plane at +wpS). wlo=0: hi only.
__global__ __launch_bounds__(256) void wconv(const float* __restrict__ W,
                                             __hip_bfloat16* __restrict__ WT,
                                             size_t wpS, int K, int N, int ldw,
                                             int wlo) {
    __shared__ float tile[64][65];
    int k0 = blockIdx.x * 64, n0 = blockIdx.y * 64;
    int t = threadIdx.x;
    int r = t >> 4, c4 = (t & 15) * 4;
#pragma unroll
    for (int rr = 0; rr < 4; rr++) {
        int row = rr * 16 + r;
        float4 v = *(const float4*)&W[(size_t)(k0 + row) * ldw + n0 + c4];
        tile[row][c4] = v.x; tile[row][c4 + 1] = v.y; tile[row][c4 + 2] = v.z; tile[row][c4 + 3] = v.w;
    }
    __syncthreads();
#pragma unroll
    for (int rr = 0; rr < 4; rr++) {
        int nrow = rr * 16 + r;
        size_t base = (size_t)(n0 + nrow) * K + k0 + c4;
#pragma unroll
        for (int j = 0; j < 4; j++) {
            float val = tile[c4 + j][nrow];
            __hip_bfloat16 hv = f2bf(val);
            WT[base + j] = hv;
            if (wlo) WT[base + j + wpS] = f2bf(val - bf2f(hv));
        }
    }
}

// ---------------------------------------------------------------------------
// Split-bf16 MFMA GEMM: C(MxN) = A(MxK) @ BT(NxK)^T with A,B as hi/lo planes.
// TERMS: 3 = hi*hi + lo*hi + hi*lo (fp32-grade); 1 = hi*hi only (bf16-grade).
// OT: float / __hip_bfloat16 (split 2-plane) / unsigned short (single bf16).
// SIMDB: batch mode over bh (z dim).
template <typename OT, int ACT, int TERMS, int SIMDB>
__global__ __launch_bounds__(256) void gemm_split(const __hip_bfloat16* __restrict__ A, int lda, size_t apS,
                                                  const __hip_bfloat16* __restrict__ BT, int ldb, size_t bpS,
                                                  OT* __restrict__ C, int ldc, size_t cpS, int K,
                                                  const float* __restrict__ bias,
                                                  const float* __restrict__ res,
                                                  int bh0) {
    __shared__ __align__(16) __hip_bfloat16 sAh[128 * 32];
    __shared__ __align__(16) __hip_bfloat16 sBh[128 * 32];
    __shared__ __align__(16) __hip_bfloat16 sAl[TERMS > 1 ? 128 * 32 : 1];
    __shared__ __align__(16) __hip_bfloat16 sBl[TERMS > 1 ? 128 * 32 : 1];
    if constexpr (SIMDB) {
        int bh = bh0 + blockIdx.z;
        A += ((size_t)(bh >> 4) * NSEQ) * lda + (bh & 15) * DH;
        BT += (size_t)(bh >> 4) * MDB * ldb;
        C += (size_t)blockIdx.z * NSEQ * ldc;
    }
    int bn = blockIdx.x * 128;
    int bm = blockIdx.y * 128;
    int t = threadIdx.x;
    int lane = t & 63, wid = t >> 6;
    int wr = wid >> 1, wc = wid & 1;
    int lr = lane & 15, kc = lane >> 4;

    f32x4v acc[4][4];
#pragma unroll
    for (int m = 0; m < 4; m++)
#pragma unroll
        for (int n = 0; n < 4; n++) acc[m][n] = (f32x4v){0.f, 0.f, 0.f, 0.f};

    for (int k0 = 0; k0 < K; k0 += 32) {
        __syncthreads();
#pragma unroll
        for (int it = 0; it < 2; it++) {
            int e = wid * 128 + it * 64 + lane;
            int r = e >> 2;
            int cl = (e & 3) ^ ((r >> 1) & 3);
            size_t aoff = (size_t)(bm + r) * lda + k0 + cl * 8;
            size_t boff = (size_t)(bn + r) * ldb + k0 + cl * 8;
            int dst = (wid * 128 + it * 64) * 8;
            gload16(&A[aoff], &sAh[dst]);
            gload16(&BT[boff], &sBh[dst]);
            if constexpr (TERMS > 1) {
                gload16(&A[aoff + apS], &sAl[dst]);
                gload16(&BT[boff + bpS], &sBl[dst]);
            }
        }
        __syncthreads();

        bf16x8v ah[4], al[4], bh[4], bl[4];
#pragma unroll
        for (int m = 0; m < 4; m++) {
            int row = wr * 64 + m * 16 + lr;
            int off = row * 32 + ((kc ^ ((row >> 1) & 3)) << 3);
            ah[m] = *(const bf16x8v*)&sAh[off];
            if constexpr (TERMS > 1) al[m] = *(const bf16x8v*)&sAl[off];
        }
#pragma unroll
        for (int n = 0; n < 4; n++) {
            int row = wc * 64 + n * 16 + lr;
            int off = row * 32 + ((kc ^ ((row >> 1) & 3)) << 3);
            bh[n] = *(const bf16x8v*)&sBh[off];
            if constexpr (TERMS > 1) bl[n] = *(const bf16x8v*)&sBl[off];
        }
#pragma unroll
        for (int m = 0; m < 4; m++)
#pragma unroll
            for (int n = 0; n < 4; n++) {
                acc[m][n] = __builtin_amdgcn_mfma_f32_16x16x32_bf16(ah[m], bh[n], acc[m][n], 0, 0, 0);
                if constexpr (TERMS > 1) {
                    acc[m][n] = __builtin_amdgcn_mfma_f32_16x16x32_bf16(al[m], bh[n], acc[m][n], 0, 0, 0);
                    acc[m][n] = __builtin_amdgcn_mfma_f32_16x16x32_bf16(ah[m], bl[n], acc[m][n], 0, 0, 0);
                }
            }
    }

#pragma unroll
    for (int m = 0; m < 4; m++) {
#pragma unroll
        for (int n = 0; n < 4; n++) {
            int gcol = bn + wc * 64 + n * 16 + lr;
            float bv = bias ? bias[gcol] : 0.f;
#pragma unroll
            for (int j = 0; j < 4; j++) {
                int grow = bm + wr * 64 + m * 16 + kc * 4 + j;
                float v = acc[m][n][j] + bv;
                if (ACT == 1) v = 0.5f * v * (1.0f + erff(v * 0.70710678118654752f));
                if (res) v += res[(size_t)grow * ldc + gcol];
                size_t idx = (size_t)grow * ldc + gcol;
                if constexpr (__is_same(OT, float)) {
                    C[idx] = v;
                } else if constexpr (__is_same(OT, unsigned short)) {
                    C[idx] = f2bfbits(v);
                } else {
                    __hip_bfloat16 hv = f2bf(v);
                    C[idx] = hv;
                    C[idx + cpS] = f2bf(v - bf2f(hv));
                }
            }
        }
    }
}

// ---------------------------------------------------------------------------
// Split-bf16 MFMA flash attention over XL + causal local keys.
// K/V pre-split by kv_prep; staging is pure global_load_lds.
template <int KNNL>
__global__ __launch_bounds__(256) void flash_kernel(const float* __restrict__ q,
                                                    const unsigned short* __restrict__ ksp,
                                                    const unsigned short* __restrict__ vtp,
                                                    const float* __restrict__ knn_scale,
                                                    __hip_bfloat16* __restrict__ out,
                                                    size_t opS,
                                                    float* __restrict__ stats) {
    __shared__ __align__(16) unsigned short sKh[64 * 64];
    __shared__ __align__(16) unsigned short sKl[64 * 64];
    __shared__ __align__(16) unsigned short sVh[64 * 64];   // transposed [dim][key]
    __shared__ __align__(16) unsigned short sVl[64 * 64];
    __shared__ __align__(16) float sPf[4 * 16 * 64];        // per-wave P fp32

    int qt = blockIdx.x, h = blockIdx.y, b = blockIdx.z;
    int q0 = qt * 64;
    int t = threadIdx.x;
    int w = t >> 6;
    int lane = t & 63;
    int lr = lane & 15, kc = lane >> 4;
    int wbase = w * 1024;

    float scale = KNNL ? __expf(knn_scale[h]) : 0.125f;

    bf16x8v qh[2], ql[2];
    {
        const float* qbase = q + (size_t)(b * NSEQ + q0 + w * 16 + lr) * DIM + h * DH;
#pragma unroll
        for (int ks = 0; ks < 2; ks++) {
            const float* s = qbase + ks * 32 + kc * 8;
            float4 a = *(const float4*)s;
            float4 c2 = *(const float4*)(s + 4);
            float vv[8] = {a.x, a.y, a.z, a.w, c2.x, c2.y, c2.z, c2.w};
            u16x8v hi, lo;
#pragma unroll
            for (int j = 0; j < 8; j++) {
                hi[j] = f2bfbits(vv[j]);
                lo[j] = f2bfbits(vv[j] - bfbits2f(hi[j]));
            }
            qh[ks] = *(bf16x8v*)&hi;
            ql[ks] = *(bf16x8v*)&lo;
        }
    }

    float m[4], l[4];
    f32x4v o[4];
#pragma unroll
    for (int j = 0; j < 4; j++) { m[j] = -1e30f; l[j] = 0.f; }
#pragma unroll
    for (int f = 0; f < 4; f++) o[f] = (f32x4v){0.f, 0.f, 0.f, 0.f};

    int ntiles = 5 + qt;
    size_t kbase = (size_t)b * NKEYS * DH;
    size_t vbase = (size_t)b * DH * NKEYS;

    for (int T = 0; T < ntiles; T++) {
        __syncthreads();
        // ---- stage K + Vt planes via global_load_lds (512 16B-chunks each)
#pragma unroll
        for (int i2 = 0; i2 < 2; i2++) {
            int cbase = i2 * 256 + w * 64;
            int c = cbase + lane;
            int key = c >> 3, ch = (c & 7) ^ (key & 7);
            size_t ko = kbase + (size_t)(T * 64 + key) * DH + ch * 8;
            gload16(&ksp[ko], &sKh[cbase * 8]);
            gload16(&ksp[ko + KSP_PS], &sKl[cbase * 8]);
            int dim = c >> 3, k8 = (c & 7) ^ (dim & 7);
            size_t vo = vbase + (size_t)dim * NKEYS + T * 64 + k8 * 8;
            gload16(&vtp[vo], &sVh[cbase * 8]);
            gload16(&vtp[vo + KSP_PS], &sVl[cbase * 8]);
        }
        __syncthreads();

        f32x4v s4[4];
#pragma unroll
        for (int n = 0; n < 4; n++) s4[n] = (f32x4v){0.f, 0.f, 0.f, 0.f};
#pragma unroll
        for (int ks = 0; ks < 2; ks++) {
            bf16x8v qh_ = qh[ks], ql_ = ql[ks];
#pragma unroll
            for (int n = 0; n < 4; n++) {
                int row = n * 16 + lr;
                int off = row * 64 + (((ks * 4 + kc) ^ (lr & 7)) << 3);
                bf16x8v kh = *(const bf16x8v*)&sKh[off];
                bf16x8v kl = *(const bf16x8v*)&sKl[off];
                s4[n] = __builtin_amdgcn_mfma_f32_16x16x32_bf16(qh_, kh, s4[n], 0, 0, 0);
                s4[n] = __builtin_amdgcn_mfma_f32_16x16x32_bf16(ql_, kh, s4[n], 0, 0, 0);
                s4[n] = __builtin_amdgcn_mfma_f32_16x16x32_bf16(qh_, kl, s4[n], 0, 0, 0);
            }
        }

#pragma unroll
        for (int n = 0; n < 4; n++) {
            int key = T * 64 + n * 16 + lr;
#pragma unroll
            for (int j = 0; j < 4; j++) {
                int gq = q0 + w * 16 + kc * 4 + j;
                float sv = s4[n][j] * scale;
                s4[n][j] = (key <= XLM + gq) ? sv : -1e30f;
            }
        }

        float tm[4];
#pragma unroll
        for (int j = 0; j < 4; j++) {
            float v = fmaxf(fmaxf(s4[0][j], s4[1][j]), fmaxf(s4[2][j], s4[3][j]));
            v = fmaxf(v, __shfl_xor(v, 1, 64));
            v = fmaxf(v, __shfl_xor(v, 2, 64));
            v = fmaxf(v, __shfl_xor(v, 4, 64));
            v = fmaxf(v, __shfl_xor(v, 8, 64));
            tm[j] = v;
        }
        float alpha[4];
#pragma unroll
        for (int j = 0; j < 4; j++) {
            float mnew = fmaxf(m[j], tm[j]);
            alpha[j] = __expf(m[j] - mnew);
            m[j] = mnew;
        }
        float psum[4] = {0.f, 0.f, 0.f, 0.f};
#pragma unroll
        for (int n = 0; n < 4; n++)
#pragma unroll
            for (int j = 0; j < 4; j++) {
                float p = __expf(s4[n][j] - m[j]);
                s4[n][j] = p;
                psum[j] += p;
            }
#pragma unroll
        for (int j = 0; j < 4; j++) {
            float v = psum[j];
            v += __shfl_xor(v, 1, 64);
            v += __shfl_xor(v, 2, 64);
            v += __shfl_xor(v, 4, 64);
            v += __shfl_xor(v, 8, 64);
            l[j] = l[j] * alpha[j] + v;
        }
#pragma unroll
        for (int f = 0; f < 4; f++)
#pragma unroll
            for (int j = 0; j < 4; j++) o[f][j] *= alpha[j];

#pragma unroll
        for (int n = 0; n < 4; n++) {
            int chunkcol = 2 * n + (lr >> 3);
#pragma unroll
            for (int j = 0; j < 4; j++) {
                int row = kc * 4 + j;
                int off = wbase + row * 64 + (((chunkcol ^ (row & 7)) << 3) + (lr & 7));
                sPf[off] = s4[n][j];
            }
        }

#pragma unroll
        for (int ks = 0; ks < 2; ks++) {
            int poff = wbase + lr * 64 + (((ks * 4 + kc) ^ (lr & 7)) << 3);
            float4 a = *(const float4*)&sPf[poff];
            float4 c2 = *(const float4*)&sPf[poff + 4];
            float vv[8] = {a.x, a.y, a.z, a.w, c2.x, c2.y, c2.z, c2.w};
            u16x8v hib, lob;
#pragma unroll
            for (int j = 0; j < 8; j++) {
                hib[j] = f2bfbits(vv[j]);
                lob[j] = f2bfbits(vv[j] - bfbits2f(hib[j]));
            }
            bf16x8v ph = *(bf16x8v*)&hib;
            bf16x8v pl = *(bf16x8v*)&lob;
#pragma unroll
            for (int f = 0; f < 4; f++) {
                int row = f * 16 + lr;
                int off = row * 64 + (((ks * 4 + kc) ^ (lr & 7)) << 3);
                bf16x8v vh = *(const bf16x8v*)&sVh[off];
                bf16x8v vl = *(const bf16x8v*)&sVl[off];
                o[f] = __builtin_amdgcn_mfma_f32_16x16x32_bf16(ph, vh, o[f], 0, 0, 0);
                o[f] = __builtin_amdgcn_mfma_f32_16x16x32_bf16(pl, vh, o[f], 0, 0, 0);
                o[f] = __builtin_amdgcn_mfma_f32_16x16x32_bf16(ph, vl, o[f], 0, 0, 0);
            }
        }
    }

    float inv[4];
#pragma unroll
    for (int j = 0; j < 4; j++) inv[j] = 1.0f / l[j];
    unsigned short* outu = (unsigned short*)out;
#pragma unroll
    for (int f = 0; f < 4; f++)
#pragma unroll
        for (int j = 0; j < 4; j++) {
            int gq = q0 + w * 16 + kc * 4 + j;
            size_t oidx = (size_t)(b * NSEQ + gq) * DIM + h * DH + f * 16 + lr;
            float v = o[f][j] * inv[j];
            unsigned short hv = f2bfbits(v);
            outu[oidx] = hv;
            outu[oidx + opS] = f2bfbits(v - bfbits2f(hv));
        }
    if (KNNL && lr == 0) {
#pragma unroll
        for (int j = 0; j < 4; j++) {
            int gq = q0 + w * 16 + kc * 4 + j;
            size_t srow = (((size_t)b * NH + h) * NSEQ + gq) * 2;
            stats[srow] = m[j];
            stats[srow + 1] = l[j];
        }
    }
}

// ---------------------------------------------------------------------------
// Per-row top-32 over bf16 simdb + exact recompute + mem softmax + combine.
__global__ __launch_bounds__(256) void knn_select(const unsigned short* __restrict__ simdb,
                                                  const float* __restrict__ db,
                                                  const float* __restrict__ qf,
                                                  const float* __restrict__ dbkn,
                                                  const float* __restrict__ knn_scale,
                                                  const float* __restrict__ stats,
                                                  __hip_bfloat16* __restrict__ out,
                                                  size_t opS,
                                                  int bh0) {
    __shared__ unsigned short sv[64 * 65];
    __shared__ float cval[4 * 64];
    __shared__ int cidx[4 * 64];
    __shared__ float stopv[TOPK];
    __shared__ int stopi[TOPK];
    __shared__ float part[4][64];

    int bh = bh0 + blockIdx.y;
    int b = bh >> 4, h = bh & 15;
    int i = blockIdx.x;
    int t = threadIdx.x;
    int w = t >> 6, lane = t & 63;

    // stage bf16 row: 2 iters x 256 thr x 8 ushorts (16B)
    const unsigned short* srow = &simdb[((size_t)blockIdx.y * NSEQ + i) * MDB];
#pragma unroll
    for (int ii = 0; ii < 2; ii++) {
        int idx = ii * 256 + t;
        int chunk = idx >> 3, sub = idx & 7;
        u16x8v g = *(const u16x8v*)&srow[(size_t)idx * 8];
        *(u16x8v*)&sv[chunk * 65 + sub * 8] = g;
    }
    __syncthreads();

    // per-column candidates: wave w scans chunks [w*16, w*16+16)
    float lmax = -1e30f; int lidx = 0;
#pragma unroll
    for (int c = 0; c < 16; c++) {
        int chunk = w * 16 + c;
        float v = bfbits2f(sv[chunk * 65 + lane]);
        int id = chunk * 64 + lane;
        if (v > lmax || (v == lmax && id < lidx)) { lmax = v; lidx = id; }
    }
    cval[w * 64 + lane] = lmax; cidx[w * 64 + lane] = lidx;
    __syncthreads();

    if (w == 0) {
        float bvv = cval[lane]; int bii = cidx[lane];
#pragma unroll
        for (int g = 1; g < 4; g++) {
            float v2 = cval[g * 64 + lane]; int i2 = cidx[g * 64 + lane];
            if (v2 > bvv || (v2 == bvv && i2 < bii)) { bvv = v2; bii = i2; }
        }
        lmax = bvv; lidx = bii;
        for (int it = 0; it < TOPK; it++) {
            float v = lmax; int idx = lidx;
#pragma unroll
            for (int off = 32; off; off >>= 1) {
                float v2 = __shfl_xor(v, off, 64);
                int i2 = __shfl_xor(idx, off, 64);
                if (v2 > v || (v2 == v && i2 < idx)) { v = v2; idx = i2; }
            }
            if (lane == it) stopi[it] = idx;
            int col = idx & 63;
            if (lane == (idx >> 6)) sv[(idx >> 6) * 65 + col] = 0xFF80;  // -inf
            float rv = bfbits2f(sv[lane * 65 + col]);
            int ridx = lane * 64 + col;
#pragma unroll
            for (int off = 32; off; off >>= 1) {
                float v2 = __shfl_xor(rv, off, 64);
                int i2 = __shfl_xor(ridx, off, 64);
                if (v2 > rv || (v2 == rv && i2 < ridx)) { rv = v2; ridx = i2; }
            }
            if (lane == col) { lmax = rv; lidx = ridx; }
        }
        // exact recompute of selected sims (q, dbkn both L2-resident fp32)
        if (lane < TOPK) {
            const float* qrow = &qf[(size_t)(b * NSEQ + i) * DIM + h * DH];
            const float* krow = &dbkn[((size_t)b * MDB + stopi[lane]) * DH];
            float s = 0.f;
#pragma unroll
            for (int d4 = 0; d4 < 16; d4++) {
                float4 a = *(const float4*)&qrow[d4 * 4];
                float4 k2 = *(const float4*)&krow[d4 * 4];
                s += a.x * k2.x + a.y * k2.y + a.z * k2.z + a.w * k2.w;
            }
            stopv[lane] = s;
        }
    }
    __syncthreads();

    float scl = __expf(knn_scale[h]);
    size_t srow_idx = (((size_t)b * NH + h) * NSEQ + i) * 2;
    float m_loc = stats[srow_idx], l_loc = stats[srow_idx + 1];
    float sval = (lane < TOPK) ? stopv[lane] : -1e30f;
    float mm = sval;
#pragma unroll
    for (int off = 32; off; off >>= 1) mm = fmaxf(mm, __shfl_xor(mm, off, 64));
    float M = fmaxf(m_loc, mm * scl);
    float co = __expf(m_loc - M);
    float e = (lane < TOPK) ? __expf(sval * scl - M) : 0.f;
    float esum = e;
#pragma unroll
    for (int off = 32; off; off >>= 1) esum += __shfl_xor(esum, off, 64);
    float denom = l_loc * co + esum;

    float acc = 0.f;
#pragma unroll
    for (int jj = 0; jj < 8; jj++) {
        int j = w * 8 + jj;
        float ej = __expf(stopv[j] * scl - M);
        acc += ej * db[(((size_t)b * MDB + stopi[j]) * 2 + 1) * DH + lane];
    }
    part[w][lane] = acc;
    __syncthreads();
    if (w == 0) {
        float a = part[0][lane] + part[1][lane] + part[2][lane] + part[3][lane];
        size_t op = (size_t)(b * NSEQ + i) * DIM + h * DH + lane;
        float o_loc = bf2f(out[op]) + bf2f(out[op + opS]);
        float nv = (o_loc * l_loc * co + a) / denom;
        __hip_bfloat16 hv = f2bf(nv);
        out[op] = hv;
        out[op + opS] = f2bf(nv - bf2f(hv));
    }
}

// ---------------------------------------------------------------------------
extern "C" void kernel_launch(void* const* d_in, const int* in_sizes, int n_in,
                              void* d_out, int out_size, void* d_ws, size_t ws_size,
                              hipStream_t stream) {
    const int* tokens = (const int*)d_in[0];
    const float* emb = (const float*)d_in[1];
    const float* ln1_w = (const float*)d_in[2];
    const float* ln1_b = (const float*)d_in[3];
    const float* wq = (const float*)d_in[4];
    const float* wkv = (const float*)d_in[5];
    const float* wo = (const float*)d_in[6];
    const float* wo_b = (const float*)d_in[7];
    const float* knn_scale = (const float*)d_in[8];
    const float* ln2_w = (const float*)d_in[9];
    const float* ln2_b = (const float*)d_in[10];
    const float* ff_w1 = (const float*)d_in[11];
    const float* ff_b1 = (const float*)d_in[12];
    const float* ff_w2 = (const float*)d_in[13];
    const float* ff_b2 = (const float*)d_in[14];
    const float* lnf_w = (const float*)d_in[15];
    const float* lnf_b = (const float*)d_in[16];
    const float* w_logits = (const float*)d_in[17];
    const float* b_logits = (const float*)d_in[18];
    const float* xl_mems = (const float*)d_in[19];
    const float* db_kv = (const float*)d_in[20];

    // ---- workspace layout ----
    const size_t PS_H = (size_t)BNROWS * DIM;        // plane stride for h / attn-out
    char* p = (char*)d_ws;
    float* x = (float*)p;                p += PS_H * 4;                        // 8 MB
    __hip_bfloat16* hb = (__hip_bfloat16*)p;  p += PS_H * 2 * 2;               // 8 MB (2 planes)
    float* qf = (float*)p;               p += PS_H * 4;                        // 8 MB
    float* kvf = (float*)p;              p += (size_t)BNROWS * 128 * 4;        // 1 MB
    float* dbkn = (float*)p;             p += (size_t)BB * MDB * DH * 4;       // 2 MB
    float* stats = (float*)p;            p += (size_t)BB * NH * NSEQ * 2 * 4;  // 0.25 MB
    unsigned short* ksp = (unsigned short*)p; p += KSP_PS * 2 * 2;             // 0.66 MB
    unsigned short* vtp = (unsigned short*)p; p += KSP_PS * 2 * 2;             // 0.66 MB
    __hip_bfloat16* wT = (__hip_bfloat16*)p; p += (size_t)4096 * DIM * 2 * 2;  // 16 MB (2 planes)

    // qsplit/dbkn-split live in the wT region during the KNN phase (wT idle)
    unsigned short* qsplit = (unsigned short*)wT;                  // 2 planes x PS_H
    unsigned short* dbks = (unsigned short*)wT + 2 * PS_H;         // 2 planes x BB*MDB*DH
    const size_t PS_DB = (size_t)BB * MDB * DH;

    const size_t PS_MID = (size_t)BNROWS * 4 * DIM;  // 8M elems per plane
    __hip_bfloat16* midb = (__hip_bfloat16*)d_out;   // 32 MB of the 262 MB out buf
    float* logits = (float*)d_out;

    embed_kernel<<<BNROWS, 256, 0, stream>>>(tokens, emb, x);
    dbnorm_kernel<<<BB * MDB, 64, 0, stream>>>(db_kv, dbkn);

    for (int l = 0; l < DEPTH; l++) {
        const float* wq_l = wq + (size_t)l * DIM * DIM;
        const float* wkv_l = wkv + (size_t)l * DIM * 128;
        const float* wo_l = wo + (size_t)l * DIM * DIM;
        const float* xlm_l = xl_mems + (size_t)l * BB * XLM * 2 * DH;

        // h = LN1(x) -> split bf16
        ln_kernel<<<BNROWS, 256, 0, stream>>>(x, ln1_w + (size_t)l * DIM, ln1_b + (size_t)l * DIM, hb, PS_H);

        // q = h @ wq  (fp32 out)
        wconv<<<dim3(16, 16), 256, 0, stream>>>(wq_l, wT, (size_t)DIM * DIM, DIM, DIM, DIM, 1);
        gemm_split<float, 0, 3, 0><<<dim3(DIM / 128, BNROWS / 128), 256, 0, stream>>>(
            hb, DIM, PS_H, wT, DIM, (size_t)DIM * DIM, qf, DIM, 0, DIM, nullptr, nullptr, 0);
        // kv = h @ wkv (fp32 out)
        wconv<<<dim3(16, 2), 256, 0, stream>>>(wkv_l, wT, (size_t)128 * DIM, DIM, 128, 128, 1);
        gemm_split<float, 0, 3, 0><<<dim3(1, BNROWS / 128), 256, 0, stream>>>(
            hb, DIM, PS_H, wT, DIM, (size_t)128 * DIM, kvf, 128, 0, DIM, nullptr, nullptr, 0);

        if (l == KNN_LAYER) {
            l2norm_kernel<<<BNROWS * NH, 64, 0, stream>>>(qf, DH);
            l2norm_kernel<<<BNROWS, 64, 0, stream>>>(kvf, 128);
            kv_prep<<<dim3(NKEYS, BB), 64, 0, stream>>>(kvf, xlm_l, ksp, vtp);
            split_conv<<<(PS_H / 4 + 255) / 256, 256, 0, stream>>>(qf, qsplit, PS_H, PS_H / 4);
            split_conv<<<(PS_DB / 4 + 255) / 256, 256, 0, stream>>>(dbkn, dbks, PS_DB, PS_DB / 4);
            flash_kernel<1><<<dim3(NSEQ / 64, NH, BB), 256, 0, stream>>>(
                qf, ksp, vtp, knn_scale, hb, PS_H, stats);
            const int CHUNK = 16;  // 16 slices x 8 MB bf16 = 134 MB in d_out
            for (int bh0 = 0; bh0 < BB * NH; bh0 += CHUNK) {
                gemm_split<unsigned short, 0, 3, 1><<<dim3(MDB / 128, NSEQ / 128, CHUNK), 256, 0, stream>>>(
                    (const __hip_bfloat16*)qsplit, DIM, PS_H,
                    (const __hip_bfloat16*)dbks, DH, PS_DB,
                    (unsigned short*)d_out, MDB, 0, DH, nullptr, nullptr, bh0);
                knn_select<<<dim3(NSEQ, CHUNK), 256, 0, stream>>>(
                    (const unsigned short*)d_out, db_kv, qf, dbkn, knn_scale, stats, hb, PS_H, bh0);
            }
        } else {
            kv_prep<<<dim3(NKEYS, BB), 64, 0, stream>>>(kvf, xlm_l, ksp, vtp);
            flash_kernel<0><<<dim3(NSEQ / 64, NH, BB), 256, 0, stream>>>(
                qf, ksp, vtp, knn_scale, hb, PS_H, stats);
        }

        // x = attn @ wo + wo_b + x
        wconv<<<dim3(16, 16), 256, 0, stream>>>(wo_l, wT, (size_t)DIM * DIM, DIM, DIM, DIM, 1);
        gemm_split<float, 0, 3, 0><<<dim3(DIM / 128, BNROWS / 128), 256, 0, stream>>>(
            hb, DIM, PS_H, wT, DIM, (size_t)DIM * DIM, x, DIM, 0, DIM,
            wo_b + (size_t)l * DIM, x, 0);

        // h = LN2(x)
        ln_kernel<<<BNROWS, 256, 0, stream>>>(x, ln2_w + (size_t)l * DIM, ln2_b + (size_t)l * DIM, hb, PS_H);
        // mid = gelu(h @ ff_w1 + b1) -> split bf16 (in d_out)
        wconv<<<dim3(16, 64), 256, 0, stream>>>(ff_w1 + (size_t)l * DIM * 4 * DIM, wT, (size_t)4096 * DIM, DIM, 4 * DIM, 4 * DIM, 1);
        gemm_split<__hip_bfloat16, 1, 3, 0><<<dim3(4 * DIM / 128, BNROWS / 128), 256, 0, stream>>>(
            hb, DIM, PS_H, wT, DIM, (size_t)4096 * DIM, midb, 4 * DIM, PS_MID, DIM,
            ff_b1 + (size_t)l * 4 * DIM, nullptr, 0);
        // x = mid @ ff_w2 + b2 + x
        wconv<<<dim3(64, 16), 256, 0, stream>>>(ff_w2 + (size_t)l * 4 * DIM * DIM, wT, (size_t)DIM * 4096, 4 * DIM, DIM, DIM, 1);
        gemm_split<float, 0, 3, 0><<<dim3(DIM / 128, BNROWS / 128), 256, 0, stream>>>(
            midb, 4 * DIM, PS_MID, wT, 4 * DIM, (size_t)DIM * 4096, x, DIM, 0, 4 * DIM,
            ff_b2 + (size_t)l * DIM, x, 0);
    }

    // final LN + logits (5 column chunks of 6400, hi-plane-only bf16 GEMM)
    ln_kernel<<<BNROWS, 256, 0, stream>>>(x, lnf_w, lnf_b, hb, PS_H);
    for (int c0 = 0; c0 < VOCAB; c0 += LOGITS_CHUNK) {
        wconv<<<dim3(16, LOGITS_CHUNK / 64), 256, 0, stream>>>(
            w_logits + c0, wT, 0, DIM, LOGITS_CHUNK, VOCAB, 0);
        gemm_split<float, 0, 1, 0><<<dim3(LOGITS_CHUNK / 128, BNROWS / 128), 256, 0, stream>>>(
            hb, DIM, PS_H, wT, DIM, 0, logits + c0, VOCAB, 0, DIM,
            b_logits + c0, nullptr, 0);
    }
}

// Round 10
// 2767.232 us; speedup vs baseline: 6.8657x; 1.1545x over previous
//
#include <hip/hip_runtime.h>
#include <hip/hip_bf16.h>
#include <math.h>

// Problem constants (from setup_inputs)
#define BB 2
#define NSEQ 1024
#define DIM 1024
#define NH 16
#define DH 64
#define DEPTH 4
#define VOCAB 32000
#define XLM 256
#define MDB 4096
#define TOPK 32
#define KNN_LAYER 2
#define BNROWS (BB * NSEQ)   // 2048
#define LOGITS_CHUNK 6400    // 32000 = 5 * 6400
#define NKEYS 1280           // XLM + NSEQ
#define KSP_PS ((size_t)BB * NKEYS * DH)   // plane stride for K/V split planes

typedef __bf16 bf16x8v __attribute__((ext_vector_type(8)));
typedef float f32x4v __attribute__((ext_vector_type(4)));
typedef unsigned short u16x8v __attribute__((ext_vector_type(8)));

__device__ __forceinline__ float bfbits2f(unsigned short u) {
    union { float f; unsigned int i; } v; v.i = ((unsigned int)u) << 16; return v.f;
}
__device__ __forceinline__ unsigned short f2bfbits(float f) {
    union { __hip_bfloat16 b; unsigned short u; } v;
    v.b = __float2bfloat16(f);
    return v.u;
}
__device__ __forceinline__ float bf2f(__hip_bfloat16 h) { return __bfloat162float(h); }
__device__ __forceinline__ __hip_bfloat16 f2bf(float f) { return __float2bfloat16(f); }

__device__ __forceinline__ void gload16(const void* gp, void* lp) {
    __builtin_amdgcn_global_load_lds(
        (const __attribute__((address_space(1))) unsigned int*)gp,
        (__attribute__((address_space(3))) unsigned int*)lp, 16, 0, 0);
}

// ---------------------------------------------------------------------------
__global__ __launch_bounds__(256) void embed_kernel(const int* __restrict__ tok,
                                                    const float* __restrict__ emb,
                                                    float* __restrict__ x) {
    int r = blockIdx.x, t = threadIdx.x;
    int id = tok[r];
    const float* er = emb + (size_t)id * DIM;
    float* xr = x + (size_t)r * DIM;
#pragma unroll
    for (int i = 0; i < 4; i++) xr[t + 256 * i] = er[t + 256 * i];
}

// ---------------------------------------------------------------------------
// Row LayerNorm over DIM=1024, fp32 in, split-bf16 (hi/lo planes) out
__global__ __launch_bounds__(256) void ln_kernel(const float* __restrict__ x,
                                                 const float* __restrict__ w,
                                                 const float* __restrict__ b,
                                                 __hip_bfloat16* __restrict__ y,
                                                 size_t ypS) {
    __shared__ float red[256];
    int r = blockIdx.x, t = threadIdx.x;
    const float* xr = x + (size_t)r * DIM;
    float v[4];
#pragma unroll
    for (int i = 0; i < 4; i++) v[i] = xr[t + 256 * i];
    float s = v[0] + v[1] + v[2] + v[3];
    red[t] = s; __syncthreads();
    for (int st = 128; st; st >>= 1) { if (t < st) red[t] += red[t + st]; __syncthreads(); }
    float mean = red[0] * (1.0f / DIM);
    __syncthreads();
    float s2 = 0.f;
#pragma unroll
    for (int i = 0; i < 4; i++) { float d = v[i] - mean; s2 += d * d; }
    red[t] = s2; __syncthreads();
    for (int st = 128; st; st >>= 1) { if (t < st) red[t] += red[t + st]; __syncthreads(); }
    float rs = rsqrtf(red[0] * (1.0f / DIM) + 1e-5f);
    __hip_bfloat16* yr = y + (size_t)r * DIM;
#pragma unroll
    for (int i = 0; i < 4; i++) {
        int c = t + 256 * i;
        float val = (v[i] - mean) * rs * w[c] + b[c];
        __hip_bfloat16 hv = f2bf(val);
        yr[c] = hv;
        yr[c + ypS] = f2bf(val - bf2f(hv));
    }
}

// ---------------------------------------------------------------------------
// L2-normalize fp32 rows of length 64 (row stride configurable), in-place
__global__ void l2norm_kernel(float* __restrict__ p, int stride) {
    int r = blockIdx.x, t = threadIdx.x; // 64 threads
    float* pr = p + (size_t)r * stride;
    float v = pr[t];
    float s = v * v;
#pragma unroll
    for (int off = 32; off; off >>= 1) s += __shfl_xor(s, off, 64);
    float n = fmaxf(sqrtf(s), 1e-12f);
    pr[t] = v / n;
}

__global__ void dbnorm_kernel(const float* __restrict__ db, float* __restrict__ dbkn) {
    int r = blockIdx.x, t = threadIdx.x; // 64 threads
    float v = db[((size_t)r * 2 + 0) * DH + t];
    float s = v * v;
#pragma unroll
    for (int off = 32; off; off >>= 1) s += __shfl_xor(s, off, 64);
    float n = fmaxf(sqrtf(s), 1e-12f);
    dbkn[(size_t)r * DH + t] = v / n;
}

// ---------------------------------------------------------------------------
// fp32 -> split-bf16 planes (hi at y, lo at y+pS). n4 = n/4 float4 groups.
__global__ __launch_bounds__(256) void split_conv(const float* __restrict__ x,
                                                  unsigned short* __restrict__ y,
                                                  size_t pS, size_t n4) {
    size_t idx = (size_t)blockIdx.x * 256 + threadIdx.x;
    if (idx >= n4) return;
    float4 v = *(const float4*)&x[idx * 4];
    float vv[4] = {v.x, v.y, v.z, v.w};
    ushort4 h4, l4;
    unsigned short* hp = (unsigned short*)&h4;
    unsigned short* lp = (unsigned short*)&l4;
#pragma unroll
    for (int j = 0; j < 4; j++) {
        hp[j] = f2bfbits(vv[j]);
        lp[j] = f2bfbits(vv[j] - bfbits2f(hp[j]));
    }
    *(ushort4*)&y[idx * 4] = h4;
    *(ushort4*)&y[idx * 4 + pS] = l4;
}

// ---------------------------------------------------------------------------
// Per-layer K/V split-bf16 prep: K planes [b][key][dim]; V transposed planes
// [b][dim][key]. keys 0..255 from xlm, 256..1279 from fresh kv.
__global__ void kv_prep(const float* __restrict__ kvf, const float* __restrict__ xlm,
                        unsigned short* __restrict__ ksp, unsigned short* __restrict__ vtp) {
    int key = blockIdx.x, b = blockIdx.y, d = threadIdx.x; // 64 threads
    float kvv, vvv;
    if (key < XLM) {
        kvv = xlm[(((size_t)b * XLM + key) * 2 + 0) * DH + d];
        vvv = xlm[(((size_t)b * XLM + key) * 2 + 1) * DH + d];
    } else {
        const float* r = &kvf[(size_t)(b * NSEQ + key - XLM) * 128];
        kvv = r[d]; vvv = r[64 + d];
    }
    unsigned short kh = f2bfbits(kvv), kl = f2bfbits(kvv - bfbits2f(kh));
    unsigned short vh = f2bfbits(vvv), vl = f2bfbits(vvv - bfbits2f(vh));
    size_t ko = (size_t)b * NKEYS * DH + (size_t)key * DH + d;
    ksp[ko] = kh; ksp[ko + KSP_PS] = kl;
    size_t vo = (size_t)b * DH * NKEYS + (size_t)d * NKEYS + key;
    vtp[vo] = vh; vtp[vo + KSP_PS] = vl;
}

// ---------------------------------------------------------------------------
// Weight convert + transpose: W (K x N fp32, row stride ldw) ->
// WT (N x K split-bf16, hi plane + lo plane at +wpS). wlo=0: hi only.
__global__ __launch_bounds__(256) void wconv(const float* __restrict__ W,
                                             __hip_bfloat16* __restrict__ WT,
                                             size_t wpS, int K, int N, int ldw,
                                             int wlo) {
    __shared__ float tile[64][65];
    int k0 = blockIdx.x * 64, n0 = blockIdx.y * 64;
    int t = threadIdx.x;
    int r = t >> 4, c4 = (t & 15) * 4;
#pragma unroll
    for (int rr = 0; rr < 4; rr++) {
        int row = rr * 16 + r;
        float4 v = *(const float4*)&W[(size_t)(k0 + row) * ldw + n0 + c4];
        tile[row][c4] = v.x; tile[row][c4 + 1] = v.y; tile[row][c4 + 2] = v.z; tile[row][c4 + 3] = v.w;
    }
    __syncthreads();
#pragma unroll
    for (int rr = 0; rr < 4; rr++) {
        int nrow = rr * 16 + r;
        size_t base = (size_t)(n0 + nrow) * K + k0 + c4;
#pragma unroll
        for (int j = 0; j < 4; j++) {
            float val = tile[c4 + j][nrow];
            __hip_bfloat16 hv = f2bf(val);
            WT[base + j] = hv;
            if (wlo) WT[base + j + wpS] = f2bf(val - bf2f(hv));
        }
    }
}

// ---------------------------------------------------------------------------
// Split-bf16 MFMA GEMM: C(MxN) = A(MxK) @ BT(NxK)^T with A,B as hi/lo planes.
// TERMS: 3 = hi*hi + lo*hi + hi*lo (fp32-grade); 1 = hi*hi only (bf16-grade).
// OT: float / __hip_bfloat16 (split 2-plane) / unsigned short (single bf16).
// SIMDB: batch mode over bh (z dim).
template <typename OT, int ACT, int TERMS, int SIMDB>
__global__ __launch_bounds__(256) void gemm_split(const __hip_bfloat16* __restrict__ A, int lda, size_t apS,
                                                  const __hip_bfloat16* __restrict__ BT, int ldb, size_t bpS,
                                                  OT* __restrict__ C, int ldc, size_t cpS, int K,
                                                  const float* __restrict__ bias,
                                                  const float* __restrict__ res,
                                                  int bh0) {
    __shared__ __align__(16) __hip_bfloat16 sAh[128 * 32];
    __shared__ __align__(16) __hip_bfloat16 sBh[128 * 32];
    __shared__ __align__(16) __hip_bfloat16 sAl[TERMS >= 2 ? 128 * 32 : 1];
    __shared__ __align__(16) __hip_bfloat16 sBl[TERMS >= 3 ? 128 * 32 : 1];
    if constexpr (SIMDB) {
        int bh = bh0 + blockIdx.z;
        A += ((size_t)(bh >> 4) * NSEQ) * lda + (bh & 15) * DH;
        BT += (size_t)(bh >> 4) * MDB * ldb;
        C += (size_t)blockIdx.z * NSEQ * ldc;
    }
    int bn = blockIdx.x * 128;
    int bm = blockIdx.y * 128;
    int t = threadIdx.x;
    int lane = t & 63, wid = t >> 6;
    int wr = wid >> 1, wc = wid & 1;
    int lr = lane & 15, kc = lane >> 4;

    f32x4v acc[4][4];
#pragma unroll
    for (int m = 0; m < 4; m++)
#pragma unroll
        for (int n = 0; n < 4; n++) acc[m][n] = (f32x4v){0.f, 0.f, 0.f, 0.f};

    for (int k0 = 0; k0 < K; k0 += 32) {
        __syncthreads();
#pragma unroll
        for (int it = 0; it < 2; it++) {
            int e = wid * 128 + it * 64 + lane;
            int r = e >> 2;
            int cl = (e & 3) ^ ((r >> 1) & 3);
            size_t aoff = (size_t)(bm + r) * lda + k0 + cl * 8;
            size_t boff = (size_t)(bn + r) * ldb + k0 + cl * 8;
            int dst = (wid * 128 + it * 64) * 8;
            gload16(&A[aoff], &sAh[dst]);
            gload16(&BT[boff], &sBh[dst]);
            if constexpr (TERMS >= 2) gload16(&A[aoff + apS], &sAl[dst]);
            if constexpr (TERMS >= 3) gload16(&BT[boff + bpS], &sBl[dst]);
        }
        __syncthreads();

        bf16x8v ah[4], al[4], bh[4], bl[4];
#pragma unroll
        for (int m = 0; m < 4; m++) {
            int row = wr * 64 + m * 16 + lr;
            int off = row * 32 + ((kc ^ ((row >> 1) & 3)) << 3);
            ah[m] = *(const bf16x8v*)&sAh[off];
            if constexpr (TERMS >= 2) al[m] = *(const bf16x8v*)&sAl[off];
        }
#pragma unroll
        for (int n = 0; n < 4; n++) {
            int row = wc * 64 + n * 16 + lr;
            int off = row * 32 + ((kc ^ ((row >> 1) & 3)) << 3);
            bh[n] = *(const bf16x8v*)&sBh[off];
            if constexpr (TERMS >= 3) bl[n] = *(const bf16x8v*)&sBl[off];
        }
#pragma unroll
        for (int m = 0; m < 4; m++)
#pragma unroll
            for (int n = 0; n < 4; n++) {
                acc[m][n] = __builtin_amdgcn_mfma_f32_16x16x32_bf16(ah[m], bh[n], acc[m][n], 0, 0, 0);
                if constexpr (TERMS >= 2)
                    acc[m][n] = __builtin_amdgcn_mfma_f32_16x16x32_bf16(al[m], bh[n], acc[m][n], 0, 0, 0);
                if constexpr (TERMS >= 3)
                    acc[m][n] = __builtin_amdgcn_mfma_f32_16x16x32_bf16(ah[m], bl[n], acc[m][n], 0, 0, 0);
            }
    }

#pragma unroll
    for (int m = 0; m < 4; m++) {
#pragma unroll
        for (int n = 0; n < 4; n++) {
            int gcol = bn + wc * 64 + n * 16 + lr;
            float bv = bias ? bias[gcol] : 0.f;
#pragma unroll
            for (int j = 0; j < 4; j++) {
                int grow = bm + wr * 64 + m * 16 + kc * 4 + j;
                float v = acc[m][n][j] + bv;
                if (ACT == 1) v = 0.5f * v * (1.0f + erff(v * 0.70710678118654752f));
                if (res) v += res[(size_t)grow * ldc + gcol];
                size_t idx = (size_t)grow * ldc + gcol;
                if constexpr (__is_same(OT, float)) {
                    C[idx] = v;
                } else if constexpr (__is_same(OT, unsigned short)) {
                    C[idx] = f2bfbits(v);
                } else {
                    __hip_bfloat16 hv = f2bf(v);
                    C[idx] = hv;
                    C[idx + cpS] = f2bf(v - bf2f(hv));
                }
            }
        }
    }
}

// ---------------------------------------------------------------------------
// Split-bf16 MFMA flash attention over XL + causal local keys.
// K/V pre-split by kv_prep; staging is pure global_load_lds.
template <int KNNL>
__global__ __launch_bounds__(256) void flash_kernel(const float* __restrict__ q,
                                                    const unsigned short* __restrict__ ksp,
                                                    const unsigned short* __restrict__ vtp,
                                                    const float* __restrict__ knn_scale,
                                                    __hip_bfloat16* __restrict__ out,
                                                    size_t opS,
                                                    float* __restrict__ stats) {
    __shared__ __align__(16) unsigned short sKh[64 * 64];
    __shared__ __align__(16) unsigned short sKl[64 * 64];
    __shared__ __align__(16) unsigned short sVh[64 * 64];   // transposed [dim][key]
    __shared__ __align__(16) unsigned short sVl[64 * 64];
    __shared__ __align__(16) float sPf[4 * 16 * 64];        // per-wave P fp32

    int qt = blockIdx.x, h = blockIdx.y, b = blockIdx.z;
    int q0 = qt * 64;
    int t = threadIdx.x;
    int w = t >> 6;
    int lane = t & 63;
    int lr = lane & 15, kc = lane >> 4;
    int wbase = w * 1024;

    float scale = KNNL ? __expf(knn_scale[h]) : 0.125f;

    bf16x8v qh[2], ql[2];
    {
        const float* qbase = q + (size_t)(b * NSEQ + q0 + w * 16 + lr) * DIM + h * DH;
#pragma unroll
        for (int ks = 0; ks < 2; ks++) {
            const float* s = qbase + ks * 32 + kc * 8;
            float4 a = *(const float4*)s;
            float4 c2 = *(const float4*)(s + 4);
            float vv[8] = {a.x, a.y, a.z, a.w, c2.x, c2.y, c2.z, c2.w};
            u16x8v hi, lo;
#pragma unroll
            for (int j = 0; j < 8; j++) {
                hi[j] = f2bfbits(vv[j]);
                lo[j] = f2bfbits(vv[j] - bfbits2f(hi[j]));
            }
            qh[ks] = *(bf16x8v*)&hi;
            ql[ks] = *(bf16x8v*)&lo;
        }
    }

    float m[4], l[4];
    f32x4v o[4];
#pragma unroll
    for (int j = 0; j < 4; j++) { m[j] = -1e30f; l[j] = 0.f; }
#pragma unroll
    for (int f = 0; f < 4; f++) o[f] = (f32x4v){0.f, 0.f, 0.f, 0.f};

    int ntiles = 5 + qt;
    size_t kbase = (size_t)b * NKEYS * DH;
    size_t vbase = (size_t)b * DH * NKEYS;

    for (int T = 0; T < ntiles; T++) {
        __syncthreads();
        // ---- stage K + Vt planes via global_load_lds (512 16B-chunks each)
#pragma unroll
        for (int i2 = 0; i2 < 2; i2++) {
            int cbase = i2 * 256 + w * 64;
            int c = cbase + lane;
            int key = c >> 3, ch = (c & 7) ^ (key & 7);
            size_t ko = kbase + (size_t)(T * 64 + key) * DH + ch * 8;
            gload16(&ksp[ko], &sKh[cbase * 8]);
            gload16(&ksp[ko + KSP_PS], &sKl[cbase * 8]);
            int dim = c >> 3, k8 = (c & 7) ^ (dim & 7);
            size_t vo = vbase + (size_t)dim * NKEYS + T * 64 + k8 * 8;
            gload16(&vtp[vo], &sVh[cbase * 8]);
            gload16(&vtp[vo + KSP_PS], &sVl[cbase * 8]);
        }
        __syncthreads();

        f32x4v s4[4];
#pragma unroll
        for (int n = 0; n < 4; n++) s4[n] = (f32x4v){0.f, 0.f, 0.f, 0.f};
#pragma unroll
        for (int ks = 0; ks < 2; ks++) {
            bf16x8v qh_ = qh[ks], ql_ = ql[ks];
#pragma unroll
            for (int n = 0; n < 4; n++) {
                int row = n * 16 + lr;
                int off = row * 64 + (((ks * 4 + kc) ^ (lr & 7)) << 3);
                bf16x8v kh = *(const bf16x8v*)&sKh[off];
                bf16x8v kl = *(const bf16x8v*)&sKl[off];
                s4[n] = __builtin_amdgcn_mfma_f32_16x16x32_bf16(qh_, kh, s4[n], 0, 0, 0);
                s4[n] = __builtin_amdgcn_mfma_f32_16x16x32_bf16(ql_, kh, s4[n], 0, 0, 0);
                s4[n] = __builtin_amdgcn_mfma_f32_16x16x32_bf16(qh_, kl, s4[n], 0, 0, 0);
            }
        }

#pragma unroll
        for (int n = 0; n < 4; n++) {
            int key = T * 64 + n * 16 + lr;
#pragma unroll
            for (int j = 0; j < 4; j++) {
                int gq = q0 + w * 16 + kc * 4 + j;
                float sv = s4[n][j] * scale;
                s4[n][j] = (key <= XLM + gq) ? sv : -1e30f;
            }
        }

        float tm[4];
#pragma unroll
        for (int j = 0; j < 4; j++) {
            float v = fmaxf(fmaxf(s4[0][j], s4[1][j]), fmaxf(s4[2][j], s4[3][j]));
            v = fmaxf(v, __shfl_xor(v, 1, 64));
            v = fmaxf(v, __shfl_xor(v, 2, 64));
            v = fmaxf(v, __shfl_xor(v, 4, 64));
            v = fmaxf(v, __shfl_xor(v, 8, 64));
            tm[j] = v;
        }
        float alpha[4];
#pragma unroll
        for (int j = 0; j < 4; j++) {
            float mnew = fmaxf(m[j], tm[j]);
            alpha[j] = __expf(m[j] - mnew);
            m[j] = mnew;
        }
        float psum[4] = {0.f, 0.f, 0.f, 0.f};
#pragma unroll
        for (int n = 0; n < 4; n++)
#pragma unroll
            for (int j = 0; j < 4; j++) {
                float p = __expf(s4[n][j] - m[j]);
                s4[n][j] = p;
                psum[j] += p;
            }
#pragma unroll
        for (int j = 0; j < 4; j++) {
            float v = psum[j];
            v += __shfl_xor(v, 1, 64);
            v += __shfl_xor(v, 2, 64);
            v += __shfl_xor(v, 4, 64);
            v += __shfl_xor(v, 8, 64);
            l[j] = l[j] * alpha[j] + v;
        }
#pragma unroll
        for (int f = 0; f < 4; f++)
#pragma unroll
            for (int j = 0; j < 4; j++) o[f][j] *= alpha[j];

#pragma unroll
        for (int n = 0; n < 4; n++) {
            int chunkcol = 2 * n + (lr >> 3);
#pragma unroll
            for (int j = 0; j < 4; j++) {
                int row = kc * 4 + j;
                int off = wbase + row * 64 + (((chunkcol ^ (row & 7)) << 3) + (lr & 7));
                sPf[off] = s4[n][j];
            }
        }

#pragma unroll
        for (int ks = 0; ks < 2; ks++) {
            int poff = wbase + lr * 64 + (((ks * 4 + kc) ^ (lr & 7)) << 3);
            float4 a = *(const float4*)&sPf[poff];
            float4 c2 = *(const float4*)&sPf[poff + 4];
            float vv[8] = {a.x, a.y, a.z, a.w, c2.x, c2.y, c2.z, c2.w};
            u16x8v hib, lob;
#pragma unroll
            for (int j = 0; j < 8; j++) {
                hib[j] = f2bfbits(vv[j]);
                lob[j] = f2bfbits(vv[j] - bfbits2f(hib[j]));
            }
            bf16x8v ph = *(bf16x8v*)&hib;
            bf16x8v pl = *(bf16x8v*)&lob;
#pragma unroll
            for (int f = 0; f < 4; f++) {
                int row = f * 16 + lr;
                int off = row * 64 + (((ks * 4 + kc) ^ (lr & 7)) << 3);
                bf16x8v vh = *(const bf16x8v*)&sVh[off];
                bf16x8v vl = *(const bf16x8v*)&sVl[off];
                o[f] = __builtin_amdgcn_mfma_f32_16x16x32_bf16(ph, vh, o[f], 0, 0, 0);
                o[f] = __builtin_amdgcn_mfma_f32_16x16x32_bf16(pl, vh, o[f], 0, 0, 0);
                o[f] = __builtin_amdgcn_mfma_f32_16x16x32_bf16(ph, vl, o[f], 0, 0, 0);
            }
        }
    }

    float inv[4];
#pragma unroll
    for (int j = 0; j < 4; j++) inv[j] = 1.0f / l[j];
    unsigned short* outu = (unsigned short*)out;
#pragma unroll
    for (int f = 0; f < 4; f++)
#pragma unroll
        for (int j = 0; j < 4; j++) {
            int gq = q0 + w * 16 + kc * 4 + j;
            size_t oidx = (size_t)(b * NSEQ + gq) * DIM + h * DH + f * 16 + lr;
            float v = o[f][j] * inv[j];
            unsigned short hv = f2bfbits(v);
            outu[oidx] = hv;
            outu[oidx + opS] = f2bfbits(v - bfbits2f(hv));
        }
    if (KNNL && lr == 0) {
#pragma unroll
        for (int j = 0; j < 4; j++) {
            int gq = q0 + w * 16 + kc * 4 + j;
            size_t srow = (((size_t)b * NH + h) * NSEQ + gq) * 2;
            stats[srow] = m[j];
            stats[srow + 1] = l[j];
        }
    }
}

// ---------------------------------------------------------------------------
// Per-row top-32 over bf16 simdb + exact recompute + mem softmax + combine.
// 4 waves per block, ONE ROW PER WAVE (no idle waves, no barriers).
// Per-wave 8KB LDS slab, chunk-of-8 XOR swizzle: element (c,l) of the row
// (c=chunk 0..63, l=0..63) at u16 index c*64 + (l ^ ((c&7)<<3)).
__global__ __launch_bounds__(256) void knn_select(const unsigned short* __restrict__ simdb,
                                                  const float* __restrict__ db,
                                                  const float* __restrict__ qf,
                                                  const float* __restrict__ dbkn,
                                                  const float* __restrict__ knn_scale,
                                                  const float* __restrict__ stats,
                                                  __hip_bfloat16* __restrict__ out,
                                                  size_t opS,
                                                  int bh0) {
    __shared__ unsigned short sv[4 * 4096];

    int bh = bh0 + blockIdx.y;
    int b = bh >> 4, h = bh & 15;
    int t = threadIdx.x;
    int w = t >> 6, lane = t & 63;
    int i = blockIdx.x * 4 + w;
    unsigned short* svw = &sv[w * 4096];

    // stage this wave's row: 512 16B-chunks / 64 lanes = 8 iters
    const unsigned short* srow = &simdb[((size_t)blockIdx.y * NSEQ + i) * MDB];
#pragma unroll
    for (int it = 0; it < 8; it++) {
        int g = it * 64 + lane;
        int c = g >> 3, sub = g & 7;
        u16x8v d = *(const u16x8v*)&srow[g * 8];
        *(u16x8v*)&svw[c * 64 + ((sub ^ (c & 7)) << 3)] = d;
    }

    // per-column candidates: lane owns column l, scans 64 chunks
    float lmax = -1e30f; int lidx = 0;
#pragma unroll
    for (int c = 0; c < 64; c++) {
        float v = bfbits2f(svw[c * 64 + (lane ^ ((c & 7) << 3))]);
        if (v > lmax) { lmax = v; lidx = c * 64 + lane; }
    }

    // 32 selection iterations, wave-synchronous
    int tidx = 0;
    for (int it = 0; it < TOPK; it++) {
        float v = lmax; int idx = lidx;
#pragma unroll
        for (int off = 32; off; off >>= 1) {
            float v2 = __shfl_xor(v, off, 64);
            int i2 = __shfl_xor(idx, off, 64);
            if (v2 > v || (v2 == v && i2 < idx)) { v = v2; idx = i2; }
        }
        if (lane == it) tidx = idx;
        int col = idx & 63, cc = idx >> 6;
        if (lane == 0) svw[cc * 64 + (col ^ ((cc & 7) << 3))] = 0xFF80; // bf16 -inf
        // rescan column col: lane reads element (c=lane, col)
        float rv = bfbits2f(svw[lane * 64 + (col ^ ((lane & 7) << 3))]);
        int ridx = lane * 64 + col;
#pragma unroll
        for (int off = 32; off; off >>= 1) {
            float v2 = __shfl_xor(rv, off, 64);
            int i2 = __shfl_xor(ridx, off, 64);
            if (v2 > rv || (v2 == rv && i2 < ridx)) { rv = v2; ridx = i2; }
        }
        if (lane == col) { lmax = rv; lidx = ridx; }
    }

    // exact recompute of selected sims (lane j < 32 recomputes sim of its idx)
    float srec = -1e30f;
    if (lane < TOPK) {
        const float* qrow = &qf[(size_t)(b * NSEQ + i) * DIM + h * DH];
        const float* krow = &dbkn[((size_t)b * MDB + tidx) * DH];
        float s = 0.f;
#pragma unroll
        for (int d4 = 0; d4 < 16; d4++) {
            float4 a = *(const float4*)&qrow[d4 * 4];
            float4 k2 = *(const float4*)&krow[d4 * 4];
            s += a.x * k2.x + a.y * k2.y + a.z * k2.z + a.w * k2.w;
        }
        srec = s;
    }

    float scl = __expf(knn_scale[h]);
    size_t srow_idx = (((size_t)b * NH + h) * NSEQ + i) * 2;
    float m_loc = stats[srow_idx], l_loc = stats[srow_idx + 1];
    float mm = srec;
#pragma unroll
    for (int off = 32; off; off >>= 1) mm = fmaxf(mm, __shfl_xor(mm, off, 64));
    float M = fmaxf(m_loc, mm * scl);
    float co = __expf(m_loc - M);
    float e = (lane < TOPK) ? __expf(srec * scl - M) : 0.f;
    float esum = e;
#pragma unroll
    for (int off = 32; off; off >>= 1) esum += __shfl_xor(esum, off, 64);
    float denom = l_loc * co + esum;

    // gather: lane = output dim; iterate 32 selected keys via shfl broadcast
    float acc = 0.f;
#pragma unroll
    for (int j = 0; j < TOPK; j++) {
        int idxj = __shfl(tidx, j, 64);
        float ej = __shfl(e, j, 64);
        acc += ej * db[(((size_t)b * MDB + idxj) * 2 + 1) * DH + lane];
    }

    size_t op = (size_t)(b * NSEQ + i) * DIM + h * DH + lane;
    float o_loc = bf2f(out[op]) + bf2f(out[op + opS]);
    float nv = (o_loc * l_loc * co + acc) / denom;
    __hip_bfloat16 hv = f2bf(nv);
    out[op] = hv;
    out[op + opS] = f2bf(nv - bf2f(hv));
}

// ---------------------------------------------------------------------------
extern "C" void kernel_launch(void* const* d_in, const int* in_sizes, int n_in,
                              void* d_out, int out_size, void* d_ws, size_t ws_size,
                              hipStream_t stream) {
    const int* tokens = (const int*)d_in[0];
    const float* emb = (const float*)d_in[1];
    const float* ln1_w = (const float*)d_in[2];
    const float* ln1_b = (const float*)d_in[3];
    const float* wq = (const float*)d_in[4];
    const float* wkv = (const float*)d_in[5];
    const float* wo = (const float*)d_in[6];
    const float* wo_b = (const float*)d_in[7];
    const float* knn_scale = (const float*)d_in[8];
    const float* ln2_w = (const float*)d_in[9];
    const float* ln2_b = (const float*)d_in[10];
    const float* ff_w1 = (const float*)d_in[11];
    const float* ff_b1 = (const float*)d_in[12];
    const float* ff_w2 = (const float*)d_in[13];
    const float* ff_b2 = (const float*)d_in[14];
    const float* lnf_w = (const float*)d_in[15];
    const float* lnf_b = (const float*)d_in[16];
    const float* w_logits = (const float*)d_in[17];
    const float* b_logits = (const float*)d_in[18];
    const float* xl_mems = (const float*)d_in[19];
    const float* db_kv = (const float*)d_in[20];

    // ---- workspace layout ----
    const size_t PS_H = (size_t)BNROWS * DIM;        // plane stride for h / attn-out
    char* p = (char*)d_ws;
    float* x = (float*)p;                p += PS_H * 4;                        // 8 MB
    __hip_bfloat16* hb = (__hip_bfloat16*)p;  p += PS_H * 2 * 2;               // 8 MB (2 planes)
    float* qf = (float*)p;               p += PS_H * 4;                        // 8 MB
    float* kvf = (float*)p;              p += (size_t)BNROWS * 128 * 4;        // 1 MB
    float* dbkn = (float*)p;             p += (size_t)BB * MDB * DH * 4;       // 2 MB
    float* stats = (float*)p;            p += (size_t)BB * NH * NSEQ * 2 * 4;  // 0.25 MB
    unsigned short* ksp = (unsigned short*)p; p += KSP_PS * 2 * 2;             // 0.66 MB
    unsigned short* vtp = (unsigned short*)p; p += KSP_PS * 2 * 2;             // 0.66 MB
    __hip_bfloat16* wT = (__hip_bfloat16*)p; p += (size_t)4096 * DIM * 2 * 2;  // 16 MB (2 planes)

    // qsplit/dbkn-split live in the wT region during the KNN phase (wT idle)
    unsigned short* qsplit = (unsigned short*)wT;                  // 2 planes x PS_H
    unsigned short* dbks = (unsigned short*)wT + 2 * PS_H;         // 2 planes x BB*MDB*DH
    const size_t PS_DB = (size_t)BB * MDB * DH;

    const size_t PS_MID = (size_t)BNROWS * 4 * DIM;  // 8M elems per plane
    __hip_bfloat16* midb = (__hip_bfloat16*)d_out;   // 32 MB of the 262 MB out buf
    float* logits = (float*)d_out;

    embed_kernel<<<BNROWS, 256, 0, stream>>>(tokens, emb, x);
    dbnorm_kernel<<<BB * MDB, 64, 0, stream>>>(db_kv, dbkn);

    for (int l = 0; l < DEPTH; l++) {
        const float* wq_l = wq + (size_t)l * DIM * DIM;
        const float* wkv_l = wkv + (size_t)l * DIM * 128;
        const float* wo_l = wo + (size_t)l * DIM * DIM;
        const float* xlm_l = xl_mems + (size_t)l * BB * XLM * 2 * DH;

        // h = LN1(x) -> split bf16
        ln_kernel<<<BNROWS, 256, 0, stream>>>(x, ln1_w + (size_t)l * DIM, ln1_b + (size_t)l * DIM, hb, PS_H);

        // q = h @ wq  (fp32 out)
        wconv<<<dim3(16, 16), 256, 0, stream>>>(wq_l, wT, (size_t)DIM * DIM, DIM, DIM, DIM, 1);
        gemm_split<float, 0, 3, 0><<<dim3(DIM / 128, BNROWS / 128), 256, 0, stream>>>(
            hb, DIM, PS_H, wT, DIM, (size_t)DIM * DIM, qf, DIM, 0, DIM, nullptr, nullptr, 0);
        // kv = h @ wkv (fp32 out)
        wconv<<<dim3(16, 2), 256, 0, stream>>>(wkv_l, wT, (size_t)128 * DIM, DIM, 128, 128, 1);
        gemm_split<float, 0, 3, 0><<<dim3(1, BNROWS / 128), 256, 0, stream>>>(
            hb, DIM, PS_H, wT, DIM, (size_t)128 * DIM, kvf, 128, 0, DIM, nullptr, nullptr, 0);

        if (l == KNN_LAYER) {
            l2norm_kernel<<<BNROWS * NH, 64, 0, stream>>>(qf, DH);
            l2norm_kernel<<<BNROWS, 64, 0, stream>>>(kvf, 128);
            kv_prep<<<dim3(NKEYS, BB), 64, 0, stream>>>(kvf, xlm_l, ksp, vtp);
            split_conv<<<(PS_H / 4 + 255) / 256, 256, 0, stream>>>(qf, qsplit, PS_H, PS_H / 4);
            split_conv<<<(PS_DB / 4 + 255) / 256, 256, 0, stream>>>(dbkn, dbks, PS_DB, PS_DB / 4);
            flash_kernel<1><<<dim3(NSEQ / 64, NH, BB), 256, 0, stream>>>(
                qf, ksp, vtp, knn_scale, hb, PS_H, stats);
            const int CHUNK = 16;  // 16 slices x 8 MB bf16 = 134 MB in d_out
            for (int bh0 = 0; bh0 < BB * NH; bh0 += CHUNK) {
                gemm_split<unsigned short, 0, 3, 1><<<dim3(MDB / 128, NSEQ / 128, CHUNK), 256, 0, stream>>>(
                    (const __hip_bfloat16*)qsplit, DIM, PS_H,
                    (const __hip_bfloat16*)dbks, DH, PS_DB,
                    (unsigned short*)d_out, MDB, 0, DH, nullptr, nullptr, bh0);
                knn_select<<<dim3(NSEQ / 4, CHUNK), 256, 0, stream>>>(
                    (const unsigned short*)d_out, db_kv, qf, dbkn, knn_scale, stats, hb, PS_H, bh0);
            }
        } else {
            kv_prep<<<dim3(NKEYS, BB), 64, 0, stream>>>(kvf, xlm_l, ksp, vtp);
            flash_kernel<0><<<dim3(NSEQ / 64, NH, BB), 256, 0, stream>>>(
                qf, ksp, vtp, knn_scale, hb, PS_H, stats);
        }

        // x = attn @ wo + wo_b + x
        wconv<<<dim3(16, 16), 256, 0, stream>>>(wo_l, wT, (size_t)DIM * DIM, DIM, DIM, DIM, 1);
        gemm_split<float, 0, 3, 0><<<dim3(DIM / 128, BNROWS / 128), 256, 0, stream>>>(
            hb, DIM, PS_H, wT, DIM, (size_t)DIM * DIM, x, DIM, 0, DIM,
            wo_b + (size_t)l * DIM, x, 0);

        // h = LN2(x)
        ln_kernel<<<BNROWS, 256, 0, stream>>>(x, ln2_w + (size_t)l * DIM, ln2_b + (size_t)l * DIM, hb, PS_H);
        // mid = gelu(h @ ff_w1 + b1) -> split bf16 (in d_out)
        wconv<<<dim3(16, 64), 256, 0, stream>>>(ff_w1 + (size_t)l * DIM * 4 * DIM, wT, (size_t)4096 * DIM, DIM, 4 * DIM, 4 * DIM, 1);
        gemm_split<__hip_bfloat16, 1, 3, 0><<<dim3(4 * DIM / 128, BNROWS / 128), 256, 0, stream>>>(
            hb, DIM, PS_H, wT, DIM, (size_t)4096 * DIM, midb, 4 * DIM, PS_MID, DIM,
            ff_b1 + (size_t)l * 4 * DIM, nullptr, 0);
        // x = mid @ ff_w2 + b2 + x
        wconv<<<dim3(64, 16), 256, 0, stream>>>(ff_w2 + (size_t)l * 4 * DIM * DIM, wT, (size_t)DIM * 4096, 4 * DIM, DIM, DIM, 1);
        gemm_split<float, 0, 3, 0><<<dim3(DIM / 128, BNROWS / 128), 256, 0, stream>>>(
            midb, 4 * DIM, PS_MID, wT, 4 * DIM, (size_t)DIM * 4096, x, DIM, 0, 4 * DIM,
            ff_b2 + (size_t)l * DIM, x, 0);
    }

    // final LN + logits (5 column chunks of 6400, hi-plane-only bf16 GEMM)
    ln_kernel<<<BNROWS, 256, 0, stream>>>(x, lnf_w, lnf_b, hb, PS_H);
    for (int c0 = 0; c0 < VOCAB; c0 += LOGITS_CHUNK) {
        wconv<<<dim3(16, LOGITS_CHUNK / 64), 256, 0, stream>>>(
            w_logits + c0, wT, 0, DIM, LOGITS_CHUNK, VOCAB, 0);
        gemm_split<float, 0, 1, 0><<<dim3(LOGITS_CHUNK / 128, BNROWS / 128), 256, 0, stream>>>(
            hb, DIM, PS_H, wT, DIM, 0, logits + c0, VOCAB, 0, DIM,
            b_logits + c0, nullptr, 0);
    }
}